// Round 9
// baseline (1975.904 us; speedup 1.0000x reference)
//
#include <hip/hip_runtime.h>

#define N_NODES 100000
#define N_EDGES 200000
#define N_GRAPHS 4000
#define F_IN 44
#define HDIM 256
#define EDIM 512
#define NLAYERS 4

typedef float floatx4 __attribute__((ext_vector_type(4)));
typedef short bhalf8 __attribute__((ext_vector_type(8)));

__device__ __forceinline__ unsigned short f2bf(float f) {
    unsigned int u = __float_as_uint(f);
    u += 0x7FFFu + ((u >> 16) & 1u);          // RNE
    return (unsigned short)(u >> 16);
}
__device__ __forceinline__ float bf2f(unsigned short s) {
    return __uint_as_float(((unsigned int)s) << 16);
}
// packed (hi | lo<<16): ushort[2k]=hi, ushort[2k+1]=lo in little-endian memory
__device__ __forceinline__ unsigned int packbf(float v) {
    const unsigned short hh = f2bf(v);
    const unsigned short ll = f2bf(v - bf2f(hh));
    return (unsigned int)hh | ((unsigned int)ll << 16);
}

// async global->LDS, 16B/lane. ldst wave-uniform base; gsrc per-lane.
__device__ __forceinline__ void gload16(const void* gsrc, void* ldst) {
    __builtin_amdgcn_global_load_lds(
        (const __attribute__((address_space(1))) void*)gsrc,
        (__attribute__((address_space(3))) void*)ldst, 16, 0, 0);
}

// ---------------- zero fill ----------------
__global__ void zero_kernel(float* __restrict__ p, size_t n4) {
    size_t i = (size_t)blockIdx.x * blockDim.x + threadIdx.x;
    const size_t stride = (size_t)gridDim.x * blockDim.x;
    const float4 z = make_float4(0.f, 0.f, 0.f, 0.f);
    for (; i < n4; i += stride) ((float4*)p)[i] = z;
}

// -------- atom MLP: h = relu(x @ W_atom + b_atom). W column in VGPRs, 16 nodes/group ------
__global__ __launch_bounds__(256) void atom_kernel(const float* __restrict__ x,
                                                   const float* __restrict__ W,
                                                   const float* __restrict__ b,
                                                   float* __restrict__ h) {
    const int t = threadIdx.x;
    float w[F_IN];
#pragma unroll
    for (int k = 0; k < F_IN; ++k) w[k] = W[k * HDIM + t];   // coalesced, once
    const float bj = b[t];
    __shared__ float xs[16 * F_IN];      // 2.8 KB broadcast buffer
    const int NG = N_NODES / 16;         // 6250
    for (int g = blockIdx.x; g < NG; g += gridDim.x) {
        __syncthreads();                 // protect xs from previous readers
        for (int i = t; i < 16 * F_IN; i += 256) xs[i] = x[(size_t)g * 16 * F_IN + i];
        __syncthreads();
        float acc[16];
#pragma unroll
        for (int n = 0; n < 16; ++n) acc[n] = bj;
#pragma unroll
        for (int k = 0; k < F_IN; ++k) {
#pragma unroll
            for (int n = 0; n < 16; ++n) acc[n] = fmaf(xs[n * F_IN + k], w[k], acc[n]);
        }
#pragma unroll
        for (int n = 0; n < 16; ++n)
            h[(size_t)(g * 16 + n) * HDIM + t] = fmaxf(acc[n], 0.f);
    }
}

// ---------------- CSR build ----------------
__global__ void hist_kernel(const int* __restrict__ dst, int* __restrict__ deg) {
    const int e = blockIdx.x * 256 + threadIdx.x;
    if (e < N_EDGES) atomicAdd(&deg[dst[e]], 1);
}

__global__ void scan1_kernel(const int* __restrict__ deg, int* __restrict__ row_ptr,
                             int* __restrict__ blk) {
    __shared__ int s[256];
    const int i = blockIdx.x * 256 + threadIdx.x;
    s[threadIdx.x] = (i < N_NODES) ? deg[i] : 0;
    __syncthreads();
    for (int off = 1; off < 256; off <<= 1) {
        int t = (threadIdx.x >= off) ? s[threadIdx.x - off] : 0;
        __syncthreads();
        s[threadIdx.x] += t;
        __syncthreads();
    }
    if (i < N_NODES) row_ptr[i + 1] = s[threadIdx.x];
    if (threadIdx.x == 255) blk[blockIdx.x] = s[255];
}

__global__ void scan2_kernel(int* __restrict__ blk, int nb) {
    if (threadIdx.x == 0 && blockIdx.x == 0) {
        int run = 0;
        for (int b = 0; b < nb; ++b) { const int t = blk[b]; blk[b] = run; run += t; }
    }
}

__global__ void scan3_kernel(int* __restrict__ row_ptr, const int* __restrict__ blk) {
    const int i = blockIdx.x * 256 + threadIdx.x;
    if (i < N_NODES) row_ptr[i + 1] += blk[i >> 8];
    if (i == 0) row_ptr[0] = 0;
}

__global__ void cursor_kernel(const int* __restrict__ row_ptr, int* __restrict__ cursor) {
    const int i = blockIdx.x * 256 + threadIdx.x;
    if (i < N_NODES) cursor[i] = row_ptr[i];
}

__global__ void fill_kernel(const int* __restrict__ src, const int* __restrict__ dst,
                            int* __restrict__ cursor, int* __restrict__ eids) {
    const int e = blockIdx.x * 256 + threadIdx.x;
    if (e < N_EDGES) {
        const int pos = atomicAdd(&cursor[dst[e]], 1);
        eids[pos] = src[e];
    }
}

// ------- gather: z = h + sum_neigh h; write K-interleaved hi/lo bf16 [n][2*HDIM] -------
__global__ void gather_kernel(const float* __restrict__ h, const int* __restrict__ row_ptr,
                              const int* __restrict__ eids, unsigned short* __restrict__ z) {
    const int tid = threadIdx.x;
    const int n = blockIdx.x * 4 + (tid >> 6);
    const int t = tid & 63;
    const float4* h4 = (const float4*)h;
    float4 acc = h4[(size_t)n * 64 + t];
    const int s = row_ptr[n], e = row_ptr[n + 1];
    for (int i = s; i < e; ++i) {
        const float4 v = h4[(size_t)eids[i] * 64 + t];
        acc.x += v.x; acc.y += v.y; acc.z += v.z; acc.w += v.w;
    }
    uint4 pk;
    pk.x = packbf(acc.x); pk.y = packbf(acc.y);
    pk.z = packbf(acc.z); pk.w = packbf(acc.w);
    ((uint4*)(z + (size_t)n * 2 * HDIM))[t] = pk;
}

// ------- fused weight prep: all weights -> [N][K] packed (hi,lo)-uint, one dispatch -------
__global__ void wprep_all(const float* __restrict__ W1, const float* __restrict__ W2,
                          const float* __restrict__ Wf1, const float* __restrict__ Wf2,
                          unsigned int* __restrict__ t1, unsigned int* __restrict__ t2,
                          unsigned int* __restrict__ tf1, unsigned int* __restrict__ tf2) {
    const int WSZ = HDIM * 2 * HDIM;                 // 131072
    const int total = 8 * WSZ + HDIM * HDIM + HDIM * EDIM;
    const int stride = gridDim.x * 256;
    for (int idx = blockIdx.x * 256 + threadIdx.x; idx < total; idx += stride) {
        if (idx < 4 * WSZ) {                         // W1: K=256, N=512
            const int l = idx >> 17, e = idx & (WSZ - 1);
            const int k = e >> 9, n = e & 511;
            t1[(size_t)l * WSZ + n * HDIM + k] = packbf(W1[idx]);
        } else if (idx < 8 * WSZ) {                  // W2: K=512, N=256
            const int r = idx - 4 * WSZ;
            const int l = r >> 17, e = r & (WSZ - 1);
            const int k = e >> 8, n = e & 255;
            t2[(size_t)l * WSZ + n * EDIM + k] = packbf(W2[r]);
        } else if (idx < 8 * WSZ + HDIM * HDIM) {    // Wf1: K=256, N=256
            const int e = idx - 8 * WSZ;
            const int k = e >> 8, n = e & 255;
            tf1[n * HDIM + k] = packbf(Wf1[e]);
        } else {                                     // Wf2: K=256, N=512
            const int e = idx - 8 * WSZ - HDIM * HDIM;
            const int k = e >> 9, n = e & 511;
            tf2[n * HDIM + k] = packbf(Wf2[e]);
        }
    }
}

// ---------------- MFMA GEMM: C = act(A @ B + bias), K-interleaved bf16 ----------------
// A [M][KK] bf16 row-major, BT [N][KK] bf16. KK mult of 32, NT >= 2. N mult of 256.
// Block tile 128x256, 4 waves (2x2), wave tile 64x128 (32 MFMA/phase -> LDS demand
// ~79 B/cy/wave, under the 256 B/cy/CU LDS ceiling). BK=32.
// Ring-3 LDS (72 KB), depth-2 prefetch, counted s_waitcnt vmcnt(12/6/0).
// LDS rows 64B, granule swizzle phys = g ^ ((row>>1)&3) -> 2-way max (free).
// OUT: 0 = fp32, 1 = fp32+relu, 2 = packed-uint hi/lo interleaved + relu
template <int OUT>
__global__ __launch_bounds__(256)
void gemm_mfma(const unsigned short* __restrict__ A, const unsigned short* __restrict__ BT,
               const float* __restrict__ bias, float* __restrict__ C,
               unsigned short* __restrict__ Z, int M, int N, int KK) {
    __shared__ __align__(16) unsigned short lds[3 * 12288];  // 3 x (A 8KB | B 16KB)

    const int nrow = (M + 127) >> 7;
    const int G = gridDim.x;
    int wg = blockIdx.x;
    {   // bijective XCD remap (m204)
        const int q = G >> 3, r = G & 7;
        const int xx = wg & 7, o = wg >> 3;
        wg = (xx < r ? xx * (q + 1) : r * (q + 1) + (xx - r) * q) + o;
    }
    const int row0 = (wg % nrow) << 7;
    const int col0 = (wg / nrow) << 8;

    const int tid = threadIdx.x;
    const int lane = tid & 63;
    const int w = tid >> 6;
    const int wr = w >> 1, wc = w & 1;
    const int lr = lane & 15;
    const int l4 = lane >> 4;

    // staging lane geometry: row = base + lane>>2, phys granule = lane&3
    const int lrow = lane >> 2;
    const int sgran = ((lane & 3) ^ ((lane >> 3) & 3)) << 3;   // pre-swizzled src granule
    // fragment read: swizzled granule for this lane (row bases are mult of 16 -> no term)
    const int pg = (l4 ^ ((lr >> 1) & 3)) << 3;

    floatx4 acc[4][8];
#pragma unroll
    for (int m = 0; m < 4; ++m)
#pragma unroll
        for (int n = 0; n < 8; ++n) acc[m][n] = (floatx4){0.f, 0.f, 0.f, 0.f};

    const int NT = KK >> 5;

    auto stage = [&](int t, int b) {
        const int k0 = t << 5;
        unsigned short* la = &lds[b * 12288];
        unsigned short* lb = la + 4096;
#pragma unroll
        for (int j = 0; j < 2; ++j) {                // A: 128 rows, 2 groups/wave
            const int R = (w << 5) + (j << 4);
            int ar = row0 + R + lrow;
            if (ar >= M) ar = M - 1;                 // clamp (keeps vmcnt uniform)
            gload16(A + (size_t)ar * KK + k0 + sgran, la + (R << 5));
        }
#pragma unroll
        for (int j = 0; j < 4; ++j) {                // B: 256 rows, 4 groups/wave
            const int R = (w << 6) + (j << 4);
            gload16(BT + (size_t)(col0 + R + lrow) * KK + k0 + sgran, lb + (R << 5));
        }
    };

    stage(0, 0);
    stage(1, 1);
    int rb = 0;                                      // read buffer = t % 3
    for (int t = 0; t < NT; ++t) {
        if (t + 2 < NT) {
            int wbuf = rb + 2; if (wbuf >= 3) wbuf -= 3;
            stage(t + 2, wbuf);                      // depth-2 prefetch
            __builtin_amdgcn_sched_barrier(0);
            asm volatile("s_waitcnt vmcnt(12)" ::: "memory");  // t landed; t+1,t+2 in flight
        } else if (t + 1 < NT) {
            __builtin_amdgcn_sched_barrier(0);
            asm volatile("s_waitcnt vmcnt(6)" ::: "memory");
        } else {
            __builtin_amdgcn_sched_barrier(0);
            asm volatile("s_waitcnt vmcnt(0)" ::: "memory");
        }
        __builtin_amdgcn_sched_barrier(0);
        __builtin_amdgcn_s_barrier();

        const unsigned short* la = &lds[rb * 12288];
        const unsigned short* lb = la + 4096;
        bhalf8 fa[4], fb[8];
#pragma unroll
        for (int m = 0; m < 4; ++m)
            fa[m] = *(const bhalf8*)&la[((wr << 6) + (m << 4) + lr) * 32 + pg];
#pragma unroll
        for (int n = 0; n < 8; ++n)
            fb[n] = *(const bhalf8*)&lb[((wc << 7) + (n << 4) + lr) * 32 + pg];
#pragma unroll
        for (int m = 0; m < 4; ++m)
#pragma unroll
            for (int n = 0; n < 8; ++n)
                acc[m][n] = __builtin_amdgcn_mfma_f32_16x16x32_bf16(fa[m], fb[n], acc[m][n], 0, 0, 0);

        asm volatile("s_waitcnt lgkmcnt(0)" ::: "memory");   // ds_reads done before reuse
        __builtin_amdgcn_sched_barrier(0);
        __builtin_amdgcn_s_barrier();
        rb = (rb + 1 == 3) ? 0 : rb + 1;
    }

    // epilogue: C/D layout col = lane&15, row = (lane>>4)*4 + j
    const int rgrp = l4 * 4;
#pragma unroll
    for (int n = 0; n < 8; ++n) {
        const int col = col0 + (wc << 7) + (n << 4) + lr;
        const float bv = bias[col];
#pragma unroll
        for (int m = 0; m < 4; ++m) {
            const int rw = row0 + (wr << 6) + (m << 4) + rgrp;
#pragma unroll
            for (int j = 0; j < 4; ++j) {
                const int row = rw + j;
                if (row < M) {
                    float v = acc[m][n][j] + bv;
                    if (OUT >= 1) v = fmaxf(v, 0.f);
                    if (OUT == 2) {
                        ((unsigned int*)Z)[(size_t)row * N + col] = packbf(v);  // coalesced
                    } else {
                        C[(size_t)row * N + col] = v;
                    }
                }
            }
        }
    }
}

// ------- pool: sorted-batch segment mean -> K-interleaved hi/lo [g][2*HDIM] -------
__global__ void pool_kernel(const float* __restrict__ h, const int* __restrict__ batch,
                            unsigned short* __restrict__ gz) {
    __shared__ int sse[2];
    const int g = blockIdx.x;
    if (threadIdx.x < 2) {
        const int target = g + threadIdx.x;
        int lo = 0, hi = N_NODES;
        while (lo < hi) {
            const int mid = (lo + hi) >> 1;
            if (batch[mid] < target) lo = mid + 1; else hi = mid;
        }
        sse[threadIdx.x] = lo;
    }
    __syncthreads();
    const int s = sse[0], e = sse[1];
    const int j = threadIdx.x;
    float acc = 0.f;
    for (int n = s; n < e; ++n) acc += h[(size_t)n * HDIM + j];
    const float v = acc * ((e > s) ? 1.f / (float)(e - s) : 1.f);
    ((unsigned int*)gz)[(size_t)g * HDIM + j] = packbf(v);
}

extern "C" void kernel_launch(void* const* d_in, const int* in_sizes, int n_in,
                              void* d_out, int out_size, void* d_ws, size_t ws_size,
                              hipStream_t stream) {
    const float* x      = (const float*)d_in[0];
    const int*   eidx   = (const int*)d_in[1];
    const int*   batch  = (const int*)d_in[2];
    const float* W_atom = (const float*)d_in[3];
    const float* b_atom = (const float*)d_in[4];
    const float* W1     = (const float*)d_in[5];
    const float* b1     = (const float*)d_in[6];
    const float* W2     = (const float*)d_in[7];
    const float* b2     = (const float*)d_in[8];
    const float* Wf1    = (const float*)d_in[9];
    const float* bf1    = (const float*)d_in[10];
    const float* Wf2    = (const float*)d_in[11];
    const float* bf2    = (const float*)d_in[12];
    float* out = (float*)d_out;

    const int* src = eidx;
    const int* dst = eidx + N_EDGES;

    const size_t NH = (size_t)N_NODES * HDIM;           // 25.6M elems
    const int WSZ = HDIM * 2 * HDIM;                    // fp32 elems per layer weight

    // ---- workspace layout ----
    char* base = (char*)d_ws;
    size_t off = 0;
    float* h = (float*)(base + off);                        off += NH * 4;
    unsigned short* zin = (unsigned short*)(base + off);    off += NH * 2 * 2;  // [N][512]
    int* deg     = (int*)(base + off);            off += (size_t)N_NODES * 4;
    int* row_ptr = (int*)(base + off);            off += (size_t)(N_NODES + 1) * 4;
    int* cursor  = (int*)(base + off);            off += (size_t)N_NODES * 4;
    int* eids    = (int*)(base + off);            off += (size_t)N_EDGES * 4;
    int* blk     = (int*)(base + off);            off += 512 * 4;
    off = (off + 255) & ~(size_t)255;
    unsigned short* t1 = (unsigned short*)(base + off); off += (size_t)NLAYERS * WSZ * 2 * 2;
    unsigned short* t2 = (unsigned short*)(base + off); off += (size_t)NLAYERS * WSZ * 2 * 2;
    unsigned short* tf1 = (unsigned short*)(base + off); off += (size_t)HDIM * HDIM * 2 * 2;
    unsigned short* tf2 = (unsigned short*)(base + off); off += (size_t)HDIM * EDIM * 2 * 2;
    off = (off + 255) & ~(size_t)255;

    const size_t avail = (ws_size > off) ? ws_size - off : 0;
    long chunk = (long)(avail / ((size_t)EDIM * 2 * 2));   // z2 row = 2*EDIM ushorts
    if (chunk > 50048) chunk = 50048;                      // 2 chunks; z2 L3-resident
    if (chunk >= N_NODES) chunk = N_NODES;
    else chunk &= ~127L;
    if (chunk < 128) chunk = 128;
    unsigned short* z2 = (unsigned short*)(base + off);    // [chunk][1024]

    // head buffers overlap the (dead-after-layers) zin region
    const size_t GH2 = (size_t)N_GRAPHS * 2 * HDIM;
    unsigned short* hg  = zin;            // [4000][512]
    unsigned short* hg1 = zin + GH2;      // [4000][512]

    const int nb = (N_NODES + 255) / 256;
    const int T1SZ = 2 * WSZ;
    const int T2SZ = 2 * WSZ;

    // 1. atom MLP (W in VGPRs, grid-stride groups of 16 nodes)
    atom_kernel<<<1024, 256, 0, stream>>>(x, W_atom, b_atom, h);

    // 2. CSR build
    zero_kernel<<<128, 256, 0, stream>>>((float*)deg, N_NODES / 4);
    hist_kernel<<<(N_EDGES + 255) / 256, 256, 0, stream>>>(dst, deg);
    scan1_kernel<<<nb, 256, 0, stream>>>(deg, row_ptr, blk);
    scan2_kernel<<<1, 64, 0, stream>>>(blk, nb);
    scan3_kernel<<<nb, 256, 0, stream>>>(row_ptr, blk);
    cursor_kernel<<<nb, 256, 0, stream>>>(row_ptr, cursor);
    fill_kernel<<<(N_EDGES + 255) / 256, 256, 0, stream>>>(src, dst, cursor, eids);

    // 3. fused weight transpose + K-interleaved bf16 split (one dispatch)
    wprep_all<<<1024, 256, 0, stream>>>(W1, W2, Wf1, Wf2,
        (unsigned int*)t1, (unsigned int*)t2, (unsigned int*)tf1, (unsigned int*)tf2);

    // 4. GIN layers
    for (int l = 0; l < NLAYERS; ++l) {
        gather_kernel<<<N_NODES / 4, 256, 0, stream>>>(h, row_ptr, eids, zin);
        for (long r0 = 0; r0 < N_NODES; r0 += chunk) {
            const int mc = (int)((N_NODES - r0 < chunk) ? (N_NODES - r0) : chunk);
            const int nrow1 = (mc + 127) / 128;
            // z2 = relu(zin @ W1[l] + b1[l])  [mc, 512] -> interleaved bf16 [mc][1024]
            gemm_mfma<2><<<2 * nrow1, 256, 0, stream>>>(
                zin + (size_t)r0 * 2 * HDIM, t1 + (size_t)l * T1SZ,
                b1 + (size_t)l * 2 * HDIM, nullptr, z2, mc, 2 * HDIM, 2 * HDIM);
            // h = relu(z2 @ W2[l] + b2[l])    [mc, 256] -> fp32
            gemm_mfma<1><<<nrow1, 256, 0, stream>>>(
                z2, t2 + (size_t)l * T2SZ,
                b2 + (size_t)l * HDIM, h + (size_t)r0 * HDIM, nullptr, mc, HDIM, 4 * HDIM);
        }
    }

    // 5. pool (interleaved split write)
    pool_kernel<<<N_GRAPHS, HDIM, 0, stream>>>(h, batch, hg);

    // 6. head
    gemm_mfma<2><<<(N_GRAPHS + 127) / 128, 256, 0, stream>>>(
        hg, tf1, bf1, nullptr, hg1, N_GRAPHS, HDIM, 2 * HDIM);
    gemm_mfma<0><<<2 * ((N_GRAPHS + 127) / 128), 256, 0, stream>>>(
        hg1, tf2, bf2, out, nullptr, N_GRAPHS, EDIM, 2 * HDIM);
}

// Round 11
// 1590.233 us; speedup vs baseline: 1.2425x; 1.2425x over previous
//
#include <hip/hip_runtime.h>

#define N_NODES 100000
#define N_EDGES 200000
#define N_GRAPHS 4000
#define F_IN 44
#define HDIM 256
#define EDIM 512
#define NLAYERS 4

typedef float floatx4 __attribute__((ext_vector_type(4)));
typedef short bhalf8 __attribute__((ext_vector_type(8)));

__device__ __forceinline__ unsigned short f2bf(float f) {
    unsigned int u = __float_as_uint(f);
    u += 0x7FFFu + ((u >> 16) & 1u);          // RNE
    return (unsigned short)(u >> 16);
}
__device__ __forceinline__ float bf2f(unsigned short s) {
    return __uint_as_float(((unsigned int)s) << 16);
}
// packed (hi | lo<<16): ushort[2k]=hi, ushort[2k+1]=lo in little-endian memory
__device__ __forceinline__ unsigned int packbf(float v) {
    const unsigned short hh = f2bf(v);
    const unsigned short ll = f2bf(v - bf2f(hh));
    return (unsigned int)hh | ((unsigned int)ll << 16);
}

// async global->LDS, 16B/lane. ldst wave-uniform base; gsrc per-lane.
__device__ __forceinline__ void gload16(const void* gsrc, void* ldst) {
    __builtin_amdgcn_global_load_lds(
        (const __attribute__((address_space(1))) void*)gsrc,
        (__attribute__((address_space(3))) void*)ldst, 16, 0, 0);
}

// ---------------- zero fill ----------------
__global__ void zero_kernel(float* __restrict__ p, size_t n4) {
    size_t i = (size_t)blockIdx.x * blockDim.x + threadIdx.x;
    const size_t stride = (size_t)gridDim.x * blockDim.x;
    const float4 z = make_float4(0.f, 0.f, 0.f, 0.f);
    for (; i < n4; i += stride) ((float4*)p)[i] = z;
}

// -------- atom MLP: h = relu(x @ W_atom + b_atom). W column in VGPRs, 16 nodes/group ------
__global__ __launch_bounds__(256) void atom_kernel(const float* __restrict__ x,
                                                   const float* __restrict__ W,
                                                   const float* __restrict__ b,
                                                   float* __restrict__ h) {
    const int t = threadIdx.x;
    float w[F_IN];
#pragma unroll
    for (int k = 0; k < F_IN; ++k) w[k] = W[k * HDIM + t];   // coalesced, once
    const float bj = b[t];
    __shared__ float xs[16 * F_IN];      // 2.8 KB broadcast buffer
    const int NG = N_NODES / 16;         // 6250
    for (int g = blockIdx.x; g < NG; g += gridDim.x) {
        __syncthreads();                 // protect xs from previous readers
        for (int i = t; i < 16 * F_IN; i += 256) xs[i] = x[(size_t)g * 16 * F_IN + i];
        __syncthreads();
        float acc[16];
#pragma unroll
        for (int n = 0; n < 16; ++n) acc[n] = bj;
#pragma unroll
        for (int k = 0; k < F_IN; ++k) {
#pragma unroll
            for (int n = 0; n < 16; ++n) acc[n] = fmaf(xs[n * F_IN + k], w[k], acc[n]);
        }
#pragma unroll
        for (int n = 0; n < 16; ++n)
            h[(size_t)(g * 16 + n) * HDIM + t] = fmaxf(acc[n], 0.f);
    }
}

// ---------------- CSR build ----------------
__global__ void hist_kernel(const int* __restrict__ dst, int* __restrict__ deg) {
    const int e = blockIdx.x * 256 + threadIdx.x;
    if (e < N_EDGES) atomicAdd(&deg[dst[e]], 1);
}

__global__ void scan1_kernel(const int* __restrict__ deg, int* __restrict__ row_ptr,
                             int* __restrict__ blk) {
    __shared__ int s[256];
    const int i = blockIdx.x * 256 + threadIdx.x;
    s[threadIdx.x] = (i < N_NODES) ? deg[i] : 0;
    __syncthreads();
    for (int off = 1; off < 256; off <<= 1) {
        int t = (threadIdx.x >= off) ? s[threadIdx.x - off] : 0;
        __syncthreads();
        s[threadIdx.x] += t;
        __syncthreads();
    }
    if (i < N_NODES) row_ptr[i + 1] = s[threadIdx.x];
    if (threadIdx.x == 255) blk[blockIdx.x] = s[255];
}

__global__ void scan2_kernel(int* __restrict__ blk, int nb) {
    if (threadIdx.x == 0 && blockIdx.x == 0) {
        int run = 0;
        for (int b = 0; b < nb; ++b) { const int t = blk[b]; blk[b] = run; run += t; }
    }
}

__global__ void scan3_kernel(int* __restrict__ row_ptr, const int* __restrict__ blk) {
    const int i = blockIdx.x * 256 + threadIdx.x;
    if (i < N_NODES) row_ptr[i + 1] += blk[i >> 8];
    if (i == 0) row_ptr[0] = 0;
}

__global__ void cursor_kernel(const int* __restrict__ row_ptr, int* __restrict__ cursor) {
    const int i = blockIdx.x * 256 + threadIdx.x;
    if (i < N_NODES) cursor[i] = row_ptr[i];
}

__global__ void fill_kernel(const int* __restrict__ src, const int* __restrict__ dst,
                            int* __restrict__ cursor, int* __restrict__ eids) {
    const int e = blockIdx.x * 256 + threadIdx.x;
    if (e < N_EDGES) {
        const int pos = atomicAdd(&cursor[dst[e]], 1);
        eids[pos] = src[e];
    }
}

// ------- segment sort: make eids order deterministic (kills atomic-fill nondeterminism) ----
// One thread per node; insertion sort its CSR segment (avg degree 2, Poisson tail small).
__global__ void sort_kernel(const int* __restrict__ row_ptr, int* __restrict__ eids) {
    const int n = blockIdx.x * 256 + threadIdx.x;
    if (n < N_NODES) {
        const int s = row_ptr[n], e = row_ptr[n + 1];
        for (int i = s + 1; i < e; ++i) {
            const int v = eids[i];
            int j = i - 1;
            while (j >= s && eids[j] > v) { eids[j + 1] = eids[j]; --j; }
            eids[j + 1] = v;
        }
    }
}

// ------- gather: z = h + sum_neigh h; write K-interleaved hi/lo bf16 [n][2*HDIM] -------
__global__ void gather_kernel(const float* __restrict__ h, const int* __restrict__ row_ptr,
                              const int* __restrict__ eids, unsigned short* __restrict__ z) {
    const int tid = threadIdx.x;
    const int n = blockIdx.x * 4 + (tid >> 6);
    const int t = tid & 63;
    const float4* h4 = (const float4*)h;
    float4 acc = h4[(size_t)n * 64 + t];
    const int s = row_ptr[n], e = row_ptr[n + 1];
    for (int i = s; i < e; ++i) {
        const float4 v = h4[(size_t)eids[i] * 64 + t];
        acc.x += v.x; acc.y += v.y; acc.z += v.z; acc.w += v.w;
    }
    uint4 pk;
    pk.x = packbf(acc.x); pk.y = packbf(acc.y);
    pk.z = packbf(acc.z); pk.w = packbf(acc.w);
    ((uint4*)(z + (size_t)n * 2 * HDIM))[t] = pk;
}

// ------- fused weight prep: all weights -> [N][K] packed (hi,lo)-uint, one dispatch -------
__global__ void wprep_all(const float* __restrict__ W1, const float* __restrict__ W2,
                          const float* __restrict__ Wf1, const float* __restrict__ Wf2,
                          unsigned int* __restrict__ t1, unsigned int* __restrict__ t2,
                          unsigned int* __restrict__ tf1, unsigned int* __restrict__ tf2) {
    const int WSZ = HDIM * 2 * HDIM;                 // 131072
    const int total = 8 * WSZ + HDIM * HDIM + HDIM * EDIM;
    const int stride = gridDim.x * 256;
    for (int idx = blockIdx.x * 256 + threadIdx.x; idx < total; idx += stride) {
        if (idx < 4 * WSZ) {                         // W1: K=256, N=512
            const int l = idx >> 17, e = idx & (WSZ - 1);
            const int k = e >> 9, n = e & 511;
            t1[(size_t)l * WSZ + n * HDIM + k] = packbf(W1[idx]);
        } else if (idx < 8 * WSZ) {                  // W2: K=512, N=256
            const int r = idx - 4 * WSZ;
            const int l = r >> 17, e = r & (WSZ - 1);
            const int k = e >> 8, n = e & 255;
            t2[(size_t)l * WSZ + n * EDIM + k] = packbf(W2[r]);
        } else if (idx < 8 * WSZ + HDIM * HDIM) {    // Wf1: K=256, N=256
            const int e = idx - 8 * WSZ;
            const int k = e >> 8, n = e & 255;
            tf1[n * HDIM + k] = packbf(Wf1[e]);
        } else {                                     // Wf2: K=256, N=512
            const int e = idx - 8 * WSZ - HDIM * HDIM;
            const int k = e >> 9, n = e & 511;
            tf2[n * HDIM + k] = packbf(Wf2[e]);
        }
    }
}

// ---------------- MFMA GEMM (m97 structure): C = act(A @ B + bias) ----------------
// A [M][KK] bf16 row-major, BT [N][KK] bf16. KK multiple of 64. N multiple of 128.
// 128x128 tile, BK=64, 4 waves (2x2 of 64x64), single-buffered LDS [128][64]us x2 (32KB),
// plain __syncthreads only (compiler schedules waitcnts - no inline asm, per m141 lesson).
// Granule XOR swizzle: 8 x 16B granules/row, phys = g ^ (row&7); staged by pre-swizzling
// the per-lane GLOBAL source (LDS dest stays linear for global_load_lds).
// OUT: 0 = fp32, 1 = fp32+relu, 2 = packed-uint hi/lo interleaved + relu
template <int OUT>
__global__ __launch_bounds__(256)
void gemm_mfma(const unsigned short* __restrict__ A, const unsigned short* __restrict__ BT,
               const float* __restrict__ bias, float* __restrict__ C,
               unsigned short* __restrict__ Z, int M, int N, int KK) {
    __shared__ __align__(16) unsigned short As[128 * 64];   // 16 KB
    __shared__ __align__(16) unsigned short Bs[128 * 64];   // 16 KB

    const int nrow = (M + 127) >> 7;
    const int G = gridDim.x;
    int wg = blockIdx.x;
    {   // bijective XCD remap (m204)
        const int q = G >> 3, r = G & 7;
        const int xx = wg & 7, o = wg >> 3;
        wg = (xx < r ? xx * (q + 1) : r * (q + 1) + (xx - r) * q) + o;
    }
    const int row0 = (wg % nrow) << 7;
    const int col0 = (wg / nrow) << 7;

    const int tid = threadIdx.x;
    const int lane = tid & 63;
    const int w = tid >> 6;
    const int wr = w >> 1, wc = w & 1;
    const int lr = lane & 15;
    const int l4 = lane >> 4;

    // staging geometry: per pass, thread covers row (pass*32 + tid>>3), phys granule tid&7.
    // source logical granule = (tid&7) ^ ((tid>>3)&7); LDS stays linear (slot = pass*256+tid).
    const int srow = tid >> 3;                              // 0..31
    const int sgran = ((tid & 7) ^ (srow & 7)) << 3;        // ushort offset within row

    floatx4 acc[4][4];
#pragma unroll
    for (int m = 0; m < 4; ++m)
#pragma unroll
        for (int n = 0; n < 4; ++n) acc[m][n] = (floatx4){0.f, 0.f, 0.f, 0.f};

    const int NT = KK >> 6;
    for (int t = 0; t < NT; ++t) {
        const int k0 = t << 6;
        __syncthreads();                 // previous tile fully consumed
#pragma unroll
        for (int pass = 0; pass < 4; ++pass) {
            const int r = (pass << 5) + srow;               // 0..127
            int ar = row0 + r; if (ar >= M) ar = M - 1;     // clamp
            gload16(A + (size_t)ar * KK + k0 + sgran, &As[(pass << 11) + (w << 9)]);
            gload16(BT + (size_t)(col0 + r) * KK + k0 + sgran, &Bs[(pass << 11) + (w << 9)]);
        }
        __syncthreads();                 // compiler inserts vmcnt drain before barrier

#pragma unroll
        for (int s = 0; s < 2; ++s) {
            const int pg = (((s << 2) + l4) ^ (lr & 7)) << 3;   // swizzled granule (ushorts)
            bhalf8 fa[4], fb[4];
#pragma unroll
            for (int m = 0; m < 4; ++m)
                fa[m] = *(const bhalf8*)&As[((wr << 6) + (m << 4) + lr) * 64 + pg];
#pragma unroll
            for (int n = 0; n < 4; ++n)
                fb[n] = *(const bhalf8*)&Bs[((wc << 6) + (n << 4) + lr) * 64 + pg];
#pragma unroll
            for (int m = 0; m < 4; ++m)
#pragma unroll
                for (int n = 0; n < 4; ++n)
                    acc[m][n] = __builtin_amdgcn_mfma_f32_16x16x32_bf16(fa[m], fb[n], acc[m][n], 0, 0, 0);
        }
    }

    // epilogue: C/D layout col = lane&15, row = (lane>>4)*4 + j
    const int rgrp = l4 * 4;
#pragma unroll
    for (int n = 0; n < 4; ++n) {
        const int col = col0 + (wc << 6) + (n << 4) + lr;
        const float bv = bias[col];
#pragma unroll
        for (int m = 0; m < 4; ++m) {
            const int rw = row0 + (wr << 6) + (m << 4) + rgrp;
#pragma unroll
            for (int j = 0; j < 4; ++j) {
                const int row = rw + j;
                if (row < M) {
                    float v = acc[m][n][j] + bv;
                    if (OUT >= 1) v = fmaxf(v, 0.f);
                    if (OUT == 2) {
                        ((unsigned int*)Z)[(size_t)row * N + col] = packbf(v);  // coalesced
                    } else {
                        C[(size_t)row * N + col] = v;
                    }
                }
            }
        }
    }
}

// ------- pool: sorted-batch segment mean -> K-interleaved hi/lo [g][2*HDIM] -------
__global__ void pool_kernel(const float* __restrict__ h, const int* __restrict__ batch,
                            unsigned short* __restrict__ gz) {
    __shared__ int sse[2];
    const int g = blockIdx.x;
    if (threadIdx.x < 2) {
        const int target = g + threadIdx.x;
        int lo = 0, hi = N_NODES;
        while (lo < hi) {
            const int mid = (lo + hi) >> 1;
            if (batch[mid] < target) lo = mid + 1; else hi = mid;
        }
        sse[threadIdx.x] = lo;
    }
    __syncthreads();
    const int s = sse[0], e = sse[1];
    const int j = threadIdx.x;
    float acc = 0.f;
    for (int n = s; n < e; ++n) acc += h[(size_t)n * HDIM + j];
    const float v = acc * ((e > s) ? 1.f / (float)(e - s) : 1.f);
    ((unsigned int*)gz)[(size_t)g * HDIM + j] = packbf(v);
}

extern "C" void kernel_launch(void* const* d_in, const int* in_sizes, int n_in,
                              void* d_out, int out_size, void* d_ws, size_t ws_size,
                              hipStream_t stream) {
    const float* x      = (const float*)d_in[0];
    const int*   eidx   = (const int*)d_in[1];
    const int*   batch  = (const int*)d_in[2];
    const float* W_atom = (const float*)d_in[3];
    const float* b_atom = (const float*)d_in[4];
    const float* W1     = (const float*)d_in[5];
    const float* b1     = (const float*)d_in[6];
    const float* W2     = (const float*)d_in[7];
    const float* b2     = (const float*)d_in[8];
    const float* Wf1    = (const float*)d_in[9];
    const float* bf1    = (const float*)d_in[10];
    const float* Wf2    = (const float*)d_in[11];
    const float* bf2    = (const float*)d_in[12];
    float* out = (float*)d_out;

    const int* src = eidx;
    const int* dst = eidx + N_EDGES;

    const size_t NH = (size_t)N_NODES * HDIM;           // 25.6M elems
    const int WSZ = HDIM * 2 * HDIM;                    // fp32 elems per layer weight

    // ---- workspace layout ----
    char* base = (char*)d_ws;
    size_t off = 0;
    float* h = (float*)(base + off);                        off += NH * 4;
    unsigned short* zin = (unsigned short*)(base + off);    off += NH * 2 * 2;  // [N][512]
    int* deg     = (int*)(base + off);            off += (size_t)N_NODES * 4;
    int* row_ptr = (int*)(base + off);            off += (size_t)(N_NODES + 1) * 4;
    int* cursor  = (int*)(base + off);            off += (size_t)N_NODES * 4;
    int* eids    = (int*)(base + off);            off += (size_t)N_EDGES * 4;
    int* blk     = (int*)(base + off);            off += 512 * 4;
    off = (off + 255) & ~(size_t)255;
    unsigned short* t1 = (unsigned short*)(base + off); off += (size_t)NLAYERS * WSZ * 2 * 2;
    unsigned short* t2 = (unsigned short*)(base + off); off += (size_t)NLAYERS * WSZ * 2 * 2;
    unsigned short* tf1 = (unsigned short*)(base + off); off += (size_t)HDIM * HDIM * 2 * 2;
    unsigned short* tf2 = (unsigned short*)(base + off); off += (size_t)HDIM * EDIM * 2 * 2;
    off = (off + 255) & ~(size_t)255;

    const size_t avail = (ws_size > off) ? ws_size - off : 0;
    long chunk = (long)(avail / ((size_t)EDIM * 2 * 2));   // z2 row = 2*EDIM ushorts
    if (chunk > 50048) chunk = 50048;                      // 2 chunks; z2 L3-resident
    if (chunk >= N_NODES) chunk = N_NODES;
    else chunk &= ~127L;
    if (chunk < 128) chunk = 128;
    unsigned short* z2 = (unsigned short*)(base + off);    // [chunk][1024]

    // head buffers overlap the (dead-after-layers) zin region
    const size_t GH2 = (size_t)N_GRAPHS * 2 * HDIM;
    unsigned short* hg  = zin;            // [4000][512]
    unsigned short* hg1 = zin + GH2;      // [4000][512]

    const int nb = (N_NODES + 255) / 256;
    const int T1SZ = 2 * WSZ;
    const int T2SZ = 2 * WSZ;

    // 1. atom MLP (W in VGPRs, grid-stride groups of 16 nodes)
    atom_kernel<<<1024, 256, 0, stream>>>(x, W_atom, b_atom, h);

    // 2. CSR build (+ deterministic segment sort)
    zero_kernel<<<128, 256, 0, stream>>>((float*)deg, N_NODES / 4);
    hist_kernel<<<(N_EDGES + 255) / 256, 256, 0, stream>>>(dst, deg);
    scan1_kernel<<<nb, 256, 0, stream>>>(deg, row_ptr, blk);
    scan2_kernel<<<1, 64, 0, stream>>>(blk, nb);
    scan3_kernel<<<nb, 256, 0, stream>>>(row_ptr, blk);
    cursor_kernel<<<nb, 256, 0, stream>>>(row_ptr, cursor);
    fill_kernel<<<(N_EDGES + 255) / 256, 256, 0, stream>>>(src, dst, cursor, eids);
    sort_kernel<<<nb, 256, 0, stream>>>(row_ptr, eids);   // deterministic gather order

    // 3. fused weight transpose + K-interleaved bf16 split (one dispatch)
    wprep_all<<<1024, 256, 0, stream>>>(W1, W2, Wf1, Wf2,
        (unsigned int*)t1, (unsigned int*)t2, (unsigned int*)tf1, (unsigned int*)tf2);

    // 4. GIN layers
    for (int l = 0; l < NLAYERS; ++l) {
        gather_kernel<<<N_NODES / 4, 256, 0, stream>>>(h, row_ptr, eids, zin);
        for (long r0 = 0; r0 < N_NODES; r0 += chunk) {
            const int mc = (int)((N_NODES - r0 < chunk) ? (N_NODES - r0) : chunk);
            const int nrow1 = (mc + 127) / 128;
            // z2 = relu(zin @ W1[l] + b1[l])  [mc, 512] -> interleaved bf16 [mc][1024]
            gemm_mfma<2><<<4 * nrow1, 256, 0, stream>>>(
                zin + (size_t)r0 * 2 * HDIM, t1 + (size_t)l * T1SZ,
                b1 + (size_t)l * 2 * HDIM, nullptr, z2, mc, 2 * HDIM, 2 * HDIM);
            // h = relu(z2 @ W2[l] + b2[l])    [mc, 256] -> fp32
            gemm_mfma<1><<<2 * nrow1, 256, 0, stream>>>(
                z2, t2 + (size_t)l * T2SZ,
                b2 + (size_t)l * HDIM, h + (size_t)r0 * HDIM, nullptr, mc, HDIM, 4 * HDIM);
        }
    }

    // 5. pool (interleaved split write)
    pool_kernel<<<N_GRAPHS, HDIM, 0, stream>>>(h, batch, hg);

    // 6. head
    gemm_mfma<2><<<2 * ((N_GRAPHS + 127) / 128), 256, 0, stream>>>(
        hg, tf1, bf1, nullptr, hg1, N_GRAPHS, HDIM, 2 * HDIM);
    gemm_mfma<0><<<4 * ((N_GRAPHS + 127) / 128), 256, 0, stream>>>(
        hg1, tf2, bf2, out, nullptr, N_GRAPHS, EDIM, 2 * HDIM);
}

// Round 12
// 1121.137 us; speedup vs baseline: 1.7624x; 1.4184x over previous
//
#include <hip/hip_runtime.h>

#define N_NODES 100000
#define N_EDGES 200000
#define N_GRAPHS 4000
#define F_IN 44
#define HDIM 256
#define EDIM 512
#define NLAYERS 4

typedef float floatx4 __attribute__((ext_vector_type(4)));
typedef short bhalf8 __attribute__((ext_vector_type(8)));

__device__ __forceinline__ unsigned short f2bf(float f) {
    unsigned int u = __float_as_uint(f);
    u += 0x7FFFu + ((u >> 16) & 1u);          // RNE
    return (unsigned short)(u >> 16);
}

// async global->LDS, 16B/lane. ldst wave-uniform base; gsrc per-lane.
__device__ __forceinline__ void gload16(const void* gsrc, void* ldst) {
    __builtin_amdgcn_global_load_lds(
        (const __attribute__((address_space(1))) void*)gsrc,
        (__attribute__((address_space(3))) void*)ldst, 16, 0, 0);
}

// ---------------- zero fill ----------------
__global__ void zero_kernel(float* __restrict__ p, size_t n4) {
    size_t i = (size_t)blockIdx.x * blockDim.x + threadIdx.x;
    const size_t stride = (size_t)gridDim.x * blockDim.x;
    const float4 z = make_float4(0.f, 0.f, 0.f, 0.f);
    for (; i < n4; i += stride) ((float4*)p)[i] = z;
}

// -------- atom MLP: h = relu(x @ W_atom + b_atom). W column in VGPRs, 16 nodes/group ------
__global__ __launch_bounds__(256) void atom_kernel(const float* __restrict__ x,
                                                   const float* __restrict__ W,
                                                   const float* __restrict__ b,
                                                   float* __restrict__ h) {
    const int t = threadIdx.x;
    float w[F_IN];
#pragma unroll
    for (int k = 0; k < F_IN; ++k) w[k] = W[k * HDIM + t];   // coalesced, once
    const float bj = b[t];
    __shared__ float xs[16 * F_IN];      // 2.8 KB broadcast buffer
    const int NG = N_NODES / 16;         // 6250
    for (int g = blockIdx.x; g < NG; g += gridDim.x) {
        __syncthreads();                 // protect xs from previous readers
        for (int i = t; i < 16 * F_IN; i += 256) xs[i] = x[(size_t)g * 16 * F_IN + i];
        __syncthreads();
        float acc[16];
#pragma unroll
        for (int n = 0; n < 16; ++n) acc[n] = bj;
#pragma unroll
        for (int k = 0; k < F_IN; ++k) {
#pragma unroll
            for (int n = 0; n < 16; ++n) acc[n] = fmaf(xs[n * F_IN + k], w[k], acc[n]);
        }
#pragma unroll
        for (int n = 0; n < 16; ++n)
            h[(size_t)(g * 16 + n) * HDIM + t] = fmaxf(acc[n], 0.f);
    }
}

// ---------------- CSR build ----------------
__global__ void hist_kernel(const int* __restrict__ dst, int* __restrict__ deg) {
    const int e = blockIdx.x * 256 + threadIdx.x;
    if (e < N_EDGES) atomicAdd(&deg[dst[e]], 1);
}

__global__ void scan1_kernel(const int* __restrict__ deg, int* __restrict__ row_ptr,
                             int* __restrict__ blk) {
    __shared__ int s[256];
    const int i = blockIdx.x * 256 + threadIdx.x;
    s[threadIdx.x] = (i < N_NODES) ? deg[i] : 0;
    __syncthreads();
    for (int off = 1; off < 256; off <<= 1) {
        int t = (threadIdx.x >= off) ? s[threadIdx.x - off] : 0;
        __syncthreads();
        s[threadIdx.x] += t;
        __syncthreads();
    }
    if (i < N_NODES) row_ptr[i + 1] = s[threadIdx.x];
    if (threadIdx.x == 255) blk[blockIdx.x] = s[255];
}

__global__ void scan2_kernel(int* __restrict__ blk, int nb) {
    if (threadIdx.x == 0 && blockIdx.x == 0) {
        int run = 0;
        for (int b = 0; b < nb; ++b) { const int t = blk[b]; blk[b] = run; run += t; }
    }
}

__global__ void scan3_kernel(int* __restrict__ row_ptr, const int* __restrict__ blk) {
    const int i = blockIdx.x * 256 + threadIdx.x;
    if (i < N_NODES) row_ptr[i + 1] += blk[i >> 8];
    if (i == 0) row_ptr[0] = 0;
}

__global__ void cursor_kernel(const int* __restrict__ row_ptr, int* __restrict__ cursor) {
    const int i = blockIdx.x * 256 + threadIdx.x;
    if (i < N_NODES) cursor[i] = row_ptr[i];
}

__global__ void fill_kernel(const int* __restrict__ src, const int* __restrict__ dst,
                            int* __restrict__ cursor, int* __restrict__ eids) {
    const int e = blockIdx.x * 256 + threadIdx.x;
    if (e < N_EDGES) {
        const int pos = atomicAdd(&cursor[dst[e]], 1);
        eids[pos] = src[e];
    }
}

// ------- segment sort: deterministic eids order (replay-stable fp32 sums) -------
__global__ void sort_kernel(const int* __restrict__ row_ptr, int* __restrict__ eids) {
    const int n = blockIdx.x * 256 + threadIdx.x;
    if (n < N_NODES) {
        const int s = row_ptr[n], e = row_ptr[n + 1];
        for (int i = s + 1; i < e; ++i) {
            const int v = eids[i];
            int j = i - 1;
            while (j >= s && eids[j] > v) { eids[j + 1] = eids[j]; --j; }
            eids[j + 1] = v;
        }
    }
}

// ------- gather: z = h + sum_neigh h; write bf16 [n][HDIM] -------
__global__ void gather_kernel(const float* __restrict__ h, const int* __restrict__ row_ptr,
                              const int* __restrict__ eids, unsigned short* __restrict__ z) {
    const int tid = threadIdx.x;
    const int n = blockIdx.x * 4 + (tid >> 6);
    const int t = tid & 63;
    const float4* h4 = (const float4*)h;
    float4 acc = h4[(size_t)n * 64 + t];
    const int s = row_ptr[n], e = row_ptr[n + 1];
    for (int i = s; i < e; ++i) {
        const float4 v = h4[(size_t)eids[i] * 64 + t];
        acc.x += v.x; acc.y += v.y; acc.z += v.z; acc.w += v.w;
    }
    ushort4 pk;
    pk.x = f2bf(acc.x); pk.y = f2bf(acc.y);
    pk.z = f2bf(acc.z); pk.w = f2bf(acc.w);
    ((ushort4*)(z + (size_t)n * HDIM))[t] = pk;
}

// ------- fused weight prep: all weights -> transposed [N][K] bf16, one dispatch -------
__global__ void wprep_all(const float* __restrict__ W1, const float* __restrict__ W2,
                          const float* __restrict__ Wf1, const float* __restrict__ Wf2,
                          unsigned short* __restrict__ t1, unsigned short* __restrict__ t2,
                          unsigned short* __restrict__ tf1, unsigned short* __restrict__ tf2) {
    const int WSZ = HDIM * 2 * HDIM;                 // 131072
    const int total = 8 * WSZ + HDIM * HDIM + HDIM * EDIM;
    const int stride = gridDim.x * 256;
    for (int idx = blockIdx.x * 256 + threadIdx.x; idx < total; idx += stride) {
        if (idx < 4 * WSZ) {                         // W1: K=256, N=512 -> t1 [512][256]
            const int l = idx >> 17, e = idx & (WSZ - 1);
            const int k = e >> 9, n = e & 511;
            t1[(size_t)l * WSZ + n * HDIM + k] = f2bf(W1[idx]);
        } else if (idx < 8 * WSZ) {                  // W2: K=512, N=256 -> t2 [256][512]
            const int r = idx - 4 * WSZ;
            const int l = r >> 17, e = r & (WSZ - 1);
            const int k = e >> 8, n = e & 255;
            t2[(size_t)l * WSZ + n * EDIM + k] = f2bf(W2[r]);
        } else if (idx < 8 * WSZ + HDIM * HDIM) {    // Wf1 -> tf1 [256][256]
            const int e = idx - 8 * WSZ;
            const int k = e >> 8, n = e & 255;
            tf1[n * HDIM + k] = f2bf(Wf1[e]);
        } else {                                     // Wf2: K=256, N=512 -> tf2 [512][256]
            const int e = idx - 8 * WSZ - HDIM * HDIM;
            const int k = e >> 9, n = e & 511;
            tf2[n * HDIM + k] = f2bf(Wf2[e]);
        }
    }
}

// ---------------- MFMA GEMM (m97 structure): C = act(A @ B + bias) ----------------
// A [M][KK] bf16 row-major, BT [N][KK] bf16. KK multiple of 64. N multiple of 128.
// 128x128 tile, BK=64, 4 waves (2x2 of 64x64), single-buffered LDS [128][64]us x2 (32KB),
// plain __syncthreads only (compiler schedules waitcnts - no inline asm, per m141 lesson).
// Granule XOR swizzle: 8 x 16B granules/row, phys = g ^ (row&7); staged by pre-swizzling
// the per-lane GLOBAL source (LDS dest stays linear for global_load_lds).
// OUT: 0 = fp32, 1 = fp32+relu, 2 = bf16 + relu
template <int OUT>
__global__ __launch_bounds__(256)
void gemm_mfma(const unsigned short* __restrict__ A, const unsigned short* __restrict__ BT,
               const float* __restrict__ bias, float* __restrict__ C,
               unsigned short* __restrict__ Z, int M, int N, int KK) {
    __shared__ __align__(16) unsigned short As[128 * 64];   // 16 KB
    __shared__ __align__(16) unsigned short Bs[128 * 64];   // 16 KB

    const int nrow = (M + 127) >> 7;
    const int G = gridDim.x;
    int wg = blockIdx.x;
    {   // bijective XCD remap (m204)
        const int q = G >> 3, r = G & 7;
        const int xx = wg & 7, o = wg >> 3;
        wg = (xx < r ? xx * (q + 1) : r * (q + 1) + (xx - r) * q) + o;
    }
    const int row0 = (wg % nrow) << 7;
    const int col0 = (wg / nrow) << 7;

    const int tid = threadIdx.x;
    const int lane = tid & 63;
    const int w = tid >> 6;
    const int wr = w >> 1, wc = w & 1;
    const int lr = lane & 15;
    const int l4 = lane >> 4;

    // staging geometry: per pass, thread covers row (pass*32 + tid>>3), phys granule tid&7.
    // source logical granule = (tid&7) ^ ((tid>>3)&7); LDS stays linear (slot = pass*256+tid).
    const int srow = tid >> 3;                              // 0..31
    const int sgran = ((tid & 7) ^ (srow & 7)) << 3;        // ushort offset within row

    floatx4 acc[4][4];
#pragma unroll
    for (int m = 0; m < 4; ++m)
#pragma unroll
        for (int n = 0; n < 4; ++n) acc[m][n] = (floatx4){0.f, 0.f, 0.f, 0.f};

    const int NT = KK >> 6;
    for (int t = 0; t < NT; ++t) {
        const int k0 = t << 6;
        __syncthreads();                 // previous tile fully consumed
#pragma unroll
        for (int pass = 0; pass < 4; ++pass) {
            const int r = (pass << 5) + srow;               // 0..127
            int ar = row0 + r; if (ar >= M) ar = M - 1;     // clamp
            gload16(A + (size_t)ar * KK + k0 + sgran, &As[(pass << 11) + (w << 9)]);
            gload16(BT + (size_t)(col0 + r) * KK + k0 + sgran, &Bs[(pass << 11) + (w << 9)]);
        }
        __syncthreads();                 // compiler inserts vmcnt drain before barrier

#pragma unroll
        for (int s = 0; s < 2; ++s) {
            const int pg = (((s << 2) + l4) ^ (lr & 7)) << 3;   // swizzled granule (ushorts)
            bhalf8 fa[4], fb[4];
#pragma unroll
            for (int m = 0; m < 4; ++m)
                fa[m] = *(const bhalf8*)&As[((wr << 6) + (m << 4) + lr) * 64 + pg];
#pragma unroll
            for (int n = 0; n < 4; ++n)
                fb[n] = *(const bhalf8*)&Bs[((wc << 6) + (n << 4) + lr) * 64 + pg];
#pragma unroll
            for (int m = 0; m < 4; ++m)
#pragma unroll
                for (int n = 0; n < 4; ++n)
                    acc[m][n] = __builtin_amdgcn_mfma_f32_16x16x32_bf16(fa[m], fb[n], acc[m][n], 0, 0, 0);
        }
    }

    // epilogue: C/D layout col = lane&15, row = (lane>>4)*4 + j
    const int rgrp = l4 * 4;
#pragma unroll
    for (int n = 0; n < 4; ++n) {
        const int col = col0 + (wc << 6) + (n << 4) + lr;
        const float bv = bias[col];
#pragma unroll
        for (int m = 0; m < 4; ++m) {
            const int rw = row0 + (wr << 6) + (m << 4) + rgrp;
#pragma unroll
            for (int j = 0; j < 4; ++j) {
                const int row = rw + j;
                if (row < M) {
                    float v = acc[m][n][j] + bv;
                    if (OUT >= 1) v = fmaxf(v, 0.f);
                    if (OUT == 2) {
                        Z[(size_t)row * N + col] = f2bf(v);
                    } else {
                        C[(size_t)row * N + col] = v;
                    }
                }
            }
        }
    }
}

// ------- pool: sorted-batch segment mean -> bf16 [g][HDIM] -------
__global__ void pool_kernel(const float* __restrict__ h, const int* __restrict__ batch,
                            unsigned short* __restrict__ gz) {
    __shared__ int sse[2];
    const int g = blockIdx.x;
    if (threadIdx.x < 2) {
        const int target = g + threadIdx.x;
        int lo = 0, hi = N_NODES;
        while (lo < hi) {
            const int mid = (lo + hi) >> 1;
            if (batch[mid] < target) lo = mid + 1; else hi = mid;
        }
        sse[threadIdx.x] = lo;
    }
    __syncthreads();
    const int s = sse[0], e = sse[1];
    const int j = threadIdx.x;
    float acc = 0.f;
    for (int n = s; n < e; ++n) acc += h[(size_t)n * HDIM + j];
    const float v = acc * ((e > s) ? 1.f / (float)(e - s) : 1.f);
    gz[(size_t)g * HDIM + j] = f2bf(v);
}

extern "C" void kernel_launch(void* const* d_in, const int* in_sizes, int n_in,
                              void* d_out, int out_size, void* d_ws, size_t ws_size,
                              hipStream_t stream) {
    const float* x      = (const float*)d_in[0];
    const int*   eidx   = (const int*)d_in[1];
    const int*   batch  = (const int*)d_in[2];
    const float* W_atom = (const float*)d_in[3];
    const float* b_atom = (const float*)d_in[4];
    const float* W1     = (const float*)d_in[5];
    const float* b1     = (const float*)d_in[6];
    const float* W2     = (const float*)d_in[7];
    const float* b2     = (const float*)d_in[8];
    const float* Wf1    = (const float*)d_in[9];
    const float* bf1    = (const float*)d_in[10];
    const float* Wf2    = (const float*)d_in[11];
    const float* bf2    = (const float*)d_in[12];
    float* out = (float*)d_out;

    const int* src = eidx;
    const int* dst = eidx + N_EDGES;

    const size_t NH = (size_t)N_NODES * HDIM;           // 25.6M elems
    const int WSZ = HDIM * 2 * HDIM;                    // 131072 elems per layer weight

    // ---- workspace layout ----
    char* base = (char*)d_ws;
    size_t off = 0;
    float* h = (float*)(base + off);                        off += NH * 4;
    unsigned short* zin = (unsigned short*)(base + off);    off += NH * 2;  // bf16 [N][256]
    int* deg     = (int*)(base + off);            off += (size_t)N_NODES * 4;
    int* row_ptr = (int*)(base + off);            off += (size_t)(N_NODES + 1) * 4;
    int* cursor  = (int*)(base + off);            off += (size_t)N_NODES * 4;
    int* eids    = (int*)(base + off);            off += (size_t)N_EDGES * 4;
    int* blk     = (int*)(base + off);            off += 512 * 4;
    off = (off + 255) & ~(size_t)255;
    unsigned short* t1 = (unsigned short*)(base + off); off += (size_t)NLAYERS * WSZ * 2;
    unsigned short* t2 = (unsigned short*)(base + off); off += (size_t)NLAYERS * WSZ * 2;
    unsigned short* tf1 = (unsigned short*)(base + off); off += (size_t)HDIM * HDIM * 2;
    unsigned short* tf2 = (unsigned short*)(base + off); off += (size_t)HDIM * EDIM * 2;
    off = (off + 255) & ~(size_t)255;

    const size_t avail = (ws_size > off) ? ws_size - off : 0;
    long chunk = (long)(avail / ((size_t)EDIM * 2));       // z2 row = 512 bf16 = 1 KB
    if (chunk > 50048) chunk = 50048;                      // 2 chunks; z2 ~51MB L3-resident
    if (chunk >= N_NODES) chunk = N_NODES;
    else chunk &= ~127L;
    if (chunk < 128) chunk = 128;
    unsigned short* z2 = (unsigned short*)(base + off);    // [chunk][512] bf16

    // head buffers overlap the (dead-after-layers) zin region
    const size_t GH = (size_t)N_GRAPHS * HDIM;
    unsigned short* hg  = zin;            // [4000][256] bf16
    unsigned short* hg1 = zin + GH;       // [4000][256] bf16

    const int nb = (N_NODES + 255) / 256;

    // 1. atom MLP (W in VGPRs, grid-stride groups of 16 nodes)
    atom_kernel<<<1024, 256, 0, stream>>>(x, W_atom, b_atom, h);

    // 2. CSR build (+ deterministic segment sort)
    zero_kernel<<<128, 256, 0, stream>>>((float*)deg, N_NODES / 4);
    hist_kernel<<<(N_EDGES + 255) / 256, 256, 0, stream>>>(dst, deg);
    scan1_kernel<<<nb, 256, 0, stream>>>(deg, row_ptr, blk);
    scan2_kernel<<<1, 64, 0, stream>>>(blk, nb);
    scan3_kernel<<<nb, 256, 0, stream>>>(row_ptr, blk);
    cursor_kernel<<<nb, 256, 0, stream>>>(row_ptr, cursor);
    fill_kernel<<<(N_EDGES + 255) / 256, 256, 0, stream>>>(src, dst, cursor, eids);
    sort_kernel<<<nb, 256, 0, stream>>>(row_ptr, eids);   // deterministic gather order

    // 3. fused weight transpose + bf16 cast (one dispatch)
    wprep_all<<<1024, 256, 0, stream>>>(W1, W2, Wf1, Wf2, t1, t2, tf1, tf2);

    // 4. GIN layers
    for (int l = 0; l < NLAYERS; ++l) {
        gather_kernel<<<N_NODES / 4, 256, 0, stream>>>(h, row_ptr, eids, zin);
        for (long r0 = 0; r0 < N_NODES; r0 += chunk) {
            const int mc = (int)((N_NODES - r0 < chunk) ? (N_NODES - r0) : chunk);
            const int nrow1 = (mc + 127) / 128;
            // z2 = relu(zin @ W1[l] + b1[l])  [mc, 512] -> bf16
            gemm_mfma<2><<<4 * nrow1, 256, 0, stream>>>(
                zin + (size_t)r0 * HDIM, t1 + (size_t)l * WSZ,
                b1 + (size_t)l * 2 * HDIM, nullptr, z2, mc, 2 * HDIM, HDIM);
            // h = relu(z2 @ W2[l] + b2[l])    [mc, 256] -> fp32
            gemm_mfma<1><<<2 * nrow1, 256, 0, stream>>>(
                z2, t2 + (size_t)l * WSZ,
                b2 + (size_t)l * HDIM, h + (size_t)r0 * HDIM, nullptr, mc, HDIM, 2 * HDIM);
        }
    }

    // 5. pool (bf16 write)
    pool_kernel<<<N_GRAPHS, HDIM, 0, stream>>>(h, batch, hg);

    // 6. head
    gemm_mfma<2><<<2 * ((N_GRAPHS + 127) / 128), 256, 0, stream>>>(
        hg, tf1, bf1, nullptr, hg1, N_GRAPHS, HDIM, HDIM);
    gemm_mfma<0><<<4 * ((N_GRAPHS + 127) / 128), 256, 0, stream>>>(
        hg1, tf2, bf2, out, nullptr, N_GRAPHS, EDIM, HDIM);
}

// Round 13
// 1080.557 us; speedup vs baseline: 1.8286x; 1.0376x over previous
//
#include <hip/hip_runtime.h>

#define N_NODES 100000
#define N_EDGES 200000
#define N_GRAPHS 4000
#define F_IN 44
#define HDIM 256
#define EDIM 512
#define NLAYERS 4

typedef float floatx4 __attribute__((ext_vector_type(4)));
typedef short bhalf8 __attribute__((ext_vector_type(8)));

__device__ __forceinline__ unsigned short f2bf(float f) {
    unsigned int u = __float_as_uint(f);
    u += 0x7FFFu + ((u >> 16) & 1u);          // RNE
    return (unsigned short)(u >> 16);
}

// async global->LDS, 16B/lane. ldst wave-uniform base; gsrc per-lane.
__device__ __forceinline__ void gload16(const void* gsrc, void* ldst) {
    __builtin_amdgcn_global_load_lds(
        (const __attribute__((address_space(1))) void*)gsrc,
        (__attribute__((address_space(3))) void*)ldst, 16, 0, 0);
}

// ---------------- zero fill ----------------
__global__ void zero_kernel(float* __restrict__ p, size_t n4) {
    size_t i = (size_t)blockIdx.x * blockDim.x + threadIdx.x;
    const size_t stride = (size_t)gridDim.x * blockDim.x;
    const float4 z = make_float4(0.f, 0.f, 0.f, 0.f);
    for (; i < n4; i += stride) ((float4*)p)[i] = z;
}

// -------- atom MLP: h = relu(x @ W_atom + b_atom). W col in VGPRs; x via scalar loads ------
__global__ __launch_bounds__(256) void atom_kernel(const float* __restrict__ x,
                                                   const float* __restrict__ W,
                                                   const float* __restrict__ b,
                                                   float* __restrict__ h) {
    const int t = threadIdx.x;
    float w[F_IN];
#pragma unroll
    for (int k = 0; k < F_IN; ++k) w[k] = W[k * HDIM + t];   // coalesced, once
    const float bj = b[t];
    const int NG = N_NODES / 16;         // 6250
    for (int g = blockIdx.x; g < NG; g += gridDim.x) {
        const float* xg = x + (size_t)g * 16 * F_IN;   // wave-uniform -> s_load path
        float acc[16];
#pragma unroll
        for (int n = 0; n < 16; ++n) acc[n] = bj;
#pragma unroll
        for (int k = 0; k < F_IN; ++k) {
#pragma unroll
            for (int n = 0; n < 16; ++n) acc[n] = fmaf(xg[n * F_IN + k], w[k], acc[n]);
        }
#pragma unroll
        for (int n = 0; n < 16; ++n)
            h[(size_t)(g * 16 + n) * HDIM + t] = fmaxf(acc[n], 0.f);
    }
}

// ---------------- CSR build ----------------
__global__ void hist_kernel(const int* __restrict__ dst, int* __restrict__ deg) {
    const int e = blockIdx.x * 256 + threadIdx.x;
    if (e < N_EDGES) atomicAdd(&deg[dst[e]], 1);
}

__global__ void scan1_kernel(const int* __restrict__ deg, int* __restrict__ row_ptr,
                             int* __restrict__ blk) {
    __shared__ int s[256];
    const int i = blockIdx.x * 256 + threadIdx.x;
    s[threadIdx.x] = (i < N_NODES) ? deg[i] : 0;
    __syncthreads();
    for (int off = 1; off < 256; off <<= 1) {
        int t = (threadIdx.x >= off) ? s[threadIdx.x - off] : 0;
        __syncthreads();
        s[threadIdx.x] += t;
        __syncthreads();
    }
    if (i < N_NODES) row_ptr[i + 1] = s[threadIdx.x];
    if (threadIdx.x == 255) blk[blockIdx.x] = s[255];
}

__global__ void scan2_kernel(int* __restrict__ blk, int nb) {
    if (threadIdx.x == 0 && blockIdx.x == 0) {
        int run = 0;
        for (int b = 0; b < nb; ++b) { const int t = blk[b]; blk[b] = run; run += t; }
    }
}

__global__ void scan3_kernel(int* __restrict__ row_ptr, const int* __restrict__ blk) {
    const int i = blockIdx.x * 256 + threadIdx.x;
    if (i < N_NODES) row_ptr[i + 1] += blk[i >> 8];
    if (i == 0) row_ptr[0] = 0;
}

__global__ void cursor_kernel(const int* __restrict__ row_ptr, int* __restrict__ cursor) {
    const int i = blockIdx.x * 256 + threadIdx.x;
    if (i < N_NODES) cursor[i] = row_ptr[i];
}

__global__ void fill_kernel(const int* __restrict__ src, const int* __restrict__ dst,
                            int* __restrict__ cursor, int* __restrict__ eids) {
    const int e = blockIdx.x * 256 + threadIdx.x;
    if (e < N_EDGES) {
        const int pos = atomicAdd(&cursor[dst[e]], 1);
        eids[pos] = src[e];
    }
}

// ------- segment sort: deterministic eids order (replay-stable fp32 sums) -------
__global__ void sort_kernel(const int* __restrict__ row_ptr, int* __restrict__ eids) {
    const int n = blockIdx.x * 256 + threadIdx.x;
    if (n < N_NODES) {
        const int s = row_ptr[n], e = row_ptr[n + 1];
        for (int i = s + 1; i < e; ++i) {
            const int v = eids[i];
            int j = i - 1;
            while (j >= s && eids[j] > v) { eids[j + 1] = eids[j]; --j; }
            eids[j + 1] = v;
        }
    }
}

// ------- gather: z = h + sum_neigh h; write bf16 [n][HDIM] -------
__global__ void gather_kernel(const float* __restrict__ h, const int* __restrict__ row_ptr,
                              const int* __restrict__ eids, unsigned short* __restrict__ z) {
    const int tid = threadIdx.x;
    const int n = blockIdx.x * 4 + (tid >> 6);
    const int t = tid & 63;
    const float4* h4 = (const float4*)h;
    float4 acc = h4[(size_t)n * 64 + t];
    const int s = row_ptr[n], e = row_ptr[n + 1];
    for (int i = s; i < e; ++i) {
        const float4 v = h4[(size_t)eids[i] * 64 + t];
        acc.x += v.x; acc.y += v.y; acc.z += v.z; acc.w += v.w;
    }
    ushort4 pk;
    pk.x = f2bf(acc.x); pk.y = f2bf(acc.y);
    pk.z = f2bf(acc.z); pk.w = f2bf(acc.w);
    ((ushort4*)(z + (size_t)n * HDIM))[t] = pk;
}

// ------- fused weight prep: all weights -> transposed [N][K] bf16, one dispatch -------
__global__ void wprep_all(const float* __restrict__ W1, const float* __restrict__ W2,
                          const float* __restrict__ Wf1, const float* __restrict__ Wf2,
                          unsigned short* __restrict__ t1, unsigned short* __restrict__ t2,
                          unsigned short* __restrict__ tf1, unsigned short* __restrict__ tf2) {
    const int WSZ = HDIM * 2 * HDIM;                 // 131072
    const int total = 8 * WSZ + HDIM * HDIM + HDIM * EDIM;
    const int stride = gridDim.x * 256;
    for (int idx = blockIdx.x * 256 + threadIdx.x; idx < total; idx += stride) {
        if (idx < 4 * WSZ) {                         // W1: K=256, N=512 -> t1 [512][256]
            const int l = idx >> 17, e = idx & (WSZ - 1);
            const int k = e >> 9, n = e & 511;
            t1[(size_t)l * WSZ + n * HDIM + k] = f2bf(W1[idx]);
        } else if (idx < 8 * WSZ) {                  // W2: K=512, N=256 -> t2 [256][512]
            const int r = idx - 4 * WSZ;
            const int l = r >> 17, e = r & (WSZ - 1);
            const int k = e >> 8, n = e & 255;
            t2[(size_t)l * WSZ + n * EDIM + k] = f2bf(W2[r]);
        } else if (idx < 8 * WSZ + HDIM * HDIM) {    // Wf1 -> tf1 [256][256]
            const int e = idx - 8 * WSZ;
            const int k = e >> 8, n = e & 255;
            tf1[n * HDIM + k] = f2bf(Wf1[e]);
        } else {                                     // Wf2: K=256, N=512 -> tf2 [512][256]
            const int e = idx - 8 * WSZ - HDIM * HDIM;
            const int k = e >> 9, n = e & 511;
            tf2[n * HDIM + k] = f2bf(Wf2[e]);
        }
    }
}

// ---------------- MFMA GEMM (m97 structure): C = act(A @ B + bias) ----------------
// A [M][KK] bf16 row-major, BT [N][KK] bf16. KK multiple of 64. N multiple of 128.
// 128x128 tile, BK=64, 4 waves (2x2 of 64x64), single-buffered LDS [128][64]us x2 (32KB),
// plain __syncthreads only (compiler schedules waitcnts - no inline asm, per m141 lesson).
// Granule XOR swizzle: 8 x 16B granules/row, phys = g ^ (row&7); staged by pre-swizzling
// the per-lane GLOBAL source (LDS dest stays linear for global_load_lds).
// OUT: 0 = fp32, 1 = fp32+relu, 2 = bf16+relu via LDS-staged COALESCED writes
//   (direct 2B stores are 32B/quarter-wave = half-sector RMW -> 2.3x write amplification,
//    measured r12: WRITE 115MB vs 51MB ideal. LDS re-stage + uint4 row copies fix it.)
template <int OUT>
__global__ __launch_bounds__(256)
void gemm_mfma(const unsigned short* __restrict__ A, const unsigned short* __restrict__ BT,
               const float* __restrict__ bias, float* __restrict__ C,
               unsigned short* __restrict__ Z, int M, int N, int KK) {
    // As = lds_all[0..8191], Bs = lds_all[8192..16383];
    // OUT=2 epilogue reuses lds_all as padded bf16 tile [128][136] (17408 us = 34 KB).
    __shared__ __align__(16) unsigned short lds_all[17408];
    unsigned short* As = lds_all;
    unsigned short* Bs = lds_all + 8192;

    const int nrow = (M + 127) >> 7;
    const int G = gridDim.x;
    int wg = blockIdx.x;
    {   // bijective XCD remap (m204)
        const int q = G >> 3, r = G & 7;
        const int xx = wg & 7, o = wg >> 3;
        wg = (xx < r ? xx * (q + 1) : r * (q + 1) + (xx - r) * q) + o;
    }
    const int row0 = (wg % nrow) << 7;
    const int col0 = (wg / nrow) << 7;

    const int tid = threadIdx.x;
    const int lane = tid & 63;
    const int w = tid >> 6;
    const int wr = w >> 1, wc = w & 1;
    const int lr = lane & 15;
    const int l4 = lane >> 4;

    // staging geometry: per pass, thread covers row (pass*32 + tid>>3), phys granule tid&7.
    // source logical granule = (tid&7) ^ ((tid>>3)&7); LDS stays linear (slot = pass*256+tid).
    const int srow = tid >> 3;                              // 0..31
    const int sgran = ((tid & 7) ^ (srow & 7)) << 3;        // ushort offset within row

    floatx4 acc[4][4];
#pragma unroll
    for (int m = 0; m < 4; ++m)
#pragma unroll
        for (int n = 0; n < 4; ++n) acc[m][n] = (floatx4){0.f, 0.f, 0.f, 0.f};

    const int NT = KK >> 6;
    for (int t = 0; t < NT; ++t) {
        const int k0 = t << 6;
        __syncthreads();                 // previous tile fully consumed
#pragma unroll
        for (int pass = 0; pass < 4; ++pass) {
            const int r = (pass << 5) + srow;               // 0..127
            int ar = row0 + r; if (ar >= M) ar = M - 1;     // clamp
            gload16(A + (size_t)ar * KK + k0 + sgran, &As[(pass << 11) + (w << 9)]);
            gload16(BT + (size_t)(col0 + r) * KK + k0 + sgran, &Bs[(pass << 11) + (w << 9)]);
        }
        __syncthreads();                 // compiler inserts vmcnt drain before barrier

#pragma unroll
        for (int s = 0; s < 2; ++s) {
            const int pg = (((s << 2) + l4) ^ (lr & 7)) << 3;   // swizzled granule (ushorts)
            bhalf8 fa[4], fb[4];
#pragma unroll
            for (int m = 0; m < 4; ++m)
                fa[m] = *(const bhalf8*)&As[((wr << 6) + (m << 4) + lr) * 64 + pg];
#pragma unroll
            for (int n = 0; n < 4; ++n)
                fb[n] = *(const bhalf8*)&Bs[((wc << 6) + (n << 4) + lr) * 64 + pg];
#pragma unroll
            for (int m = 0; m < 4; ++m)
#pragma unroll
                for (int n = 0; n < 4; ++n)
                    acc[m][n] = __builtin_amdgcn_mfma_f32_16x16x32_bf16(fa[m], fb[n], acc[m][n], 0, 0, 0);
        }
    }

    // epilogue: C/D layout col = lane&15, row = (lane>>4)*4 + j
    const int rgrp = l4 * 4;
    if (OUT == 2) {
        __syncthreads();                 // done reading As/Bs this tile
        // stage bf16 tile into padded LDS [128][136] (272B rows: 16B-aligned, bank-rotated)
#pragma unroll
        for (int n = 0; n < 4; ++n) {
            const int colt = (wc << 6) + (n << 4) + lr;
            const float bv = bias[col0 + colt];
#pragma unroll
            for (int m = 0; m < 4; ++m) {
                const int rwt = (wr << 6) + (m << 4) + rgrp;
#pragma unroll
                for (int j = 0; j < 4; ++j)
                    lds_all[(rwt + j) * 136 + colt] = f2bf(fmaxf(acc[m][n][j] + bv, 0.f));
            }
        }
        __syncthreads();
        // coalesced copy-out: 2 threads per row, 128B (8 x uint4) each
        const int orow = tid >> 1;
        const int ocol = (tid & 1) << 6;
        if (row0 + orow < M) {
            const uint4* sp = (const uint4*)(lds_all + orow * 136 + ocol);
            uint4* dp = (uint4*)(Z + (size_t)(row0 + orow) * N + col0 + ocol);
#pragma unroll
            for (int q = 0; q < 8; ++q) dp[q] = sp[q];
        }
    } else {
#pragma unroll
        for (int n = 0; n < 4; ++n) {
            const int col = col0 + (wc << 6) + (n << 4) + lr;
            const float bv = bias[col];
#pragma unroll
            for (int m = 0; m < 4; ++m) {
                const int rw = row0 + (wr << 6) + (m << 4) + rgrp;
#pragma unroll
                for (int j = 0; j < 4; ++j) {
                    const int row = rw + j;
                    if (row < M) {
                        float v = acc[m][n][j] + bv;
                        if (OUT >= 1) v = fmaxf(v, 0.f);
                        C[(size_t)row * N + col] = v;
                    }
                }
            }
        }
    }
}

// ------- pool: sorted-batch segment mean -> bf16 [g][HDIM] -------
__global__ void pool_kernel(const float* __restrict__ h, const int* __restrict__ batch,
                            unsigned short* __restrict__ gz) {
    __shared__ int sse[2];
    const int g = blockIdx.x;
    if (threadIdx.x < 2) {
        const int target = g + threadIdx.x;
        int lo = 0, hi = N_NODES;
        while (lo < hi) {
            const int mid = (lo + hi) >> 1;
            if (batch[mid] < target) lo = mid + 1; else hi = mid;
        }
        sse[threadIdx.x] = lo;
    }
    __syncthreads();
    const int s = sse[0], e = sse[1];
    const int j = threadIdx.x;
    float acc = 0.f;
    for (int n = s; n < e; ++n) acc += h[(size_t)n * HDIM + j];
    const float v = acc * ((e > s) ? 1.f / (float)(e - s) : 1.f);
    gz[(size_t)g * HDIM + j] = f2bf(v);
}

extern "C" void kernel_launch(void* const* d_in, const int* in_sizes, int n_in,
                              void* d_out, int out_size, void* d_ws, size_t ws_size,
                              hipStream_t stream) {
    const float* x      = (const float*)d_in[0];
    const int*   eidx   = (const int*)d_in[1];
    const int*   batch  = (const int*)d_in[2];
    const float* W_atom = (const float*)d_in[3];
    const float* b_atom = (const float*)d_in[4];
    const float* W1     = (const float*)d_in[5];
    const float* b1     = (const float*)d_in[6];
    const float* W2     = (const float*)d_in[7];
    const float* b2     = (const float*)d_in[8];
    const float* Wf1    = (const float*)d_in[9];
    const float* bf1    = (const float*)d_in[10];
    const float* Wf2    = (const float*)d_in[11];
    const float* bf2    = (const float*)d_in[12];
    float* out = (float*)d_out;

    const int* src = eidx;
    const int* dst = eidx + N_EDGES;

    const size_t NH = (size_t)N_NODES * HDIM;           // 25.6M elems
    const int WSZ = HDIM * 2 * HDIM;                    // 131072 elems per layer weight

    // ---- workspace layout ----
    char* base = (char*)d_ws;
    size_t off = 0;
    float* h = (float*)(base + off);                        off += NH * 4;
    unsigned short* zin = (unsigned short*)(base + off);    off += NH * 2;  // bf16 [N][256]
    int* deg     = (int*)(base + off);            off += (size_t)N_NODES * 4;
    int* row_ptr = (int*)(base + off);            off += (size_t)(N_NODES + 1) * 4;
    int* cursor  = (int*)(base + off);            off += (size_t)N_NODES * 4;
    int* eids    = (int*)(base + off);            off += (size_t)N_EDGES * 4;
    int* blk     = (int*)(base + off);            off += 512 * 4;
    off = (off + 255) & ~(size_t)255;
    unsigned short* t1 = (unsigned short*)(base + off); off += (size_t)NLAYERS * WSZ * 2;
    unsigned short* t2 = (unsigned short*)(base + off); off += (size_t)NLAYERS * WSZ * 2;
    unsigned short* tf1 = (unsigned short*)(base + off); off += (size_t)HDIM * HDIM * 2;
    unsigned short* tf2 = (unsigned short*)(base + off); off += (size_t)HDIM * EDIM * 2;
    off = (off + 255) & ~(size_t)255;

    const size_t avail = (ws_size > off) ? ws_size - off : 0;
    long chunk = (long)(avail / ((size_t)EDIM * 2));       // z2 row = 512 bf16 = 1 KB
    if (chunk > 50048) chunk = 50048;                      // 2 chunks; z2 ~51MB L3-resident
    if (chunk >= N_NODES) chunk = N_NODES;
    else chunk &= ~127L;
    if (chunk < 128) chunk = 128;
    unsigned short* z2 = (unsigned short*)(base + off);    // [chunk][512] bf16

    // head buffers overlap the (dead-after-layers) zin region
    const size_t GH = (size_t)N_GRAPHS * HDIM;
    unsigned short* hg  = zin;            // [4000][256] bf16
    unsigned short* hg1 = zin + GH;       // [4000][256] bf16

    const int nb = (N_NODES + 255) / 256;

    // 1. atom MLP (W in VGPRs, x via scalar loads, grid-stride groups of 16 nodes)
    atom_kernel<<<1024, 256, 0, stream>>>(x, W_atom, b_atom, h);

    // 2. CSR build (+ deterministic segment sort)
    zero_kernel<<<128, 256, 0, stream>>>((float*)deg, N_NODES / 4);
    hist_kernel<<<(N_EDGES + 255) / 256, 256, 0, stream>>>(dst, deg);
    scan1_kernel<<<nb, 256, 0, stream>>>(deg, row_ptr, blk);
    scan2_kernel<<<1, 64, 0, stream>>>(blk, nb);
    scan3_kernel<<<nb, 256, 0, stream>>>(row_ptr, blk);
    cursor_kernel<<<nb, 256, 0, stream>>>(row_ptr, cursor);
    fill_kernel<<<(N_EDGES + 255) / 256, 256, 0, stream>>>(src, dst, cursor, eids);
    sort_kernel<<<nb, 256, 0, stream>>>(row_ptr, eids);   // deterministic gather order

    // 3. fused weight transpose + bf16 cast (one dispatch)
    wprep_all<<<1024, 256, 0, stream>>>(W1, W2, Wf1, Wf2, t1, t2, tf1, tf2);

    // 4. GIN layers
    for (int l = 0; l < NLAYERS; ++l) {
        gather_kernel<<<N_NODES / 4, 256, 0, stream>>>(h, row_ptr, eids, zin);
        for (long r0 = 0; r0 < N_NODES; r0 += chunk) {
            const int mc = (int)((N_NODES - r0 < chunk) ? (N_NODES - r0) : chunk);
            const int nrow1 = (mc + 127) / 128;
            // z2 = relu(zin @ W1[l] + b1[l])  [mc, 512] -> bf16 (coalesced LDS-staged)
            gemm_mfma<2><<<4 * nrow1, 256, 0, stream>>>(
                zin + (size_t)r0 * HDIM, t1 + (size_t)l * WSZ,
                b1 + (size_t)l * 2 * HDIM, nullptr, z2, mc, 2 * HDIM, HDIM);
            // h = relu(z2 @ W2[l] + b2[l])    [mc, 256] -> fp32
            gemm_mfma<1><<<2 * nrow1, 256, 0, stream>>>(
                z2, t2 + (size_t)l * WSZ,
                b2 + (size_t)l * HDIM, h + (size_t)r0 * HDIM, nullptr, mc, HDIM, 2 * HDIM);
        }
    }

    // 5. pool (bf16 write)
    pool_kernel<<<N_GRAPHS, HDIM, 0, stream>>>(h, batch, hg);

    // 6. head
    gemm_mfma<2><<<2 * ((N_GRAPHS + 127) / 128), 256, 0, stream>>>(
        hg, tf1, bf1, nullptr, hg1, N_GRAPHS, HDIM, HDIM);
    gemm_mfma<0><<<4 * ((N_GRAPHS + 127) / 128), 256, 0, stream>>>(
        hg1, tf2, bf2, out, nullptr, N_GRAPHS, EDIM, HDIM);
}

// Round 14
// 928.633 us; speedup vs baseline: 2.1278x; 1.1636x over previous
//
#include <hip/hip_runtime.h>

#define N_NODES 100000
#define N_EDGES 200000
#define N_GRAPHS 4000
#define F_IN 44
#define HDIM 256
#define EDIM 512
#define NLAYERS 4

typedef float floatx4 __attribute__((ext_vector_type(4)));
typedef short bhalf8 __attribute__((ext_vector_type(8)));

__device__ __forceinline__ unsigned short f2bf(float f) {
    unsigned int u = __float_as_uint(f);
    u += 0x7FFFu + ((u >> 16) & 1u);          // RNE
    return (unsigned short)(u >> 16);
}
__device__ __forceinline__ float bf2f(unsigned short s) {
    return __uint_as_float(((unsigned int)s) << 16);
}

// async global->LDS, 16B/lane. ldst wave-uniform base; gsrc per-lane.
__device__ __forceinline__ void gload16(const void* gsrc, void* ldst) {
    __builtin_amdgcn_global_load_lds(
        (const __attribute__((address_space(1))) void*)gsrc,
        (__attribute__((address_space(3))) void*)ldst, 16, 0, 0);
}

// ---------------- zero fill ----------------
__global__ void zero_kernel(float* __restrict__ p, size_t n4) {
    size_t i = (size_t)blockIdx.x * blockDim.x + threadIdx.x;
    const size_t stride = (size_t)gridDim.x * blockDim.x;
    const float4 z = make_float4(0.f, 0.f, 0.f, 0.f);
    for (; i < n4; i += stride) ((float4*)p)[i] = z;
}

// -------- atom MLP: h = relu(x @ W_atom + b_atom) -> bf16. LDS x broadcast, float4 reads ---
__global__ __launch_bounds__(256) void atom_kernel(const float* __restrict__ x,
                                                   const float* __restrict__ W,
                                                   const float* __restrict__ b,
                                                   unsigned short* __restrict__ h) {
    const int t = threadIdx.x;
    float w[F_IN];
#pragma unroll
    for (int k = 0; k < F_IN; ++k) w[k] = W[k * HDIM + t];   // coalesced, once
    const float bj = b[t];
    __shared__ __align__(16) float xs[16 * F_IN];   // 2.8 KB; node stride 176B (16B-aligned)
    const int NG = N_NODES / 16;                    // 6250
    for (int g = blockIdx.x; g < NG; g += gridDim.x) {
        __syncthreads();                 // protect xs from previous readers
        for (int i = t; i < 16 * F_IN; i += 256) xs[i] = x[(size_t)g * 16 * F_IN + i];
        __syncthreads();
        float acc[16];
#pragma unroll
        for (int n = 0; n < 16; ++n) acc[n] = bj;
#pragma unroll
        for (int k4 = 0; k4 < F_IN / 4; ++k4) {     // 11 x float4 per node
#pragma unroll
            for (int n = 0; n < 16; ++n) {
                const float4 xv = *(const float4*)&xs[n * F_IN + k4 * 4];
                acc[n] = fmaf(xv.x, w[k4 * 4 + 0], acc[n]);
                acc[n] = fmaf(xv.y, w[k4 * 4 + 1], acc[n]);
                acc[n] = fmaf(xv.z, w[k4 * 4 + 2], acc[n]);
                acc[n] = fmaf(xv.w, w[k4 * 4 + 3], acc[n]);
            }
        }
#pragma unroll
        for (int n = 0; n < 16; ++n)
            h[(size_t)(g * 16 + n) * HDIM + t] = f2bf(fmaxf(acc[n], 0.f));
    }
}

// ---------------- CSR build ----------------
__global__ void hist_kernel(const int* __restrict__ dst, int* __restrict__ deg) {
    const int e = blockIdx.x * 256 + threadIdx.x;
    if (e < N_EDGES) atomicAdd(&deg[dst[e]], 1);
}

__global__ void scan1_kernel(const int* __restrict__ deg, int* __restrict__ row_ptr,
                             int* __restrict__ blk) {
    __shared__ int s[256];
    const int i = blockIdx.x * 256 + threadIdx.x;
    s[threadIdx.x] = (i < N_NODES) ? deg[i] : 0;
    __syncthreads();
    for (int off = 1; off < 256; off <<= 1) {
        int t = (threadIdx.x >= off) ? s[threadIdx.x - off] : 0;
        __syncthreads();
        s[threadIdx.x] += t;
        __syncthreads();
    }
    if (i < N_NODES) row_ptr[i + 1] = s[threadIdx.x];
    if (threadIdx.x == 255) blk[blockIdx.x] = s[255];
}

__global__ void scan2_kernel(int* __restrict__ blk, int nb) {
    if (threadIdx.x == 0 && blockIdx.x == 0) {
        int run = 0;
        for (int b = 0; b < nb; ++b) { const int t = blk[b]; blk[b] = run; run += t; }
    }
}

__global__ void scan3_kernel(int* __restrict__ row_ptr, const int* __restrict__ blk) {
    const int i = blockIdx.x * 256 + threadIdx.x;
    if (i < N_NODES) row_ptr[i + 1] += blk[i >> 8];
    if (i == 0) row_ptr[0] = 0;
}

__global__ void cursor_kernel(const int* __restrict__ row_ptr, int* __restrict__ cursor) {
    const int i = blockIdx.x * 256 + threadIdx.x;
    if (i < N_NODES) cursor[i] = row_ptr[i];
}

__global__ void fill_kernel(const int* __restrict__ src, const int* __restrict__ dst,
                            int* __restrict__ cursor, int* __restrict__ eids) {
    const int e = blockIdx.x * 256 + threadIdx.x;
    if (e < N_EDGES) {
        const int pos = atomicAdd(&cursor[dst[e]], 1);
        eids[pos] = src[e];
    }
}

// ------- segment sort: deterministic eids order (replay-stable fp32 sums) -------
__global__ void sort_kernel(const int* __restrict__ row_ptr, int* __restrict__ eids) {
    const int n = blockIdx.x * 256 + threadIdx.x;
    if (n < N_NODES) {
        const int s = row_ptr[n], e = row_ptr[n + 1];
        for (int i = s + 1; i < e; ++i) {
            const int v = eids[i];
            int j = i - 1;
            while (j >= s && eids[j] > v) { eids[j + 1] = eids[j]; --j; }
            eids[j + 1] = v;
        }
    }
}

// ------- gather: z = h + sum_neigh h (bf16 h, fp32 acc); write bf16 [n][HDIM] -------
__global__ void gather_kernel(const unsigned short* __restrict__ h,
                              const int* __restrict__ row_ptr,
                              const int* __restrict__ eids, unsigned short* __restrict__ z) {
    const int tid = threadIdx.x;
    const int n = blockIdx.x * 4 + (tid >> 6);
    const int t = tid & 63;
    const ushort4* h4 = (const ushort4*)h;          // 4 bf16 per lane (8B)
    ushort4 hv = h4[(size_t)n * 64 + t];
    float4 acc = make_float4(bf2f(hv.x), bf2f(hv.y), bf2f(hv.z), bf2f(hv.w));
    const int s = row_ptr[n], e = row_ptr[n + 1];
    for (int i = s; i < e; ++i) {
        const ushort4 v = h4[(size_t)eids[i] * 64 + t];
        acc.x += bf2f(v.x); acc.y += bf2f(v.y);
        acc.z += bf2f(v.z); acc.w += bf2f(v.w);
    }
    ushort4 pk;
    pk.x = f2bf(acc.x); pk.y = f2bf(acc.y);
    pk.z = f2bf(acc.z); pk.w = f2bf(acc.w);
    ((ushort4*)(z + (size_t)n * HDIM))[t] = pk;
}

// ------- fused weight prep: all weights -> transposed [N][K] bf16, one dispatch -------
__global__ void wprep_all(const float* __restrict__ W1, const float* __restrict__ W2,
                          const float* __restrict__ Wf1, const float* __restrict__ Wf2,
                          unsigned short* __restrict__ t1, unsigned short* __restrict__ t2,
                          unsigned short* __restrict__ tf1, unsigned short* __restrict__ tf2) {
    const int WSZ = HDIM * 2 * HDIM;                 // 131072
    const int total = 8 * WSZ + HDIM * HDIM + HDIM * EDIM;
    const int stride = gridDim.x * 256;
    for (int idx = blockIdx.x * 256 + threadIdx.x; idx < total; idx += stride) {
        if (idx < 4 * WSZ) {                         // W1: K=256, N=512 -> t1 [512][256]
            const int l = idx >> 17, e = idx & (WSZ - 1);
            const int k = e >> 9, n = e & 511;
            t1[(size_t)l * WSZ + n * HDIM + k] = f2bf(W1[idx]);
        } else if (idx < 8 * WSZ) {                  // W2: K=512, N=256 -> t2 [256][512]
            const int r = idx - 4 * WSZ;
            const int l = r >> 17, e = r & (WSZ - 1);
            const int k = e >> 8, n = e & 255;
            t2[(size_t)l * WSZ + n * EDIM + k] = f2bf(W2[r]);
        } else if (idx < 8 * WSZ + HDIM * HDIM) {    // Wf1 -> tf1 [256][256]
            const int e = idx - 8 * WSZ;
            const int k = e >> 8, n = e & 255;
            tf1[n * HDIM + k] = f2bf(Wf1[e]);
        } else {                                     // Wf2: K=256, N=512 -> tf2 [512][256]
            const int e = idx - 8 * WSZ - HDIM * HDIM;
            const int k = e >> 9, n = e & 511;
            tf2[n * HDIM + k] = f2bf(Wf2[e]);
        }
    }
}

// ---------------- MFMA GEMM (m97 structure): C = act(A @ B + bias) ----------------
// A [M][KK] bf16 row-major, BT [N][KK] bf16. KK multiple of 64. N multiple of 128.
// 128x128 tile, BK=64, 4 waves (2x2 of 64x64), single-buffered LDS [128][64]us x2 (32KB),
// plain __syncthreads only (compiler schedules waitcnts - no inline asm, per m141 lesson).
// Granule XOR swizzle: 8 x 16B granules/row, phys = g ^ (row&7); staged by pre-swizzling
// the per-lane GLOBAL source (LDS dest stays linear for global_load_lds).
// OUT: 0 = fp32, 2 = bf16+relu via LDS-staged COALESCED writes (r12: fixes 2.3x RMW ampl.)
template <int OUT>
__global__ __launch_bounds__(256)
void gemm_mfma(const unsigned short* __restrict__ A, const unsigned short* __restrict__ BT,
               const float* __restrict__ bias, float* __restrict__ C,
               unsigned short* __restrict__ Z, int M, int N, int KK) {
    // As = lds_all[0..8191], Bs = lds_all[8192..16383];
    // OUT=2 epilogue reuses lds_all as padded bf16 tile [128][136] (17408 us = 34 KB).
    __shared__ __align__(16) unsigned short lds_all[17408];
    unsigned short* As = lds_all;
    unsigned short* Bs = lds_all + 8192;

    const int nrow = (M + 127) >> 7;
    const int G = gridDim.x;
    int wg = blockIdx.x;
    {   // bijective XCD remap (m204)
        const int q = G >> 3, r = G & 7;
        const int xx = wg & 7, o = wg >> 3;
        wg = (xx < r ? xx * (q + 1) : r * (q + 1) + (xx - r) * q) + o;
    }
    const int row0 = (wg % nrow) << 7;
    const int col0 = (wg / nrow) << 7;

    const int tid = threadIdx.x;
    const int lane = tid & 63;
    const int w = tid >> 6;
    const int wr = w >> 1, wc = w & 1;
    const int lr = lane & 15;
    const int l4 = lane >> 4;

    // staging geometry: per pass, thread covers row (pass*32 + tid>>3), phys granule tid&7.
    // source logical granule = (tid&7) ^ ((tid>>3)&7); LDS stays linear (slot = pass*256+tid).
    const int srow = tid >> 3;                              // 0..31
    const int sgran = ((tid & 7) ^ (srow & 7)) << 3;        // ushort offset within row

    floatx4 acc[4][4];
#pragma unroll
    for (int m = 0; m < 4; ++m)
#pragma unroll
        for (int n = 0; n < 4; ++n) acc[m][n] = (floatx4){0.f, 0.f, 0.f, 0.f};

    const int NT = KK >> 6;
    for (int t = 0; t < NT; ++t) {
        const int k0 = t << 6;
        __syncthreads();                 // previous tile fully consumed
#pragma unroll
        for (int pass = 0; pass < 4; ++pass) {
            const int r = (pass << 5) + srow;               // 0..127
            int ar = row0 + r; if (ar >= M) ar = M - 1;     // clamp
            gload16(A + (size_t)ar * KK + k0 + sgran, &As[(pass << 11) + (w << 9)]);
            gload16(BT + (size_t)(col0 + r) * KK + k0 + sgran, &Bs[(pass << 11) + (w << 9)]);
        }
        __syncthreads();                 // compiler inserts vmcnt drain before barrier

#pragma unroll
        for (int s = 0; s < 2; ++s) {
            const int pg = (((s << 2) + l4) ^ (lr & 7)) << 3;   // swizzled granule (ushorts)
            bhalf8 fa[4], fb[4];
#pragma unroll
            for (int m = 0; m < 4; ++m)
                fa[m] = *(const bhalf8*)&As[((wr << 6) + (m << 4) + lr) * 64 + pg];
#pragma unroll
            for (int n = 0; n < 4; ++n)
                fb[n] = *(const bhalf8*)&Bs[((wc << 6) + (n << 4) + lr) * 64 + pg];
#pragma unroll
            for (int m = 0; m < 4; ++m)
#pragma unroll
                for (int n = 0; n < 4; ++n)
                    acc[m][n] = __builtin_amdgcn_mfma_f32_16x16x32_bf16(fa[m], fb[n], acc[m][n], 0, 0, 0);
        }
    }

    // epilogue: C/D layout col = lane&15, row = (lane>>4)*4 + j
    const int rgrp = l4 * 4;
    if (OUT == 2) {
        __syncthreads();                 // done reading As/Bs this tile
        // stage bf16 tile into padded LDS [128][136] (272B rows: 16B-aligned, bank-rotated)
#pragma unroll
        for (int n = 0; n < 4; ++n) {
            const int colt = (wc << 6) + (n << 4) + lr;
            const float bv = bias[col0 + colt];
#pragma unroll
            for (int m = 0; m < 4; ++m) {
                const int rwt = (wr << 6) + (m << 4) + rgrp;
#pragma unroll
                for (int j = 0; j < 4; ++j)
                    lds_all[(rwt + j) * 136 + colt] = f2bf(fmaxf(acc[m][n][j] + bv, 0.f));
            }
        }
        __syncthreads();
        // coalesced copy-out: 2 threads per row, 128B (8 x uint4) each
        const int orow = tid >> 1;
        const int ocol = (tid & 1) << 6;
        if (row0 + orow < M) {
            const uint4* sp = (const uint4*)(lds_all + orow * 136 + ocol);
            uint4* dp = (uint4*)(Z + (size_t)(row0 + orow) * N + col0 + ocol);
#pragma unroll
            for (int q = 0; q < 8; ++q) dp[q] = sp[q];
        }
    } else {
#pragma unroll
        for (int n = 0; n < 4; ++n) {
            const int col = col0 + (wc << 6) + (n << 4) + lr;
            const float bv = bias[col];
#pragma unroll
            for (int m = 0; m < 4; ++m) {
                const int rw = row0 + (wr << 6) + (m << 4) + rgrp;
#pragma unroll
                for (int j = 0; j < 4; ++j) {
                    const int row = rw + j;
                    if (row < M) C[(size_t)row * N + col] = acc[m][n][j] + bv;
                }
            }
        }
    }
}

// ------- pool: sorted-batch segment mean over bf16 h -> bf16 [g][HDIM] -------
__global__ void pool_kernel(const unsigned short* __restrict__ h,
                            const int* __restrict__ batch,
                            unsigned short* __restrict__ gz) {
    __shared__ int sse[2];
    const int g = blockIdx.x;
    if (threadIdx.x < 2) {
        const int target = g + threadIdx.x;
        int lo = 0, hi = N_NODES;
        while (lo < hi) {
            const int mid = (lo + hi) >> 1;
            if (batch[mid] < target) lo = mid + 1; else hi = mid;
        }
        sse[threadIdx.x] = lo;
    }
    __syncthreads();
    const int s = sse[0], e = sse[1];
    const int j = threadIdx.x;
    float acc = 0.f;
    for (int n = s; n < e; ++n) acc += bf2f(h[(size_t)n * HDIM + j]);
    const float v = acc * ((e > s) ? 1.f / (float)(e - s) : 1.f);
    gz[(size_t)g * HDIM + j] = f2bf(v);
}

extern "C" void kernel_launch(void* const* d_in, const int* in_sizes, int n_in,
                              void* d_out, int out_size, void* d_ws, size_t ws_size,
                              hipStream_t stream) {
    const float* x      = (const float*)d_in[0];
    const int*   eidx   = (const int*)d_in[1];
    const int*   batch  = (const int*)d_in[2];
    const float* W_atom = (const float*)d_in[3];
    const float* b_atom = (const float*)d_in[4];
    const float* W1     = (const float*)d_in[5];
    const float* b1     = (const float*)d_in[6];
    const float* W2     = (const float*)d_in[7];
    const float* b2     = (const float*)d_in[8];
    const float* Wf1    = (const float*)d_in[9];
    const float* bf1    = (const float*)d_in[10];
    const float* Wf2    = (const float*)d_in[11];
    const float* bf2    = (const float*)d_in[12];
    float* out = (float*)d_out;

    const int* src = eidx;
    const int* dst = eidx + N_EDGES;

    const size_t NH = (size_t)N_NODES * HDIM;           // 25.6M elems
    const int WSZ = HDIM * 2 * HDIM;                    // 131072 elems per layer weight

    // ---- workspace layout ----
    char* base = (char*)d_ws;
    size_t off = 0;
    unsigned short* h = (unsigned short*)(base + off);      off += NH * 2;  // bf16 [N][256]
    unsigned short* zin = (unsigned short*)(base + off);    off += NH * 2;  // bf16 [N][256]
    int* deg     = (int*)(base + off);            off += (size_t)N_NODES * 4;
    int* row_ptr = (int*)(base + off);            off += (size_t)(N_NODES + 1) * 4;
    int* cursor  = (int*)(base + off);            off += (size_t)N_NODES * 4;
    int* eids    = (int*)(base + off);            off += (size_t)N_EDGES * 4;
    int* blk     = (int*)(base + off);            off += 512 * 4;
    off = (off + 255) & ~(size_t)255;
    unsigned short* t1 = (unsigned short*)(base + off); off += (size_t)NLAYERS * WSZ * 2;
    unsigned short* t2 = (unsigned short*)(base + off); off += (size_t)NLAYERS * WSZ * 2;
    unsigned short* tf1 = (unsigned short*)(base + off); off += (size_t)HDIM * HDIM * 2;
    unsigned short* tf2 = (unsigned short*)(base + off); off += (size_t)HDIM * EDIM * 2;
    off = (off + 255) & ~(size_t)255;

    const size_t avail = (ws_size > off) ? ws_size - off : 0;
    long chunk = (long)(avail / ((size_t)EDIM * 2));       // z2 row = 512 bf16 = 1 KB
    if (chunk > 50048) chunk = 50048;                      // 2 chunks; z2 ~51MB L3-resident
    if (chunk >= N_NODES) chunk = N_NODES;
    else chunk &= ~127L;
    if (chunk < 128) chunk = 128;
    unsigned short* z2 = (unsigned short*)(base + off);    // [chunk][512] bf16

    // head buffers overlap the (dead-after-layers) zin region
    const size_t GH = (size_t)N_GRAPHS * HDIM;
    unsigned short* hg  = zin;            // [4000][256] bf16
    unsigned short* hg1 = zin + GH;       // [4000][256] bf16

    const int nb = (N_NODES + 255) / 256;

    // 1. atom MLP (W in VGPRs, LDS x broadcast, float4 reads, bf16 out)
    atom_kernel<<<1024, 256, 0, stream>>>(x, W_atom, b_atom, h);

    // 2. CSR build (+ deterministic segment sort)
    zero_kernel<<<128, 256, 0, stream>>>((float*)deg, N_NODES / 4);
    hist_kernel<<<(N_EDGES + 255) / 256, 256, 0, stream>>>(dst, deg);
    scan1_kernel<<<nb, 256, 0, stream>>>(deg, row_ptr, blk);
    scan2_kernel<<<1, 64, 0, stream>>>(blk, nb);
    scan3_kernel<<<nb, 256, 0, stream>>>(row_ptr, blk);
    cursor_kernel<<<nb, 256, 0, stream>>>(row_ptr, cursor);
    fill_kernel<<<(N_EDGES + 255) / 256, 256, 0, stream>>>(src, dst, cursor, eids);
    sort_kernel<<<nb, 256, 0, stream>>>(row_ptr, eids);   // deterministic gather order

    // 3. fused weight transpose + bf16 cast (one dispatch)
    wprep_all<<<1024, 256, 0, stream>>>(W1, W2, Wf1, Wf2, t1, t2, tf1, tf2);

    // 4. GIN layers
    for (int l = 0; l < NLAYERS; ++l) {
        gather_kernel<<<N_NODES / 4, 256, 0, stream>>>(h, row_ptr, eids, zin);
        for (long r0 = 0; r0 < N_NODES; r0 += chunk) {
            const int mc = (int)((N_NODES - r0 < chunk) ? (N_NODES - r0) : chunk);
            const int nrow1 = (mc + 127) / 128;
            // z2 = relu(zin @ W1[l] + b1[l])  [mc, 512] -> bf16 (coalesced LDS-staged)
            gemm_mfma<2><<<4 * nrow1, 256, 0, stream>>>(
                zin + (size_t)r0 * HDIM, t1 + (size_t)l * WSZ,
                b1 + (size_t)l * 2 * HDIM, nullptr, z2, mc, 2 * HDIM, HDIM);
            // h = relu(z2 @ W2[l] + b2[l])    [mc, 256] -> bf16 (coalesced LDS-staged)
            gemm_mfma<2><<<2 * nrow1, 256, 0, stream>>>(
                z2, t2 + (size_t)l * WSZ,
                b2 + (size_t)l * HDIM, nullptr, h + (size_t)r0 * HDIM, mc, HDIM, 2 * HDIM);
        }
    }

    // 5. pool (bf16 in/out)
    pool_kernel<<<N_GRAPHS, HDIM, 0, stream>>>(h, batch, hg);

    // 6. head
    gemm_mfma<2><<<2 * ((N_GRAPHS + 127) / 128), 256, 0, stream>>>(
        hg, tf1, bf1, nullptr, hg1, N_GRAPHS, HDIM, HDIM);
    gemm_mfma<0><<<4 * ((N_GRAPHS + 127) / 128), 256, 0, stream>>>(
        hg1, tf2, bf2, out, nullptr, N_GRAPHS, EDIM, HDIM);
}

// Round 15
// 805.673 us; speedup vs baseline: 2.4525x; 1.1526x over previous
//
#include <hip/hip_runtime.h>

#define N_NODES 100000
#define N_EDGES 200000
#define N_GRAPHS 4000
#define F_IN 44
#define HDIM 256
#define EDIM 512
#define NLAYERS 4

typedef float floatx4 __attribute__((ext_vector_type(4)));
typedef short bhalf8 __attribute__((ext_vector_type(8)));

__device__ __forceinline__ unsigned short f2bf(float f) {
    unsigned int u = __float_as_uint(f);
    u += 0x7FFFu + ((u >> 16) & 1u);          // RNE
    return (unsigned short)(u >> 16);
}
__device__ __forceinline__ float bf2f(unsigned short s) {
    return __uint_as_float(((unsigned int)s) << 16);
}

// async global->LDS, 16B/lane. ldst wave-uniform base; gsrc per-lane.
__device__ __forceinline__ void gload16(const void* gsrc, void* ldst) {
    __builtin_amdgcn_global_load_lds(
        (const __attribute__((address_space(1))) void*)gsrc,
        (__attribute__((address_space(3))) void*)ldst, 16, 0, 0);
}

// ---------------- zero fill ----------------
__global__ void zero_kernel(float* __restrict__ p, size_t n4) {
    size_t i = (size_t)blockIdx.x * blockDim.x + threadIdx.x;
    const size_t stride = (size_t)gridDim.x * blockDim.x;
    const float4 z = make_float4(0.f, 0.f, 0.f, 0.f);
    for (; i < n4; i += stride) ((float4*)p)[i] = z;
}

// ------- xprep: x fp32 [N][44] -> xb bf16 [N][64] zero-padded (coalesced 8B writes) -------
__global__ void xprep_kernel(const float* __restrict__ x, unsigned short* __restrict__ xb) {
    int idx = blockIdx.x * 256 + threadIdx.x;
    const int total = N_NODES * 16;               // 16 x ushort4 slots per node
    const int stride = gridDim.x * 256;
    for (; idx < total; idx += stride) {
        const int n = idx >> 4, k4 = idx & 15;
        ushort4 v = make_ushort4(0, 0, 0, 0);
        if (k4 < F_IN / 4) {                      // 11 valid float4 slots
            const float4 xv = *(const float4*)(x + (size_t)n * F_IN + k4 * 4);
            v.x = f2bf(xv.x); v.y = f2bf(xv.y); v.z = f2bf(xv.z); v.w = f2bf(xv.w);
        }
        *(ushort4*)(xb + (size_t)n * 64 + k4 * 4) = v;
    }
}

// ---------------- CSR build ----------------
__global__ void hist_kernel(const int* __restrict__ dst, int* __restrict__ deg) {
    const int e = blockIdx.x * 256 + threadIdx.x;
    if (e < N_EDGES) atomicAdd(&deg[dst[e]], 1);
}

__global__ void scan1_kernel(const int* __restrict__ deg, int* __restrict__ row_ptr,
                             int* __restrict__ blk) {
    __shared__ int s[256];
    const int i = blockIdx.x * 256 + threadIdx.x;
    s[threadIdx.x] = (i < N_NODES) ? deg[i] : 0;
    __syncthreads();
    for (int off = 1; off < 256; off <<= 1) {
        int t = (threadIdx.x >= off) ? s[threadIdx.x - off] : 0;
        __syncthreads();
        s[threadIdx.x] += t;
        __syncthreads();
    }
    if (i < N_NODES) row_ptr[i + 1] = s[threadIdx.x];
    if (threadIdx.x == 255) blk[blockIdx.x] = s[255];
}

__global__ void scan2_kernel(int* __restrict__ blk, int nb) {
    if (threadIdx.x == 0 && blockIdx.x == 0) {
        int run = 0;
        for (int b = 0; b < nb; ++b) { const int t = blk[b]; blk[b] = run; run += t; }
    }
}

__global__ void scan3_kernel(int* __restrict__ row_ptr, const int* __restrict__ blk) {
    const int i = blockIdx.x * 256 + threadIdx.x;
    if (i < N_NODES) row_ptr[i + 1] += blk[i >> 8];
    if (i == 0) row_ptr[0] = 0;
}

__global__ void cursor_kernel(const int* __restrict__ row_ptr, int* __restrict__ cursor) {
    const int i = blockIdx.x * 256 + threadIdx.x;
    if (i < N_NODES) cursor[i] = row_ptr[i];
}

__global__ void fill_kernel(const int* __restrict__ src, const int* __restrict__ dst,
                            int* __restrict__ cursor, int* __restrict__ eids) {
    const int e = blockIdx.x * 256 + threadIdx.x;
    if (e < N_EDGES) {
        const int pos = atomicAdd(&cursor[dst[e]], 1);
        eids[pos] = src[e];
    }
}

// ------- segment sort: deterministic eids order (replay-stable fp32 sums) -------
__global__ void sort_kernel(const int* __restrict__ row_ptr, int* __restrict__ eids) {
    const int n = blockIdx.x * 256 + threadIdx.x;
    if (n < N_NODES) {
        const int s = row_ptr[n], e = row_ptr[n + 1];
        for (int i = s + 1; i < e; ++i) {
            const int v = eids[i];
            int j = i - 1;
            while (j >= s && eids[j] > v) { eids[j + 1] = eids[j]; --j; }
            eids[j + 1] = v;
        }
    }
}

// ------- gather: z = h + sum_neigh h (bf16 h, fp32 acc); write bf16 [n][HDIM] -------
__global__ void gather_kernel(const unsigned short* __restrict__ h,
                              const int* __restrict__ row_ptr,
                              const int* __restrict__ eids, unsigned short* __restrict__ z) {
    const int tid = threadIdx.x;
    const int n = blockIdx.x * 4 + (tid >> 6);
    const int t = tid & 63;
    const ushort4* h4 = (const ushort4*)h;          // 4 bf16 per lane (8B)
    ushort4 hv = h4[(size_t)n * 64 + t];
    float4 acc = make_float4(bf2f(hv.x), bf2f(hv.y), bf2f(hv.z), bf2f(hv.w));
    const int s = row_ptr[n], e = row_ptr[n + 1];
    for (int i = s; i < e; ++i) {
        const ushort4 v = h4[(size_t)eids[i] * 64 + t];
        acc.x += bf2f(v.x); acc.y += bf2f(v.y);
        acc.z += bf2f(v.z); acc.w += bf2f(v.w);
    }
    ushort4 pk;
    pk.x = f2bf(acc.x); pk.y = f2bf(acc.y);
    pk.z = f2bf(acc.z); pk.w = f2bf(acc.w);
    ((ushort4*)(z + (size_t)n * HDIM))[t] = pk;
}

// ------- fused weight prep: all weights -> transposed [N][K] bf16, one dispatch -------
__global__ void wprep_all(const float* __restrict__ W1, const float* __restrict__ W2,
                          const float* __restrict__ Wf1, const float* __restrict__ Wf2,
                          const float* __restrict__ Wa,
                          unsigned short* __restrict__ t1, unsigned short* __restrict__ t2,
                          unsigned short* __restrict__ tf1, unsigned short* __restrict__ tf2,
                          unsigned short* __restrict__ tat) {
    const int WSZ = HDIM * 2 * HDIM;                 // 131072
    const int T0 = 8 * WSZ;                          // W1+W2
    const int T1 = T0 + HDIM * HDIM;                 // +Wf1
    const int T2 = T1 + HDIM * EDIM;                 // +Wf2
    const int T3 = T2 + 64 * HDIM;                   // +W_atom (padded K=64)
    const int stride = gridDim.x * 256;
    for (int idx = blockIdx.x * 256 + threadIdx.x; idx < T3; idx += stride) {
        if (idx < 4 * WSZ) {                         // W1: K=256, N=512 -> t1 [512][256]
            const int l = idx >> 17, e = idx & (WSZ - 1);
            const int k = e >> 9, n = e & 511;
            t1[(size_t)l * WSZ + n * HDIM + k] = f2bf(W1[idx]);
        } else if (idx < T0) {                       // W2: K=512, N=256 -> t2 [256][512]
            const int r = idx - 4 * WSZ;
            const int l = r >> 17, e = r & (WSZ - 1);
            const int k = e >> 8, n = e & 255;
            t2[(size_t)l * WSZ + n * EDIM + k] = f2bf(W2[r]);
        } else if (idx < T1) {                       // Wf1 -> tf1 [256][256]
            const int e = idx - T0;
            const int k = e >> 8, n = e & 255;
            tf1[n * HDIM + k] = f2bf(Wf1[e]);
        } else if (idx < T2) {                       // Wf2: K=256, N=512 -> tf2 [512][256]
            const int e = idx - T1;
            const int k = e >> 9, n = e & 511;
            tf2[n * HDIM + k] = f2bf(Wf2[e]);
        } else {                                     // W_atom: [44][256] -> tat [256][64] pad0
            const int e = idx - T2;                  // e over 64*256, k-major per n
            const int n = e >> 6, k = e & 63;
            tat[n * 64 + k] = (k < F_IN) ? f2bf(Wa[k * HDIM + n]) : (unsigned short)0;
        }
    }
}

// ---------------- MFMA GEMM (m97 structure): C = act(A @ B + bias) ----------------
// A [M][KK] bf16 row-major, BT [N][KK] bf16. KK multiple of 64. N multiple of 128.
// 128x128 tile, BK=64, 4 waves (2x2 of 64x64), single-buffered LDS [128][64]us x2 (32KB),
// plain __syncthreads only (compiler schedules waitcnts - no inline asm, per m141 lesson).
// Granule XOR swizzle: 8 x 16B granules/row, phys = g ^ (row&7); staged by pre-swizzling
// the per-lane GLOBAL source (LDS dest stays linear for global_load_lds).
// OUT: 0 = fp32, 2 = bf16+relu via LDS-staged COALESCED writes (r12: fixes 2.3x RMW ampl.)
template <int OUT>
__global__ __launch_bounds__(256)
void gemm_mfma(const unsigned short* __restrict__ A, const unsigned short* __restrict__ BT,
               const float* __restrict__ bias, float* __restrict__ C,
               unsigned short* __restrict__ Z, int M, int N, int KK) {
    // As = lds_all[0..8191], Bs = lds_all[8192..16383];
    // OUT=2 epilogue reuses lds_all as padded bf16 tile [128][136] (17408 us = 34 KB).
    __shared__ __align__(16) unsigned short lds_all[17408];
    unsigned short* As = lds_all;
    unsigned short* Bs = lds_all + 8192;

    const int nrow = (M + 127) >> 7;
    const int G = gridDim.x;
    int wg = blockIdx.x;
    {   // bijective XCD remap (m204)
        const int q = G >> 3, r = G & 7;
        const int xx = wg & 7, o = wg >> 3;
        wg = (xx < r ? xx * (q + 1) : r * (q + 1) + (xx - r) * q) + o;
    }
    const int row0 = (wg % nrow) << 7;
    const int col0 = (wg / nrow) << 7;

    const int tid = threadIdx.x;
    const int lane = tid & 63;
    const int w = tid >> 6;
    const int wr = w >> 1, wc = w & 1;
    const int lr = lane & 15;
    const int l4 = lane >> 4;

    // staging geometry: per pass, thread covers row (pass*32 + tid>>3), phys granule tid&7.
    // source logical granule = (tid&7) ^ ((tid>>3)&7); LDS stays linear (slot = pass*256+tid).
    const int srow = tid >> 3;                              // 0..31
    const int sgran = ((tid & 7) ^ (srow & 7)) << 3;        // ushort offset within row

    floatx4 acc[4][4];
#pragma unroll
    for (int m = 0; m < 4; ++m)
#pragma unroll
        for (int n = 0; n < 4; ++n) acc[m][n] = (floatx4){0.f, 0.f, 0.f, 0.f};

    const int NT = KK >> 6;
    for (int t = 0; t < NT; ++t) {
        const int k0 = t << 6;
        __syncthreads();                 // previous tile fully consumed
#pragma unroll
        for (int pass = 0; pass < 4; ++pass) {
            const int r = (pass << 5) + srow;               // 0..127
            int ar = row0 + r; if (ar >= M) ar = M - 1;     // clamp
            gload16(A + (size_t)ar * KK + k0 + sgran, &As[(pass << 11) + (w << 9)]);
            gload16(BT + (size_t)(col0 + r) * KK + k0 + sgran, &Bs[(pass << 11) + (w << 9)]);
        }
        __syncthreads();                 // compiler inserts vmcnt drain before barrier

#pragma unroll
        for (int s = 0; s < 2; ++s) {
            const int pg = (((s << 2) + l4) ^ (lr & 7)) << 3;   // swizzled granule (ushorts)
            bhalf8 fa[4], fb[4];
#pragma unroll
            for (int m = 0; m < 4; ++m)
                fa[m] = *(const bhalf8*)&As[((wr << 6) + (m << 4) + lr) * 64 + pg];
#pragma unroll
            for (int n = 0; n < 4; ++n)
                fb[n] = *(const bhalf8*)&Bs[((wc << 6) + (n << 4) + lr) * 64 + pg];
#pragma unroll
            for (int m = 0; m < 4; ++m)
#pragma unroll
                for (int n = 0; n < 4; ++n)
                    acc[m][n] = __builtin_amdgcn_mfma_f32_16x16x32_bf16(fa[m], fb[n], acc[m][n], 0, 0, 0);
        }
    }

    // epilogue: C/D layout col = lane&15, row = (lane>>4)*4 + j
    const int rgrp = l4 * 4;
    if (OUT == 2) {
        __syncthreads();                 // done reading As/Bs this tile
        // stage bf16 tile into padded LDS [128][136] (272B rows: 16B-aligned, bank-rotated)
#pragma unroll
        for (int n = 0; n < 4; ++n) {
            const int colt = (wc << 6) + (n << 4) + lr;
            const float bv = bias[col0 + colt];
#pragma unroll
            for (int m = 0; m < 4; ++m) {
                const int rwt = (wr << 6) + (m << 4) + rgrp;
#pragma unroll
                for (int j = 0; j < 4; ++j)
                    lds_all[(rwt + j) * 136 + colt] = f2bf(fmaxf(acc[m][n][j] + bv, 0.f));
            }
        }
        __syncthreads();
        // coalesced copy-out: 2 threads per row, 128B (8 x uint4) each
        const int orow = tid >> 1;
        const int ocol = (tid & 1) << 6;
        if (row0 + orow < M) {
            const uint4* sp = (const uint4*)(lds_all + orow * 136 + ocol);
            uint4* dp = (uint4*)(Z + (size_t)(row0 + orow) * N + col0 + ocol);
#pragma unroll
            for (int q = 0; q < 8; ++q) dp[q] = sp[q];
        }
    } else {
#pragma unroll
        for (int n = 0; n < 4; ++n) {
            const int col = col0 + (wc << 6) + (n << 4) + lr;
            const float bv = bias[col];
#pragma unroll
            for (int m = 0; m < 4; ++m) {
                const int rw = row0 + (wr << 6) + (m << 4) + rgrp;
#pragma unroll
                for (int j = 0; j < 4; ++j) {
                    const int row = rw + j;
                    if (row < M) C[(size_t)row * N + col] = acc[m][n][j] + bv;
                }
            }
        }
    }
}

// ------- pool: sorted-batch segment mean over bf16 h -> bf16 [g][HDIM] -------
__global__ void pool_kernel(const unsigned short* __restrict__ h,
                            const int* __restrict__ batch,
                            unsigned short* __restrict__ gz) {
    __shared__ int sse[2];
    const int g = blockIdx.x;
    if (threadIdx.x < 2) {
        const int target = g + threadIdx.x;
        int lo = 0, hi = N_NODES;
        while (lo < hi) {
            const int mid = (lo + hi) >> 1;
            if (batch[mid] < target) lo = mid + 1; else hi = mid;
        }
        sse[threadIdx.x] = lo;
    }
    __syncthreads();
    const int s = sse[0], e = sse[1];
    const int j = threadIdx.x;
    float acc = 0.f;
    for (int n = s; n < e; ++n) acc += bf2f(h[(size_t)n * HDIM + j]);
    const float v = acc * ((e > s) ? 1.f / (float)(e - s) : 1.f);
    gz[(size_t)g * HDIM + j] = f2bf(v);
}

extern "C" void kernel_launch(void* const* d_in, const int* in_sizes, int n_in,
                              void* d_out, int out_size, void* d_ws, size_t ws_size,
                              hipStream_t stream) {
    const float* x      = (const float*)d_in[0];
    const int*   eidx   = (const int*)d_in[1];
    const int*   batch  = (const int*)d_in[2];
    const float* W_atom = (const float*)d_in[3];
    const float* b_atom = (const float*)d_in[4];
    const float* W1     = (const float*)d_in[5];
    const float* b1     = (const float*)d_in[6];
    const float* W2     = (const float*)d_in[7];
    const float* b2     = (const float*)d_in[8];
    const float* Wf1    = (const float*)d_in[9];
    const float* bf1    = (const float*)d_in[10];
    const float* Wf2    = (const float*)d_in[11];
    const float* bf2    = (const float*)d_in[12];
    float* out = (float*)d_out;

    const int* src = eidx;
    const int* dst = eidx + N_EDGES;

    const size_t NH = (size_t)N_NODES * HDIM;           // 25.6M elems
    const int WSZ = HDIM * 2 * HDIM;                    // 131072 elems per layer weight

    // ---- workspace layout ----
    char* base = (char*)d_ws;
    size_t off = 0;
    unsigned short* h = (unsigned short*)(base + off);      off += NH * 2;  // bf16 [N][256]
    unsigned short* zin = (unsigned short*)(base + off);    off += NH * 2;  // bf16 [N][256]
    unsigned short* xb = (unsigned short*)(base + off);     off += (size_t)N_NODES * 64 * 2;
    int* deg     = (int*)(base + off);            off += (size_t)N_NODES * 4;
    int* row_ptr = (int*)(base + off);            off += (size_t)(N_NODES + 1) * 4;
    int* cursor  = (int*)(base + off);            off += (size_t)N_NODES * 4;
    int* eids    = (int*)(base + off);            off += (size_t)N_EDGES * 4;
    int* blk     = (int*)(base + off);            off += 512 * 4;
    off = (off + 255) & ~(size_t)255;
    unsigned short* t1 = (unsigned short*)(base + off); off += (size_t)NLAYERS * WSZ * 2;
    unsigned short* t2 = (unsigned short*)(base + off); off += (size_t)NLAYERS * WSZ * 2;
    unsigned short* tf1 = (unsigned short*)(base + off); off += (size_t)HDIM * HDIM * 2;
    unsigned short* tf2 = (unsigned short*)(base + off); off += (size_t)HDIM * EDIM * 2;
    unsigned short* tat = (unsigned short*)(base + off); off += (size_t)HDIM * 64 * 2;
    off = (off + 255) & ~(size_t)255;

    const size_t avail = (ws_size > off) ? ws_size - off : 0;
    long chunk = (long)(avail / ((size_t)EDIM * 2));       // z2 row = 512 bf16 = 1 KB
    if (chunk >= N_NODES) chunk = N_NODES;                 // single chunk (z2 102MB, L3-res)
    else chunk &= ~127L;
    if (chunk < 128) chunk = 128;
    unsigned short* z2 = (unsigned short*)(base + off);    // [chunk][512] bf16

    // head buffers overlap the (dead-after-layers) zin region
    const size_t GH = (size_t)N_GRAPHS * HDIM;
    unsigned short* hg  = zin;            // [4000][256] bf16
    unsigned short* hg1 = zin + GH;       // [4000][256] bf16

    const int nb = (N_NODES + 255) / 256;

    // 1. x -> bf16 padded [N][64]; weights -> transposed bf16 (one dispatch each)
    xprep_kernel<<<1024, 256, 0, stream>>>(x, xb);
    wprep_all<<<1024, 256, 0, stream>>>(W1, W2, Wf1, Wf2, W_atom, t1, t2, tf1, tf2, tat);

    // 2. CSR build (+ deterministic segment sort)
    zero_kernel<<<128, 256, 0, stream>>>((float*)deg, N_NODES / 4);
    hist_kernel<<<(N_EDGES + 255) / 256, 256, 0, stream>>>(dst, deg);
    scan1_kernel<<<nb, 256, 0, stream>>>(deg, row_ptr, blk);
    scan2_kernel<<<1, 64, 0, stream>>>(blk, nb);
    scan3_kernel<<<nb, 256, 0, stream>>>(row_ptr, blk);
    cursor_kernel<<<nb, 256, 0, stream>>>(row_ptr, cursor);
    fill_kernel<<<(N_EDGES + 255) / 256, 256, 0, stream>>>(src, dst, cursor, eids);
    sort_kernel<<<nb, 256, 0, stream>>>(row_ptr, eids);   // deterministic gather order

    // 3. atom MLP as MFMA GEMM: h = relu(xb @ W_atom + b_atom)  [100000, 256], KK=64
    {
        const int nrow1 = (N_NODES + 127) / 128;
        gemm_mfma<2><<<2 * nrow1, 256, 0, stream>>>(
            xb, tat, b_atom, nullptr, h, N_NODES, HDIM, 64);
    }

    // 4. GIN layers
    for (int l = 0; l < NLAYERS; ++l) {
        gather_kernel<<<N_NODES / 4, 256, 0, stream>>>(h, row_ptr, eids, zin);
        for (long r0 = 0; r0 < N_NODES; r0 += chunk) {
            const int mc = (int)((N_NODES - r0 < chunk) ? (N_NODES - r0) : chunk);
            const int nrow1 = (mc + 127) / 128;
            // z2 = relu(zin @ W1[l] + b1[l])  [mc, 512] -> bf16 (coalesced LDS-staged)
            gemm_mfma<2><<<4 * nrow1, 256, 0, stream>>>(
                zin + (size_t)r0 * HDIM, t1 + (size_t)l * WSZ,
                b1 + (size_t)l * 2 * HDIM, nullptr, z2, mc, 2 * HDIM, HDIM);
            // h = relu(z2 @ W2[l] + b2[l])    [mc, 256] -> bf16 (coalesced LDS-staged)
            gemm_mfma<2><<<2 * nrow1, 256, 0, stream>>>(
                z2, t2 + (size_t)l * WSZ,
                b2 + (size_t)l * HDIM, nullptr, h + (size_t)r0 * HDIM, mc, HDIM, 2 * HDIM);
        }
    }

    // 5. pool (bf16 in/out)
    pool_kernel<<<N_GRAPHS, HDIM, 0, stream>>>(h, batch, hg);

    // 6. head
    gemm_mfma<2><<<2 * ((N_GRAPHS + 127) / 128), 256, 0, stream>>>(
        hg, tf1, bf1, nullptr, hg1, N_GRAPHS, HDIM, HDIM);
    gemm_mfma<0><<<4 * ((N_GRAPHS + 127) / 128), 256, 0, stream>>>(
        hg1, tf2, bf2, out, nullptr, N_GRAPHS, EDIM, HDIM);
}

// Round 16
// 763.700 us; speedup vs baseline: 2.5873x; 1.0550x over previous
//
#include <hip/hip_runtime.h>

#define N_NODES 100000
#define N_EDGES 200000
#define N_GRAPHS 4000
#define F_IN 44
#define HDIM 256
#define EDIM 512
#define NLAYERS 4

typedef float floatx4 __attribute__((ext_vector_type(4)));
typedef short bhalf8 __attribute__((ext_vector_type(8)));

__device__ __forceinline__ unsigned short f2bf(float f) {
    unsigned int u = __float_as_uint(f);
    u += 0x7FFFu + ((u >> 16) & 1u);          // RNE
    return (unsigned short)(u >> 16);
}
__device__ __forceinline__ float bf2f(unsigned short s) {
    return __uint_as_float(((unsigned int)s) << 16);
}

// async global->LDS, 16B/lane. ldst wave-uniform base; gsrc per-lane.
__device__ __forceinline__ void gload16(const void* gsrc, void* ldst) {
    __builtin_amdgcn_global_load_lds(
        (const __attribute__((address_space(1))) void*)gsrc,
        (__attribute__((address_space(3))) void*)ldst, 16, 0, 0);
}

// ---------------- zero fill ----------------
__global__ void zero_kernel(float* __restrict__ p, size_t n4) {
    size_t i = (size_t)blockIdx.x * blockDim.x + threadIdx.x;
    const size_t stride = (size_t)gridDim.x * blockDim.x;
    const float4 z = make_float4(0.f, 0.f, 0.f, 0.f);
    for (; i < n4; i += stride) ((float4*)p)[i] = z;
}

// ------- xprep: x fp32 [N][44] -> xb bf16 [N][64] zero-padded (coalesced 8B writes) -------
__global__ void xprep_kernel(const float* __restrict__ x, unsigned short* __restrict__ xb) {
    int idx = blockIdx.x * 256 + threadIdx.x;
    const int total = N_NODES * 16;               // 16 x ushort4 slots per node
    const int stride = gridDim.x * 256;
    for (; idx < total; idx += stride) {
        const int n = idx >> 4, k4 = idx & 15;
        ushort4 v = make_ushort4(0, 0, 0, 0);
        if (k4 < F_IN / 4) {                      // 11 valid float4 slots
            const float4 xv = *(const float4*)(x + (size_t)n * F_IN + k4 * 4);
            v.x = f2bf(xv.x); v.y = f2bf(xv.y); v.z = f2bf(xv.z); v.w = f2bf(xv.w);
        }
        *(ushort4*)(xb + (size_t)n * 64 + k4 * 4) = v;
    }
}

// ---------------- CSR build ----------------
__global__ void hist_kernel(const int* __restrict__ dst, int* __restrict__ deg) {
    const int e = blockIdx.x * 256 + threadIdx.x;
    if (e < N_EDGES) atomicAdd(&deg[dst[e]], 1);
}

__global__ void scan1_kernel(const int* __restrict__ deg, int* __restrict__ row_ptr,
                             int* __restrict__ blk) {
    __shared__ int s[256];
    const int i = blockIdx.x * 256 + threadIdx.x;
    s[threadIdx.x] = (i < N_NODES) ? deg[i] : 0;
    __syncthreads();
    for (int off = 1; off < 256; off <<= 1) {
        int t = (threadIdx.x >= off) ? s[threadIdx.x - off] : 0;
        __syncthreads();
        s[threadIdx.x] += t;
        __syncthreads();
    }
    if (i < N_NODES) row_ptr[i + 1] = s[threadIdx.x];
    if (threadIdx.x == 255) blk[blockIdx.x] = s[255];
}

__global__ void scan2_kernel(int* __restrict__ blk, int nb) {
    if (threadIdx.x == 0 && blockIdx.x == 0) {
        int run = 0;
        for (int b = 0; b < nb; ++b) { const int t = blk[b]; blk[b] = run; run += t; }
    }
}

__global__ void scan3_kernel(int* __restrict__ row_ptr, const int* __restrict__ blk) {
    const int i = blockIdx.x * 256 + threadIdx.x;
    if (i < N_NODES) row_ptr[i + 1] += blk[i >> 8];
    if (i == 0) row_ptr[0] = 0;
}

__global__ void cursor_kernel(const int* __restrict__ row_ptr, int* __restrict__ cursor) {
    const int i = blockIdx.x * 256 + threadIdx.x;
    if (i < N_NODES) cursor[i] = row_ptr[i];
}

__global__ void fill_kernel(const int* __restrict__ src, const int* __restrict__ dst,
                            int* __restrict__ cursor, int* __restrict__ eids) {
    const int e = blockIdx.x * 256 + threadIdx.x;
    if (e < N_EDGES) {
        const int pos = atomicAdd(&cursor[dst[e]], 1);
        eids[pos] = src[e];
    }
}

// ------- segment sort: deterministic eids order (replay-stable fp32 sums) -------
__global__ void sort_kernel(const int* __restrict__ row_ptr, int* __restrict__ eids) {
    const int n = blockIdx.x * 256 + threadIdx.x;
    if (n < N_NODES) {
        const int s = row_ptr[n], e = row_ptr[n + 1];
        for (int i = s + 1; i < e; ++i) {
            const int v = eids[i];
            int j = i - 1;
            while (j >= s && eids[j] > v) { eids[j + 1] = eids[j]; --j; }
            eids[j + 1] = v;
        }
    }
}

// ------- gather: z = h + sum_neigh h (bf16 h, fp32 acc); write bf16 [n][HDIM] -------
__global__ void gather_kernel(const unsigned short* __restrict__ h,
                              const int* __restrict__ row_ptr,
                              const int* __restrict__ eids, unsigned short* __restrict__ z) {
    const int tid = threadIdx.x;
    const int n = blockIdx.x * 4 + (tid >> 6);
    const int t = tid & 63;
    const ushort4* h4 = (const ushort4*)h;          // 4 bf16 per lane (8B)
    ushort4 hv = h4[(size_t)n * 64 + t];
    float4 acc = make_float4(bf2f(hv.x), bf2f(hv.y), bf2f(hv.z), bf2f(hv.w));
    const int s = row_ptr[n], e = row_ptr[n + 1];
    for (int i = s; i < e; ++i) {
        const ushort4 v = h4[(size_t)eids[i] * 64 + t];
        acc.x += bf2f(v.x); acc.y += bf2f(v.y);
        acc.z += bf2f(v.z); acc.w += bf2f(v.w);
    }
    ushort4 pk;
    pk.x = f2bf(acc.x); pk.y = f2bf(acc.y);
    pk.z = f2bf(acc.z); pk.w = f2bf(acc.w);
    ((ushort4*)(z + (size_t)n * HDIM))[t] = pk;
}

// ------- fused weight prep: all weights -> transposed [N][K] bf16, one dispatch -------
__global__ void wprep_all(const float* __restrict__ W1, const float* __restrict__ W2,
                          const float* __restrict__ Wf1, const float* __restrict__ Wf2,
                          const float* __restrict__ Wa,
                          unsigned short* __restrict__ t1, unsigned short* __restrict__ t2,
                          unsigned short* __restrict__ tf1, unsigned short* __restrict__ tf2,
                          unsigned short* __restrict__ tat) {
    const int WSZ = HDIM * 2 * HDIM;                 // 131072
    const int T0 = 8 * WSZ;                          // W1+W2
    const int T1 = T0 + HDIM * HDIM;                 // +Wf1
    const int T2 = T1 + HDIM * EDIM;                 // +Wf2
    const int T3 = T2 + 64 * HDIM;                   // +W_atom (padded K=64)
    const int stride = gridDim.x * 256;
    for (int idx = blockIdx.x * 256 + threadIdx.x; idx < T3; idx += stride) {
        if (idx < 4 * WSZ) {                         // W1: K=256, N=512 -> t1 [512][256]
            const int l = idx >> 17, e = idx & (WSZ - 1);
            const int k = e >> 9, n = e & 511;
            t1[(size_t)l * WSZ + n * HDIM + k] = f2bf(W1[idx]);
        } else if (idx < T0) {                       // W2: K=512, N=256 -> t2 [256][512]
            const int r = idx - 4 * WSZ;
            const int l = r >> 17, e = r & (WSZ - 1);
            const int k = e >> 8, n = e & 255;
            t2[(size_t)l * WSZ + n * EDIM + k] = f2bf(W2[r]);
        } else if (idx < T1) {                       // Wf1 -> tf1 [256][256]
            const int e = idx - T0;
            const int k = e >> 8, n = e & 255;
            tf1[n * HDIM + k] = f2bf(Wf1[e]);
        } else if (idx < T2) {                       // Wf2: K=256, N=512 -> tf2 [512][256]
            const int e = idx - T1;
            const int k = e >> 9, n = e & 511;
            tf2[n * HDIM + k] = f2bf(Wf2[e]);
        } else {                                     // W_atom: [44][256] -> tat [256][64] pad0
            const int e = idx - T2;                  // e over 64*256, k-major per n
            const int n = e >> 6, k = e & 63;
            tat[n * 64 + k] = (k < F_IN) ? f2bf(Wa[k * HDIM + n]) : (unsigned short)0;
        }
    }
}

// ---------------- MFMA GEMM (m97 structure): C = act(A @ B + bias) ----------------
// A [M][KK] bf16 row-major, BT [N][KK] bf16. KK multiple of 64. N multiple of 128.
// 128x128 tile, BK=64, 4 waves (2x2 of 64x64), single-buffered LDS [128][64]us x2 (32KB),
// plain __syncthreads only (compiler schedules waitcnts - no inline asm, per m141 lesson).
// Granule XOR swizzle: 8 x 16B granules/row, phys = g ^ (row&7); staged by pre-swizzling
// the per-lane GLOBAL source (LDS dest stays linear for global_load_lds).
// Tile order: COL-FASTEST (r15 fix) — consecutive (remapped) blocks share one A row-panel
// across all col panels on the same XCD -> A fetched from HBM once (r15 measured 2x
// A-over-fetch with row-fastest: FETCH 100MB vs 51.5MB ideal on GEMM1).
// OUT: 0 = fp32, 2 = bf16+relu via LDS-staged COALESCED writes (r12: fixes 2.3x RMW ampl.)
template <int OUT>
__global__ __launch_bounds__(256)
void gemm_mfma(const unsigned short* __restrict__ A, const unsigned short* __restrict__ BT,
               const float* __restrict__ bias, float* __restrict__ C,
               unsigned short* __restrict__ Z, int M, int N, int KK) {
    // As = lds_all[0..8191], Bs = lds_all[8192..16383];
    // OUT=2 epilogue reuses lds_all as padded bf16 tile [128][136] (17408 us = 34 KB).
    __shared__ __align__(16) unsigned short lds_all[17408];
    unsigned short* As = lds_all;
    unsigned short* Bs = lds_all + 8192;

    const int ncol = N >> 7;
    const int G = gridDim.x;
    int wg = blockIdx.x;
    {   // bijective XCD remap (m204)
        const int q = G >> 3, r = G & 7;
        const int xx = wg & 7, o = wg >> 3;
        wg = (xx < r ? xx * (q + 1) : r * (q + 1) + (xx - r) * q) + o;
    }
    const int col0 = (wg % ncol) << 7;    // col fastest: A row-panel shared by
    const int row0 = (wg / ncol) << 7;    // ncol consecutive blocks (same XCD L2)

    const int tid = threadIdx.x;
    const int lane = tid & 63;
    const int w = tid >> 6;
    const int wr = w >> 1, wc = w & 1;
    const int lr = lane & 15;
    const int l4 = lane >> 4;

    // staging geometry: per pass, thread covers row (pass*32 + tid>>3), phys granule tid&7.
    // source logical granule = (tid&7) ^ ((tid>>3)&7); LDS stays linear (slot = pass*256+tid).
    const int srow = tid >> 3;                              // 0..31
    const int sgran = ((tid & 7) ^ (srow & 7)) << 3;        // ushort offset within row

    floatx4 acc[4][4];
#pragma unroll
    for (int m = 0; m < 4; ++m)
#pragma unroll
        for (int n = 0; n < 4; ++n) acc[m][n] = (floatx4){0.f, 0.f, 0.f, 0.f};

    const int NT = KK >> 6;
    for (int t = 0; t < NT; ++t) {
        const int k0 = t << 6;
        __syncthreads();                 // previous tile fully consumed
#pragma unroll
        for (int pass = 0; pass < 4; ++pass) {
            const int r = (pass << 5) + srow;               // 0..127
            int ar = row0 + r; if (ar >= M) ar = M - 1;     // clamp
            gload16(A + (size_t)ar * KK + k0 + sgran, &As[(pass << 11) + (w << 9)]);
            gload16(BT + (size_t)(col0 + r) * KK + k0 + sgran, &Bs[(pass << 11) + (w << 9)]);
        }
        __syncthreads();                 // compiler inserts vmcnt drain before barrier

#pragma unroll
        for (int s = 0; s < 2; ++s) {
            const int pg = (((s << 2) + l4) ^ (lr & 7)) << 3;   // swizzled granule (ushorts)
            bhalf8 fa[4], fb[4];
#pragma unroll
            for (int m = 0; m < 4; ++m)
                fa[m] = *(const bhalf8*)&As[((wr << 6) + (m << 4) + lr) * 64 + pg];
#pragma unroll
            for (int n = 0; n < 4; ++n)
                fb[n] = *(const bhalf8*)&Bs[((wc << 6) + (n << 4) + lr) * 64 + pg];
#pragma unroll
            for (int m = 0; m < 4; ++m)
#pragma unroll
                for (int n = 0; n < 4; ++n)
                    acc[m][n] = __builtin_amdgcn_mfma_f32_16x16x32_bf16(fa[m], fb[n], acc[m][n], 0, 0, 0);
        }
    }

    // epilogue: C/D layout col = lane&15, row = (lane>>4)*4 + j
    const int rgrp = l4 * 4;
    if (OUT == 2) {
        __syncthreads();                 // done reading As/Bs this tile
        // stage bf16 tile into padded LDS [128][136] (272B rows: 16B-aligned, bank-rotated)
#pragma unroll
        for (int n = 0; n < 4; ++n) {
            const int colt = (wc << 6) + (n << 4) + lr;
            const float bv = bias[col0 + colt];
#pragma unroll
            for (int m = 0; m < 4; ++m) {
                const int rwt = (wr << 6) + (m << 4) + rgrp;
#pragma unroll
                for (int j = 0; j < 4; ++j)
                    lds_all[(rwt + j) * 136 + colt] = f2bf(fmaxf(acc[m][n][j] + bv, 0.f));
            }
        }
        __syncthreads();
        // coalesced copy-out: 2 threads per row, 128B (8 x uint4) each
        const int orow = tid >> 1;
        const int ocol = (tid & 1) << 6;
        if (row0 + orow < M) {
            const uint4* sp = (const uint4*)(lds_all + orow * 136 + ocol);
            uint4* dp = (uint4*)(Z + (size_t)(row0 + orow) * N + col0 + ocol);
#pragma unroll
            for (int q = 0; q < 8; ++q) dp[q] = sp[q];
        }
    } else {
#pragma unroll
        for (int n = 0; n < 4; ++n) {
            const int col = col0 + (wc << 6) + (n << 4) + lr;
            const float bv = bias[col];
#pragma unroll
            for (int m = 0; m < 4; ++m) {
                const int rw = row0 + (wr << 6) + (m << 4) + rgrp;
#pragma unroll
                for (int j = 0; j < 4; ++j) {
                    const int row = rw + j;
                    if (row < M) C[(size_t)row * N + col] = acc[m][n][j] + bv;
                }
            }
        }
    }
}

// ------- pool: sorted-batch segment mean over bf16 h -> bf16 [g][HDIM] -------
__global__ void pool_kernel(const unsigned short* __restrict__ h,
                            const int* __restrict__ batch,
                            unsigned short* __restrict__ gz) {
    __shared__ int sse[2];
    const int g = blockIdx.x;
    if (threadIdx.x < 2) {
        const int target = g + threadIdx.x;
        int lo = 0, hi = N_NODES;
        while (lo < hi) {
            const int mid = (lo + hi) >> 1;
            if (batch[mid] < target) lo = mid + 1; else hi = mid;
        }
        sse[threadIdx.x] = lo;
    }
    __syncthreads();
    const int s = sse[0], e = sse[1];
    const int j = threadIdx.x;
    float acc = 0.f;
    for (int n = s; n < e; ++n) acc += bf2f(h[(size_t)n * HDIM + j]);
    const float v = acc * ((e > s) ? 1.f / (float)(e - s) : 1.f);
    gz[(size_t)g * HDIM + j] = f2bf(v);
}

extern "C" void kernel_launch(void* const* d_in, const int* in_sizes, int n_in,
                              void* d_out, int out_size, void* d_ws, size_t ws_size,
                              hipStream_t stream) {
    const float* x      = (const float*)d_in[0];
    const int*   eidx   = (const int*)d_in[1];
    const int*   batch  = (const int*)d_in[2];
    const float* W_atom = (const float*)d_in[3];
    const float* b_atom = (const float*)d_in[4];
    const float* W1     = (const float*)d_in[5];
    const float* b1     = (const float*)d_in[6];
    const float* W2     = (const float*)d_in[7];
    const float* b2     = (const float*)d_in[8];
    const float* Wf1    = (const float*)d_in[9];
    const float* bf1    = (const float*)d_in[10];
    const float* Wf2    = (const float*)d_in[11];
    const float* bf2    = (const float*)d_in[12];
    float* out = (float*)d_out;

    const int* src = eidx;
    const int* dst = eidx + N_EDGES;

    const size_t NH = (size_t)N_NODES * HDIM;           // 25.6M elems
    const int WSZ = HDIM * 2 * HDIM;                    // 131072 elems per layer weight

    // ---- workspace layout ----
    char* base = (char*)d_ws;
    size_t off = 0;
    unsigned short* h = (unsigned short*)(base + off);      off += NH * 2;  // bf16 [N][256]
    unsigned short* zin = (unsigned short*)(base + off);    off += NH * 2;  // bf16 [N][256]
    unsigned short* xb = (unsigned short*)(base + off);     off += (size_t)N_NODES * 64 * 2;
    int* deg     = (int*)(base + off);            off += (size_t)N_NODES * 4;
    int* row_ptr = (int*)(base + off);            off += (size_t)(N_NODES + 1) * 4;
    int* cursor  = (int*)(base + off);            off += (size_t)N_NODES * 4;
    int* eids    = (int*)(base + off);            off += (size_t)N_EDGES * 4;
    int* blk     = (int*)(base + off);            off += 512 * 4;
    off = (off + 255) & ~(size_t)255;
    unsigned short* t1 = (unsigned short*)(base + off); off += (size_t)NLAYERS * WSZ * 2;
    unsigned short* t2 = (unsigned short*)(base + off); off += (size_t)NLAYERS * WSZ * 2;
    unsigned short* tf1 = (unsigned short*)(base + off); off += (size_t)HDIM * HDIM * 2;
    unsigned short* tf2 = (unsigned short*)(base + off); off += (size_t)HDIM * EDIM * 2;
    unsigned short* tat = (unsigned short*)(base + off); off += (size_t)HDIM * 64 * 2;
    off = (off + 255) & ~(size_t)255;

    const size_t avail = (ws_size > off) ? ws_size - off : 0;
    long chunk = (long)(avail / ((size_t)EDIM * 2));       // z2 row = 512 bf16 = 1 KB
    if (chunk >= N_NODES) chunk = N_NODES;                 // single chunk (z2 102MB, L3-res)
    else chunk &= ~127L;
    if (chunk < 128) chunk = 128;
    unsigned short* z2 = (unsigned short*)(base + off);    // [chunk][512] bf16

    // head buffers overlap the (dead-after-layers) zin region
    const size_t GH = (size_t)N_GRAPHS * HDIM;
    unsigned short* hg  = zin;            // [4000][256] bf16
    unsigned short* hg1 = zin + GH;       // [4000][256] bf16

    const int nb = (N_NODES + 255) / 256;

    // 1. x -> bf16 padded [N][64]; weights -> transposed bf16 (one dispatch each)
    xprep_kernel<<<1024, 256, 0, stream>>>(x, xb);
    wprep_all<<<1024, 256, 0, stream>>>(W1, W2, Wf1, Wf2, W_atom, t1, t2, tf1, tf2, tat);

    // 2. CSR build (+ deterministic segment sort)
    zero_kernel<<<128, 256, 0, stream>>>((float*)deg, N_NODES / 4);
    hist_kernel<<<(N_EDGES + 255) / 256, 256, 0, stream>>>(dst, deg);
    scan1_kernel<<<nb, 256, 0, stream>>>(deg, row_ptr, blk);
    scan2_kernel<<<1, 64, 0, stream>>>(blk, nb);
    scan3_kernel<<<nb, 256, 0, stream>>>(row_ptr, blk);
    cursor_kernel<<<nb, 256, 0, stream>>>(row_ptr, cursor);
    fill_kernel<<<(N_EDGES + 255) / 256, 256, 0, stream>>>(src, dst, cursor, eids);
    sort_kernel<<<nb, 256, 0, stream>>>(row_ptr, eids);   // deterministic gather order

    // 3. atom MLP as MFMA GEMM: h = relu(xb @ W_atom + b_atom)  [100000, 256], KK=64
    {
        const int nrow1 = (N_NODES + 127) / 128;
        gemm_mfma<2><<<2 * nrow1, 256, 0, stream>>>(
            xb, tat, b_atom, nullptr, h, N_NODES, HDIM, 64);
    }

    // 4. GIN layers
    for (int l = 0; l < NLAYERS; ++l) {
        gather_kernel<<<N_NODES / 4, 256, 0, stream>>>(h, row_ptr, eids, zin);
        for (long r0 = 0; r0 < N_NODES; r0 += chunk) {
            const int mc = (int)((N_NODES - r0 < chunk) ? (N_NODES - r0) : chunk);
            const int nrow1 = (mc + 127) / 128;
            // z2 = relu(zin @ W1[l] + b1[l])  [mc, 512] -> bf16 (coalesced LDS-staged)
            gemm_mfma<2><<<4 * nrow1, 256, 0, stream>>>(
                zin + (size_t)r0 * HDIM, t1 + (size_t)l * WSZ,
                b1 + (size_t)l * 2 * HDIM, nullptr, z2, mc, 2 * HDIM, HDIM);
            // h = relu(z2 @ W2[l] + b2[l])    [mc, 256] -> bf16 (coalesced LDS-staged)
            gemm_mfma<2><<<2 * nrow1, 256, 0, stream>>>(
                z2, t2 + (size_t)l * WSZ,
                b2 + (size_t)l * HDIM, nullptr, h + (size_t)r0 * HDIM, mc, HDIM, 2 * HDIM);
        }
    }

    // 5. pool (bf16 in/out)
    pool_kernel<<<N_GRAPHS, HDIM, 0, stream>>>(h, batch, hg);

    // 6. head
    gemm_mfma<2><<<2 * ((N_GRAPHS + 127) / 128), 256, 0, stream>>>(
        hg, tf1, bf1, nullptr, hg1, N_GRAPHS, HDIM, HDIM);
    gemm_mfma<0><<<4 * ((N_GRAPHS + 127) / 128), 256, 0, stream>>>(
        hg1, tf2, bf2, out, nullptr, N_GRAPHS, EDIM, HDIM);
}

// Round 17
// 762.776 us; speedup vs baseline: 2.5904x; 1.0012x over previous
//
#include <hip/hip_runtime.h>

#define N_NODES 100000
#define N_EDGES 200000
#define N_GRAPHS 4000
#define F_IN 44
#define HDIM 256
#define EDIM 512
#define NLAYERS 4

typedef float floatx4 __attribute__((ext_vector_type(4)));
typedef short bhalf8 __attribute__((ext_vector_type(8)));

__device__ __forceinline__ unsigned short f2bf(float f) {
    unsigned int u = __float_as_uint(f);
    u += 0x7FFFu + ((u >> 16) & 1u);          // RNE
    return (unsigned short)(u >> 16);
}
__device__ __forceinline__ float bf2f(unsigned short s) {
    return __uint_as_float(((unsigned int)s) << 16);
}

// async global->LDS, 16B/lane. ldst wave-uniform base; gsrc per-lane.
__device__ __forceinline__ void gload16(const void* gsrc, void* ldst) {
    __builtin_amdgcn_global_load_lds(
        (const __attribute__((address_space(1))) void*)gsrc,
        (__attribute__((address_space(3))) void*)ldst, 16, 0, 0);
}

// ---------------- zero fill ----------------
__global__ void zero_kernel(float* __restrict__ p, size_t n4) {
    size_t i = (size_t)blockIdx.x * blockDim.x + threadIdx.x;
    const size_t stride = (size_t)gridDim.x * blockDim.x;
    const float4 z = make_float4(0.f, 0.f, 0.f, 0.f);
    for (; i < n4; i += stride) ((float4*)p)[i] = z;
}

// ------- xprep: x fp32 [N][44] -> xb bf16 [N][64] zero-padded (coalesced 8B writes) -------
__global__ void xprep_kernel(const float* __restrict__ x, unsigned short* __restrict__ xb) {
    int idx = blockIdx.x * 256 + threadIdx.x;
    const int total = N_NODES * 16;               // 16 x ushort4 slots per node
    const int stride = gridDim.x * 256;
    for (; idx < total; idx += stride) {
        const int n = idx >> 4, k4 = idx & 15;
        ushort4 v = make_ushort4(0, 0, 0, 0);
        if (k4 < F_IN / 4) {                      // 11 valid float4 slots
            const float4 xv = *(const float4*)(x + (size_t)n * F_IN + k4 * 4);
            v.x = f2bf(xv.x); v.y = f2bf(xv.y); v.z = f2bf(xv.z); v.w = f2bf(xv.w);
        }
        *(ushort4*)(xb + (size_t)n * 64 + k4 * 4) = v;
    }
}

// ---------------- CSR build ----------------
__global__ void hist_kernel(const int* __restrict__ dst, int* __restrict__ deg) {
    const int e = blockIdx.x * 256 + threadIdx.x;
    if (e < N_EDGES) atomicAdd(&deg[dst[e]], 1);
}

__global__ void scan1_kernel(const int* __restrict__ deg, int* __restrict__ row_ptr,
                             int* __restrict__ blk) {
    __shared__ int s[256];
    const int i = blockIdx.x * 256 + threadIdx.x;
    s[threadIdx.x] = (i < N_NODES) ? deg[i] : 0;
    __syncthreads();
    for (int off = 1; off < 256; off <<= 1) {
        int t = (threadIdx.x >= off) ? s[threadIdx.x - off] : 0;
        __syncthreads();
        s[threadIdx.x] += t;
        __syncthreads();
    }
    if (i < N_NODES) row_ptr[i + 1] = s[threadIdx.x];
    if (threadIdx.x == 255) blk[blockIdx.x] = s[255];
}

__global__ void scan2_kernel(int* __restrict__ blk, int nb) {
    if (threadIdx.x == 0 && blockIdx.x == 0) {
        int run = 0;
        for (int b = 0; b < nb; ++b) { const int t = blk[b]; blk[b] = run; run += t; }
    }
}

__global__ void scan3_kernel(int* __restrict__ row_ptr, const int* __restrict__ blk) {
    const int i = blockIdx.x * 256 + threadIdx.x;
    if (i < N_NODES) row_ptr[i + 1] += blk[i >> 8];
    if (i == 0) row_ptr[0] = 0;
}

__global__ void cursor_kernel(const int* __restrict__ row_ptr, int* __restrict__ cursor) {
    const int i = blockIdx.x * 256 + threadIdx.x;
    if (i < N_NODES) cursor[i] = row_ptr[i];
}

__global__ void fill_kernel(const int* __restrict__ src, const int* __restrict__ dst,
                            int* __restrict__ cursor, int* __restrict__ eids) {
    const int e = blockIdx.x * 256 + threadIdx.x;
    if (e < N_EDGES) {
        const int pos = atomicAdd(&cursor[dst[e]], 1);
        eids[pos] = src[e];
    }
}

// ------- segment sort: deterministic eids order (replay-stable fp32 sums) -------
__global__ void sort_kernel(const int* __restrict__ row_ptr, int* __restrict__ eids) {
    const int n = blockIdx.x * 256 + threadIdx.x;
    if (n < N_NODES) {
        const int s = row_ptr[n], e = row_ptr[n + 1];
        for (int i = s + 1; i < e; ++i) {
            const int v = eids[i];
            int j = i - 1;
            while (j >= s && eids[j] > v) { eids[j + 1] = eids[j]; --j; }
            eids[j + 1] = v;
        }
    }
}

// ------- gather: z = h + sum_neigh h (bf16 h, fp32 acc); write bf16 [n][HDIM] -------
__global__ void gather_kernel(const unsigned short* __restrict__ h,
                              const int* __restrict__ row_ptr,
                              const int* __restrict__ eids, unsigned short* __restrict__ z) {
    const int tid = threadIdx.x;
    const int n = blockIdx.x * 4 + (tid >> 6);
    const int t = tid & 63;
    const ushort4* h4 = (const ushort4*)h;          // 4 bf16 per lane (8B)
    ushort4 hv = h4[(size_t)n * 64 + t];
    float4 acc = make_float4(bf2f(hv.x), bf2f(hv.y), bf2f(hv.z), bf2f(hv.w));
    const int s = row_ptr[n], e = row_ptr[n + 1];
    for (int i = s; i < e; ++i) {
        const ushort4 v = h4[(size_t)eids[i] * 64 + t];
        acc.x += bf2f(v.x); acc.y += bf2f(v.y);
        acc.z += bf2f(v.z); acc.w += bf2f(v.w);
    }
    ushort4 pk;
    pk.x = f2bf(acc.x); pk.y = f2bf(acc.y);
    pk.z = f2bf(acc.z); pk.w = f2bf(acc.w);
    ((ushort4*)(z + (size_t)n * HDIM))[t] = pk;
}

// ------- fused weight prep: all weights -> transposed [N][K] bf16, one dispatch -------
__global__ void wprep_all(const float* __restrict__ W1, const float* __restrict__ W2,
                          const float* __restrict__ Wf1, const float* __restrict__ Wf2,
                          const float* __restrict__ Wa,
                          unsigned short* __restrict__ t1, unsigned short* __restrict__ t2,
                          unsigned short* __restrict__ tf1, unsigned short* __restrict__ tf2,
                          unsigned short* __restrict__ tat) {
    const int WSZ = HDIM * 2 * HDIM;                 // 131072
    const int T0 = 8 * WSZ;                          // W1+W2
    const int T1 = T0 + HDIM * HDIM;                 // +Wf1
    const int T2 = T1 + HDIM * EDIM;                 // +Wf2
    const int T3 = T2 + 64 * HDIM;                   // +W_atom (padded K=64)
    const int stride = gridDim.x * 256;
    for (int idx = blockIdx.x * 256 + threadIdx.x; idx < T3; idx += stride) {
        if (idx < 4 * WSZ) {                         // W1: K=256, N=512 -> t1 [512][256]
            const int l = idx >> 17, e = idx & (WSZ - 1);
            const int k = e >> 9, n = e & 511;
            t1[(size_t)l * WSZ + n * HDIM + k] = f2bf(W1[idx]);
        } else if (idx < T0) {                       // W2: K=512, N=256 -> t2 [256][512]
            const int r = idx - 4 * WSZ;
            const int l = r >> 17, e = r & (WSZ - 1);
            const int k = e >> 8, n = e & 255;
            t2[(size_t)l * WSZ + n * EDIM + k] = f2bf(W2[r]);
        } else if (idx < T1) {                       // Wf1 -> tf1 [256][256]
            const int e = idx - T0;
            const int k = e >> 8, n = e & 255;
            tf1[n * HDIM + k] = f2bf(Wf1[e]);
        } else if (idx < T2) {                       // Wf2: K=256, N=512 -> tf2 [512][256]
            const int e = idx - T1;
            const int k = e >> 9, n = e & 511;
            tf2[n * HDIM + k] = f2bf(Wf2[e]);
        } else {                                     // W_atom: [44][256] -> tat [256][64] pad0
            const int e = idx - T2;                  // e over 64*256, k-major per n
            const int n = e >> 6, k = e & 63;
            tat[n * 64 + k] = (k < F_IN) ? f2bf(Wa[k * HDIM + n]) : (unsigned short)0;
        }
    }
}

// ---------------- MFMA GEMM: C = act(A @ B + bias), counted-vmcnt double-buffer ----------
// A [M][KK] bf16 row-major, BT [N][KK] bf16. KK multiple of 64. N multiple of 128.
// 128x128 tile, BK=64, 4 waves (2x2 of 64x64). TWO LDS buffers (64KB total).
// K-loop (T4, r16): per step ONE counted s_waitcnt vmcnt(8) (prefetch of t+1 stays in
// flight across both raw s_barriers — never drains mid-loop), stage t+2 after the
// read-done barrier. No sched_barrier pins (m141), no lgkmcnt asm (compiler handles).
// Granule XOR swizzle: 8 x 16B granules/row, phys = g ^ (row&7); staged by pre-swizzling
// the per-lane GLOBAL source (LDS dest stays linear for global_load_lds).
// Tile order: COL-FASTEST (r15) — A row-panel shared across col panels on one XCD.
// OUT: 0 = fp32, 2 = bf16+relu via LDS-staged COALESCED writes (r12: fixes 2.3x RMW ampl.)
template <int OUT>
__global__ __launch_bounds__(256)
void gemm_mfma(const unsigned short* __restrict__ A, const unsigned short* __restrict__ BT,
               const float* __restrict__ bias, float* __restrict__ C,
               unsigned short* __restrict__ Z, int M, int N, int KK) {
    // two buffers of (As 8192us | Bs 8192us); OUT=2 epilogue reuses front 17408us (34KB)
    __shared__ __align__(16) unsigned short lds_all[32768];   // 64 KB

    const int ncol = N >> 7;
    const int G = gridDim.x;
    int wg = blockIdx.x;
    {   // bijective XCD remap (m204)
        const int q = G >> 3, r = G & 7;
        const int xx = wg & 7, o = wg >> 3;
        wg = (xx < r ? xx * (q + 1) : r * (q + 1) + (xx - r) * q) + o;
    }
    const int col0 = (wg % ncol) << 7;    // col fastest: A row-panel shared by
    const int row0 = (wg / ncol) << 7;    // ncol consecutive blocks (same XCD L2)

    const int tid = threadIdx.x;
    const int lane = tid & 63;
    const int w = tid >> 6;
    const int wr = w >> 1, wc = w & 1;
    const int lr = lane & 15;
    const int l4 = lane >> 4;

    // staging geometry: per pass, thread covers row (pass*32 + tid>>3), phys granule tid&7.
    // source logical granule = (tid&7) ^ ((tid>>3)&7); LDS stays linear.
    const int srow = tid >> 3;                              // 0..31
    const int sgran = ((tid & 7) ^ (srow & 7)) << 3;        // ushort offset within row

    floatx4 acc[4][4];
#pragma unroll
    for (int m = 0; m < 4; ++m)
#pragma unroll
        for (int n = 0; n < 4; ++n) acc[m][n] = (floatx4){0.f, 0.f, 0.f, 0.f};

    const int NT = KK >> 6;

    // stage tile t into buffer b: 8 gload16 per thread (4 passes x A,B)
    auto stage = [&](int t, int b) {
        const int k0 = t << 6;
        unsigned short* la = &lds_all[b * 16384];
        unsigned short* lb = la + 8192;
#pragma unroll
        for (int pass = 0; pass < 4; ++pass) {
            const int r = (pass << 5) + srow;               // 0..127
            int ar = row0 + r; if (ar >= M) ar = M - 1;     // clamp (uniform vmcnt)
            gload16(A + (size_t)ar * KK + k0 + sgran, &la[(pass << 11) + (w << 9)]);
            gload16(BT + (size_t)(col0 + r) * KK + k0 + sgran, &lb[(pass << 11) + (w << 9)]);
        }
    };

    stage(0, 0);
    if (NT > 1) stage(1, 1);
    for (int t = 0; t < NT; ++t) {
        const int cur = t & 1;
        if (t + 1 < NT) {
            asm volatile("s_waitcnt vmcnt(8)" ::: "memory");   // t landed; t+1 in flight
        } else {
            asm volatile("s_waitcnt vmcnt(0)" ::: "memory");
        }
        __builtin_amdgcn_s_barrier();                          // tile t visible to all

        const unsigned short* la = &lds_all[cur * 16384];
        const unsigned short* lb = la + 8192;
#pragma unroll
        for (int s = 0; s < 2; ++s) {
            const int pg = (((s << 2) + l4) ^ (lr & 7)) << 3;  // swizzled granule (ushorts)
            bhalf8 fa[4], fb[4];
#pragma unroll
            for (int m = 0; m < 4; ++m)
                fa[m] = *(const bhalf8*)&la[((wr << 6) + (m << 4) + lr) * 64 + pg];
#pragma unroll
            for (int n = 0; n < 4; ++n)
                fb[n] = *(const bhalf8*)&lb[((wc << 6) + (n << 4) + lr) * 64 + pg];
#pragma unroll
            for (int m = 0; m < 4; ++m)
#pragma unroll
                for (int n = 0; n < 4; ++n)
                    acc[m][n] = __builtin_amdgcn_mfma_f32_16x16x32_bf16(fa[m], fb[n], acc[m][n], 0, 0, 0);
        }

        __builtin_amdgcn_s_barrier();                          // all waves done reading cur
        if (t + 2 < NT) stage(t + 2, cur);                     // overwrite cur; flies over
    }                                                          // next iter's wait+barriers

    // epilogue: C/D layout col = lane&15, row = (lane>>4)*4 + j
    const int rgrp = l4 * 4;
    if (OUT == 2) {
        __syncthreads();                 // drain + barrier before aliasing buffers
        // stage bf16 tile into padded LDS [128][136] (272B rows: 16B-aligned, bank-rotated)
#pragma unroll
        for (int n = 0; n < 4; ++n) {
            const int colt = (wc << 6) + (n << 4) + lr;
            const float bv = bias[col0 + colt];
#pragma unroll
            for (int m = 0; m < 4; ++m) {
                const int rwt = (wr << 6) + (m << 4) + rgrp;
#pragma unroll
                for (int j = 0; j < 4; ++j)
                    lds_all[(rwt + j) * 136 + colt] = f2bf(fmaxf(acc[m][n][j] + bv, 0.f));
            }
        }
        __syncthreads();
        // coalesced copy-out: 2 threads per row, 128B (8 x uint4) each
        const int orow = tid >> 1;
        const int ocol = (tid & 1) << 6;
        if (row0 + orow < M) {
            const uint4* sp = (const uint4*)(lds_all + orow * 136 + ocol);
            uint4* dp = (uint4*)(Z + (size_t)(row0 + orow) * N + col0 + ocol);
#pragma unroll
            for (int q = 0; q < 8; ++q) dp[q] = sp[q];
        }
    } else {
#pragma unroll
        for (int n = 0; n < 4; ++n) {
            const int col = col0 + (wc << 6) + (n << 4) + lr;
            const float bv = bias[col];
#pragma unroll
            for (int m = 0; m < 4; ++m) {
                const int rw = row0 + (wr << 6) + (m << 4) + rgrp;
#pragma unroll
                for (int j = 0; j < 4; ++j) {
                    const int row = rw + j;
                    if (row < M) C[(size_t)row * N + col] = acc[m][n][j] + bv;
                }
            }
        }
    }
}

// ------- pool: sorted-batch segment mean over bf16 h -> bf16 [g][HDIM] -------
__global__ void pool_kernel(const unsigned short* __restrict__ h,
                            const int* __restrict__ batch,
                            unsigned short* __restrict__ gz) {
    __shared__ int sse[2];
    const int g = blockIdx.x;
    if (threadIdx.x < 2) {
        const int target = g + threadIdx.x;
        int lo = 0, hi = N_NODES;
        while (lo < hi) {
            const int mid = (lo + hi) >> 1;
            if (batch[mid] < target) lo = mid + 1; else hi = mid;
        }
        sse[threadIdx.x] = lo;
    }
    __syncthreads();
    const int s = sse[0], e = sse[1];
    const int j = threadIdx.x;
    float acc = 0.f;
    for (int n = s; n < e; ++n) acc += bf2f(h[(size_t)n * HDIM + j]);
    const float v = acc * ((e > s) ? 1.f / (float)(e - s) : 1.f);
    gz[(size_t)g * HDIM + j] = f2bf(v);
}

extern "C" void kernel_launch(void* const* d_in, const int* in_sizes, int n_in,
                              void* d_out, int out_size, void* d_ws, size_t ws_size,
                              hipStream_t stream) {
    const float* x      = (const float*)d_in[0];
    const int*   eidx   = (const int*)d_in[1];
    const int*   batch  = (const int*)d_in[2];
    const float* W_atom = (const float*)d_in[3];
    const float* b_atom = (const float*)d_in[4];
    const float* W1     = (const float*)d_in[5];
    const float* b1     = (const float*)d_in[6];
    const float* W2     = (const float*)d_in[7];
    const float* b2     = (const float*)d_in[8];
    const float* Wf1    = (const float*)d_in[9];
    const float* bf1    = (const float*)d_in[10];
    const float* Wf2    = (const float*)d_in[11];
    const float* bf2    = (const float*)d_in[12];
    float* out = (float*)d_out;

    const int* src = eidx;
    const int* dst = eidx + N_EDGES;

    const size_t NH = (size_t)N_NODES * HDIM;           // 25.6M elems
    const int WSZ = HDIM * 2 * HDIM;                    // 131072 elems per layer weight

    // ---- workspace layout ----
    char* base = (char*)d_ws;
    size_t off = 0;
    unsigned short* h = (unsigned short*)(base + off);      off += NH * 2;  // bf16 [N][256]
    unsigned short* zin = (unsigned short*)(base + off);    off += NH * 2;  // bf16 [N][256]
    unsigned short* xb = (unsigned short*)(base + off);     off += (size_t)N_NODES * 64 * 2;
    int* deg     = (int*)(base + off);            off += (size_t)N_NODES * 4;
    int* row_ptr = (int*)(base + off);            off += (size_t)(N_NODES + 1) * 4;
    int* cursor  = (int*)(base + off);            off += (size_t)N_NODES * 4;
    int* eids    = (int*)(base + off);            off += (size_t)N_EDGES * 4;
    int* blk     = (int*)(base + off);            off += 512 * 4;
    off = (off + 255) & ~(size_t)255;
    unsigned short* t1 = (unsigned short*)(base + off); off += (size_t)NLAYERS * WSZ * 2;
    unsigned short* t2 = (unsigned short*)(base + off); off += (size_t)NLAYERS * WSZ * 2;
    unsigned short* tf1 = (unsigned short*)(base + off); off += (size_t)HDIM * HDIM * 2;
    unsigned short* tf2 = (unsigned short*)(base + off); off += (size_t)HDIM * EDIM * 2;
    unsigned short* tat = (unsigned short*)(base + off); off += (size_t)HDIM * 64 * 2;
    off = (off + 255) & ~(size_t)255;

    const size_t avail = (ws_size > off) ? ws_size - off : 0;
    long chunk = (long)(avail / ((size_t)EDIM * 2));       // z2 row = 512 bf16 = 1 KB
    if (chunk >= N_NODES) chunk = N_NODES;                 // single chunk (z2 102MB, L3-res)
    else chunk &= ~127L;
    if (chunk < 128) chunk = 128;
    unsigned short* z2 = (unsigned short*)(base + off);    // [chunk][512] bf16

    // head buffers overlap the (dead-after-layers) zin region
    const size_t GH = (size_t)N_GRAPHS * HDIM;
    unsigned short* hg  = zin;            // [4000][256] bf16
    unsigned short* hg1 = zin + GH;       // [4000][256] bf16

    const int nb = (N_NODES + 255) / 256;

    // 1. x -> bf16 padded [N][64]; weights -> transposed bf16 (one dispatch each)
    xprep_kernel<<<1024, 256, 0, stream>>>(x, xb);
    wprep_all<<<1024, 256, 0, stream>>>(W1, W2, Wf1, Wf2, W_atom, t1, t2, tf1, tf2, tat);

    // 2. CSR build (+ deterministic segment sort)
    zero_kernel<<<128, 256, 0, stream>>>((float*)deg, N_NODES / 4);
    hist_kernel<<<(N_EDGES + 255) / 256, 256, 0, stream>>>(dst, deg);
    scan1_kernel<<<nb, 256, 0, stream>>>(deg, row_ptr, blk);
    scan2_kernel<<<1, 64, 0, stream>>>(blk, nb);
    scan3_kernel<<<nb, 256, 0, stream>>>(row_ptr, blk);
    cursor_kernel<<<nb, 256, 0, stream>>>(row_ptr, cursor);
    fill_kernel<<<(N_EDGES + 255) / 256, 256, 0, stream>>>(src, dst, cursor, eids);
    sort_kernel<<<nb, 256, 0, stream>>>(row_ptr, eids);   // deterministic gather order

    // 3. atom MLP as MFMA GEMM: h = relu(xb @ W_atom + b_atom)  [100000, 256], KK=64
    {
        const int nrow1 = (N_NODES + 127) / 128;
        gemm_mfma<2><<<2 * nrow1, 256, 0, stream>>>(
            xb, tat, b_atom, nullptr, h, N_NODES, HDIM, 64);
    }

    // 4. GIN layers
    for (int l = 0; l < NLAYERS; ++l) {
        gather_kernel<<<N_NODES / 4, 256, 0, stream>>>(h, row_ptr, eids, zin);
        for (long r0 = 0; r0 < N_NODES; r0 += chunk) {
            const int mc = (int)((N_NODES - r0 < chunk) ? (N_NODES - r0) : chunk);
            const int nrow1 = (mc + 127) / 128;
            // z2 = relu(zin @ W1[l] + b1[l])  [mc, 512] -> bf16 (coalesced LDS-staged)
            gemm_mfma<2><<<4 * nrow1, 256, 0, stream>>>(
                zin + (size_t)r0 * HDIM, t1 + (size_t)l * WSZ,
                b1 + (size_t)l * 2 * HDIM, nullptr, z2, mc, 2 * HDIM, HDIM);
            // h = relu(z2 @ W2[l] + b2[l])    [mc, 256] -> bf16 (coalesced LDS-staged)
            gemm_mfma<2><<<2 * nrow1, 256, 0, stream>>>(
                z2, t2 + (size_t)l * WSZ,
                b2 + (size_t)l * HDIM, nullptr, h + (size_t)r0 * HDIM, mc, HDIM, 2 * HDIM);
        }
    }

    // 5. pool (bf16 in/out)
    pool_kernel<<<N_GRAPHS, HDIM, 0, stream>>>(h, batch, hg);

    // 6. head
    gemm_mfma<2><<<2 * ((N_GRAPHS + 127) / 128), 256, 0, stream>>>(
        hg, tf1, bf1, nullptr, hg1, N_GRAPHS, HDIM, HDIM);
    gemm_mfma<0><<<4 * ((N_GRAPHS + 127) / 128), 256, 0, stream>>>(
        hg1, tf2, bf2, out, nullptr, N_GRAPHS, EDIM, HDIM);
}

// Round 18
// 748.926 us; speedup vs baseline: 2.6383x; 1.0185x over previous
//
#include <hip/hip_runtime.h>

#define N_NODES 100000
#define N_EDGES 200000
#define N_GRAPHS 4000
#define F_IN 44
#define HDIM 256
#define EDIM 512
#define NLAYERS 4

typedef float floatx4 __attribute__((ext_vector_type(4)));
typedef short bhalf8 __attribute__((ext_vector_type(8)));

__device__ __forceinline__ unsigned short f2bf(float f) {
    unsigned int u = __float_as_uint(f);
    u += 0x7FFFu + ((u >> 16) & 1u);          // RNE
    return (unsigned short)(u >> 16);
}
__device__ __forceinline__ float bf2f(unsigned short s) {
    return __uint_as_float(((unsigned int)s) << 16);
}

// async global->LDS, 16B/lane. ldst wave-uniform base; gsrc per-lane.
__device__ __forceinline__ void gload16(const void* gsrc, void* ldst) {
    __builtin_amdgcn_global_load_lds(
        (const __attribute__((address_space(1))) void*)gsrc,
        (__attribute__((address_space(3))) void*)ldst, 16, 0, 0);
}

// ---------------- zero fill ----------------
__global__ void zero_kernel(float* __restrict__ p, size_t n4) {
    size_t i = (size_t)blockIdx.x * blockDim.x + threadIdx.x;
    const size_t stride = (size_t)gridDim.x * blockDim.x;
    const float4 z = make_float4(0.f, 0.f, 0.f, 0.f);
    for (; i < n4; i += stride) ((float4*)p)[i] = z;
}

// ------- xprep: x fp32 [N][44] -> xb bf16 [N][64] zero-padded (coalesced 8B writes) -------
__global__ void xprep_kernel(const float* __restrict__ x, unsigned short* __restrict__ xb) {
    int idx = blockIdx.x * 256 + threadIdx.x;
    const int total = N_NODES * 16;               // 16 x ushort4 slots per node
    const int stride = gridDim.x * 256;
    for (; idx < total; idx += stride) {
        const int n = idx >> 4, k4 = idx & 15;
        ushort4 v = make_ushort4(0, 0, 0, 0);
        if (k4 < F_IN / 4) {                      // 11 valid float4 slots
            const float4 xv = *(const float4*)(x + (size_t)n * F_IN + k4 * 4);
            v.x = f2bf(xv.x); v.y = f2bf(xv.y); v.z = f2bf(xv.z); v.w = f2bf(xv.w);
        }
        *(ushort4*)(xb + (size_t)n * 64 + k4 * 4) = v;
    }
}

// ---------------- CSR build ----------------
__global__ void hist_kernel(const int* __restrict__ dst, int* __restrict__ deg) {
    const int e = blockIdx.x * 256 + threadIdx.x;
    if (e < N_EDGES) atomicAdd(&deg[dst[e]], 1);
}

__global__ void scan1_kernel(const int* __restrict__ deg, int* __restrict__ row_ptr,
                             int* __restrict__ blk) {
    __shared__ int s[256];
    const int i = blockIdx.x * 256 + threadIdx.x;
    s[threadIdx.x] = (i < N_NODES) ? deg[i] : 0;
    __syncthreads();
    for (int off = 1; off < 256; off <<= 1) {
        int t = (threadIdx.x >= off) ? s[threadIdx.x - off] : 0;
        __syncthreads();
        s[threadIdx.x] += t;
        __syncthreads();
    }
    if (i < N_NODES) row_ptr[i + 1] = s[threadIdx.x];
    if (threadIdx.x == 255) blk[blockIdx.x] = s[255];
}

__global__ void scan2_kernel(int* __restrict__ blk, int nb) {
    if (threadIdx.x == 0 && blockIdx.x == 0) {
        int run = 0;
        for (int b = 0; b < nb; ++b) { const int t = blk[b]; blk[b] = run; run += t; }
    }
}

__global__ void scan3_kernel(int* __restrict__ row_ptr, const int* __restrict__ blk) {
    const int i = blockIdx.x * 256 + threadIdx.x;
    if (i < N_NODES) row_ptr[i + 1] += blk[i >> 8];
    if (i == 0) row_ptr[0] = 0;
}

__global__ void cursor_kernel(const int* __restrict__ row_ptr, int* __restrict__ cursor) {
    const int i = blockIdx.x * 256 + threadIdx.x;
    if (i < N_NODES) cursor[i] = row_ptr[i];
}

__global__ void fill_kernel(const int* __restrict__ src, const int* __restrict__ dst,
                            int* __restrict__ cursor, int* __restrict__ eids) {
    const int e = blockIdx.x * 256 + threadIdx.x;
    if (e < N_EDGES) {
        const int pos = atomicAdd(&cursor[dst[e]], 1);
        eids[pos] = src[e];
    }
}

// ------- segment sort: deterministic eids order (replay-stable fp32 sums) -------
__global__ void sort_kernel(const int* __restrict__ row_ptr, int* __restrict__ eids) {
    const int n = blockIdx.x * 256 + threadIdx.x;
    if (n < N_NODES) {
        const int s = row_ptr[n], e = row_ptr[n + 1];
        for (int i = s + 1; i < e; ++i) {
            const int v = eids[i];
            int j = i - 1;
            while (j >= s && eids[j] > v) { eids[j + 1] = eids[j]; --j; }
            eids[j + 1] = v;
        }
    }
}

// ------- gather: z = h + sum_neigh h (bf16 h, fp32 acc); write bf16 [n][HDIM] -------
__global__ void gather_kernel(const unsigned short* __restrict__ h,
                              const int* __restrict__ row_ptr,
                              const int* __restrict__ eids, unsigned short* __restrict__ z) {
    const int tid = threadIdx.x;
    const int n = blockIdx.x * 4 + (tid >> 6);
    const int t = tid & 63;
    const ushort4* h4 = (const ushort4*)h;          // 4 bf16 per lane (8B)
    ushort4 hv = h4[(size_t)n * 64 + t];
    float4 acc = make_float4(bf2f(hv.x), bf2f(hv.y), bf2f(hv.z), bf2f(hv.w));
    const int s = row_ptr[n], e = row_ptr[n + 1];
    for (int i = s; i < e; ++i) {
        const ushort4 v = h4[(size_t)eids[i] * 64 + t];
        acc.x += bf2f(v.x); acc.y += bf2f(v.y);
        acc.z += bf2f(v.z); acc.w += bf2f(v.w);
    }
    ushort4 pk;
    pk.x = f2bf(acc.x); pk.y = f2bf(acc.y);
    pk.z = f2bf(acc.z); pk.w = f2bf(acc.w);
    ((ushort4*)(z + (size_t)n * HDIM))[t] = pk;
}

// ------- fused weight prep: all weights -> transposed [N][K] bf16, one dispatch -------
__global__ void wprep_all(const float* __restrict__ W1, const float* __restrict__ W2,
                          const float* __restrict__ Wf1, const float* __restrict__ Wf2,
                          const float* __restrict__ Wa,
                          unsigned short* __restrict__ t1, unsigned short* __restrict__ t2,
                          unsigned short* __restrict__ tf1, unsigned short* __restrict__ tf2,
                          unsigned short* __restrict__ tat) {
    const int WSZ = HDIM * 2 * HDIM;                 // 131072
    const int T0 = 8 * WSZ;                          // W1+W2
    const int T1 = T0 + HDIM * HDIM;                 // +Wf1
    const int T2 = T1 + HDIM * EDIM;                 // +Wf2
    const int T3 = T2 + 64 * HDIM;                   // +W_atom (padded K=64)
    const int stride = gridDim.x * 256;
    for (int idx = blockIdx.x * 256 + threadIdx.x; idx < T3; idx += stride) {
        if (idx < 4 * WSZ) {                         // W1: K=256, N=512 -> t1 [512][256]
            const int l = idx >> 17, e = idx & (WSZ - 1);
            const int k = e >> 9, n = e & 511;
            t1[(size_t)l * WSZ + n * HDIM + k] = f2bf(W1[idx]);
        } else if (idx < T0) {                       // W2: K=512, N=256 -> t2 [256][512]
            const int r = idx - 4 * WSZ;
            const int l = r >> 17, e = r & (WSZ - 1);
            const int k = e >> 8, n = e & 255;
            t2[(size_t)l * WSZ + n * EDIM + k] = f2bf(W2[r]);
        } else if (idx < T1) {                       // Wf1 -> tf1 [256][256]
            const int e = idx - T0;
            const int k = e >> 8, n = e & 255;
            tf1[n * HDIM + k] = f2bf(Wf1[e]);
        } else if (idx < T2) {                       // Wf2: K=256, N=512 -> tf2 [512][256]
            const int e = idx - T1;
            const int k = e >> 9, n = e & 511;
            tf2[n * HDIM + k] = f2bf(Wf2[e]);
        } else {                                     // W_atom: [44][256] -> tat [256][64] pad0
            const int e = idx - T2;                  // e over 64*256, k-major per n
            const int n = e >> 6, k = e & 63;
            tat[n * 64 + k] = (k < F_IN) ? f2bf(Wa[k * HDIM + n]) : (unsigned short)0;
        }
    }
}

// ============ FUSED GIN LAYER: H = relu(relu(zin@W1+b1)@W2+b2), z2 never leaves LDS =======
// Per block: 128 rows x full 256-col output. 8 sub-chunks of 64 z2-cols:
//   phase A: z2c[128][64] = relu(zin[128][256] @ W1[:,c*64..] + b1c)  (acc_z 32 VGPR)
//   phase B: acc_h += z2c @ W2T[256][c*64..]                          (acc_h 128 VGPR)
// MFMA accumulation order identical to the unfused GEMM pair (ascending 32-k chunks)
// -> bit-identical h. Eliminates 100MB z2 write + ~100MB z2 read per layer.
// zbuf [128][72]us padded: row stride 144B -> dword-bank stride 4 -> 2-way max (free).
__global__ __launch_bounds__(256, 2)
void fused_layer(const unsigned short* __restrict__ zin, const unsigned short* __restrict__ T1,
                 const unsigned short* __restrict__ T2, const float* __restrict__ b1,
                 const float* __restrict__ b2, unsigned short* __restrict__ H, int M) {
    // stageA 8192 | stageB1 4096 | zbuf 9216 ([128][72]) | stageB2 16384  = 37888 us (74KB)
    // epilogue aliases front 33792 us as [128][264]
    __shared__ __align__(16) unsigned short lds[37888];
    unsigned short* sA  = lds;
    unsigned short* sB1 = lds + 8192;
    unsigned short* zb  = lds + 12288;
    unsigned short* sB2 = lds + 21504;

    const int G = gridDim.x;
    int wg = blockIdx.x;
    {   // bijective XCD remap (m204)
        const int q = G >> 3, r = G & 7;
        const int xx = wg & 7, o = wg >> 3;
        wg = (xx < r ? xx * (q + 1) : r * (q + 1) + (xx - r) * q) + o;
    }
    const int row0 = wg << 7;

    const int tid = threadIdx.x;
    const int lane = tid & 63;
    const int w = tid >> 6;
    const int wr = w >> 1, wc = w & 1;
    const int lr = lane & 15;
    const int l4 = lane >> 4;
    const int rgrp = l4 * 4;
    const int srow = tid >> 3;                              // 0..31
    const int sgran = ((tid & 7) ^ (srow & 7)) << 3;        // pre-swizzled src granule

    floatx4 acc_h[4][8];
#pragma unroll
    for (int m = 0; m < 4; ++m)
#pragma unroll
        for (int n = 0; n < 8; ++n) acc_h[m][n] = (floatx4){0.f, 0.f, 0.f, 0.f};

#pragma unroll 1
    for (int c = 0; c < 8; ++c) {
        floatx4 acc_z[4][2];
#pragma unroll
        for (int m = 0; m < 4; ++m)
#pragma unroll
            for (int n = 0; n < 2; ++n) acc_z[m][n] = (floatx4){0.f, 0.f, 0.f, 0.f};

        // ---- phase A: 4 K-steps over zin K=256 ----
#pragma unroll 1
        for (int t = 0; t < 4; ++t) {
            __syncthreads();             // stage buffers free
#pragma unroll
            for (int p = 0; p < 4; ++p) {                   // zin [128][64]
                const int r = (p << 5) + srow;
                int ar = row0 + r; if (ar >= M) ar = M - 1;
                gload16(zin + (size_t)ar * 256 + (t << 6) + sgran, &sA[(p << 11) + (w << 9)]);
            }
#pragma unroll
            for (int p = 0; p < 2; ++p) {                   // W1 slice rows c*64.. [64][64]
                const int r = (p << 5) + srow;
                gload16(T1 + (size_t)((c << 6) + r) * 256 + (t << 6) + sgran,
                        &sB1[(p << 11) + (w << 9)]);
            }
            __syncthreads();             // compiler drains vmcnt before barrier
#pragma unroll
            for (int s = 0; s < 2; ++s) {
                const int pg = (((s << 2) + l4) ^ (lr & 7)) << 3;
                bhalf8 fa[4], fb[2];
#pragma unroll
                for (int m = 0; m < 4; ++m)
                    fa[m] = *(const bhalf8*)&sA[((wr << 6) + (m << 4) + lr) * 64 + pg];
#pragma unroll
                for (int n = 0; n < 2; ++n)
                    fb[n] = *(const bhalf8*)&sB1[((wc << 5) + (n << 4) + lr) * 64 + pg];
#pragma unroll
                for (int m = 0; m < 4; ++m)
#pragma unroll
                    for (int n = 0; n < 2; ++n)
                        acc_z[m][n] = __builtin_amdgcn_mfma_f32_16x16x32_bf16(fa[m], fb[n], acc_z[m][n], 0, 0, 0);
            }
        }

        // ---- z2c -> zbuf (bf16, relu+bias), unswizzled [128][72] ----
#pragma unroll
        for (int n = 0; n < 2; ++n) {
            const int ck = (wc << 5) + (n << 4) + lr;       // 0..63
            const float bv = b1[(c << 6) + ck];
#pragma unroll
            for (int m = 0; m < 4; ++m) {
                const int rw = (wr << 6) + (m << 4) + rgrp;
#pragma unroll
                for (int j = 0; j < 4; ++j)
                    zb[(rw + j) * 72 + ck] = f2bf(fmaxf(acc_z[m][n][j] + bv, 0.f));
            }
        }
        // ---- stage W2T k-slice [256][64] (prev readers of sB2 long done) ----
#pragma unroll
        for (int p = 0; p < 8; ++p) {
            const int r = (p << 5) + srow;
            gload16(T2 + (size_t)r * 512 + (c << 6) + sgran, &sB2[(p << 11) + (w << 9)]);
        }
        __syncthreads();                 // zbuf visible + sB2 loaded (vmcnt drained)

        // ---- phase B: acc_h += zbuf[128][64] @ W2T-slice ----
#pragma unroll
        for (int s = 0; s < 2; ++s) {
            const int pg = (((s << 2) + l4) ^ (lr & 7)) << 3;
            const int zg = ((s << 2) + l4) << 3;            // zbuf granule (no swizzle)
            bhalf8 fa[4], fb[8];
#pragma unroll
            for (int m = 0; m < 4; ++m)
                fa[m] = *(const bhalf8*)&zb[((wr << 6) + (m << 4) + lr) * 72 + zg];
#pragma unroll
            for (int n = 0; n < 8; ++n)
                fb[n] = *(const bhalf8*)&sB2[((wc << 7) + (n << 4) + lr) * 64 + pg];
#pragma unroll
            for (int m = 0; m < 4; ++m)
#pragma unroll
                for (int n = 0; n < 8; ++n)
                    acc_h[m][n] = __builtin_amdgcn_mfma_f32_16x16x32_bf16(fa[m], fb[n], acc_h[m][n], 0, 0, 0);
        }
    }

    // ---- epilogue: relu+bias -> bf16, LDS-staged coalesced write (r12 pattern) ----
    __syncthreads();
#pragma unroll
    for (int n = 0; n < 8; ++n) {
        const int colt = (wc << 7) + (n << 4) + lr;
        const float bv = b2[colt];
#pragma unroll
        for (int m = 0; m < 4; ++m) {
            const int rwt = (wr << 6) + (m << 4) + rgrp;
#pragma unroll
            for (int j = 0; j < 4; ++j)
                lds[(rwt + j) * 264 + colt] = f2bf(fmaxf(acc_h[m][n][j] + bv, 0.f));
        }
    }
    __syncthreads();
    const int orow = tid >> 1;
    const int ohalf = (tid & 1) << 7;    // 128 us = 256B halves
    if (row0 + orow < M) {
        const uint4* sp = (const uint4*)(lds + orow * 264 + ohalf);
        uint4* dp = (uint4*)(H + (size_t)(row0 + orow) * 256 + ohalf);
#pragma unroll
        for (int q = 0; q < 16; ++q) dp[q] = sp[q];
    }
}

// ---------------- MFMA GEMM (r17): counted-vmcnt double-buffer; atom + head only ---------
template <int OUT>
__global__ __launch_bounds__(256)
void gemm_mfma(const unsigned short* __restrict__ A, const unsigned short* __restrict__ BT,
               const float* __restrict__ bias, float* __restrict__ C,
               unsigned short* __restrict__ Z, int M, int N, int KK) {
    __shared__ __align__(16) unsigned short lds_all[32768];   // 64 KB

    const int ncol = N >> 7;
    const int G = gridDim.x;
    int wg = blockIdx.x;
    {   // bijective XCD remap (m204)
        const int q = G >> 3, r = G & 7;
        const int xx = wg & 7, o = wg >> 3;
        wg = (xx < r ? xx * (q + 1) : r * (q + 1) + (xx - r) * q) + o;
    }
    const int col0 = (wg % ncol) << 7;
    const int row0 = (wg / ncol) << 7;

    const int tid = threadIdx.x;
    const int lane = tid & 63;
    const int w = tid >> 6;
    const int wr = w >> 1, wc = w & 1;
    const int lr = lane & 15;
    const int l4 = lane >> 4;
    const int srow = tid >> 3;
    const int sgran = ((tid & 7) ^ (srow & 7)) << 3;

    floatx4 acc[4][4];
#pragma unroll
    for (int m = 0; m < 4; ++m)
#pragma unroll
        for (int n = 0; n < 4; ++n) acc[m][n] = (floatx4){0.f, 0.f, 0.f, 0.f};

    const int NT = KK >> 6;

    auto stage = [&](int t, int b) {
        const int k0 = t << 6;
        unsigned short* la = &lds_all[b * 16384];
        unsigned short* lb = la + 8192;
#pragma unroll
        for (int pass = 0; pass < 4; ++pass) {
            const int r = (pass << 5) + srow;
            int ar = row0 + r; if (ar >= M) ar = M - 1;
            gload16(A + (size_t)ar * KK + k0 + sgran, &la[(pass << 11) + (w << 9)]);
            gload16(BT + (size_t)(col0 + r) * KK + k0 + sgran, &lb[(pass << 11) + (w << 9)]);
        }
    };

    stage(0, 0);
    if (NT > 1) stage(1, 1);
    for (int t = 0; t < NT; ++t) {
        const int cur = t & 1;
        if (t + 1 < NT) {
            asm volatile("s_waitcnt vmcnt(8)" ::: "memory");
        } else {
            asm volatile("s_waitcnt vmcnt(0)" ::: "memory");
        }
        __builtin_amdgcn_s_barrier();

        const unsigned short* la = &lds_all[cur * 16384];
        const unsigned short* lb = la + 8192;
#pragma unroll
        for (int s = 0; s < 2; ++s) {
            const int pg = (((s << 2) + l4) ^ (lr & 7)) << 3;
            bhalf8 fa[4], fb[4];
#pragma unroll
            for (int m = 0; m < 4; ++m)
                fa[m] = *(const bhalf8*)&la[((wr << 6) + (m << 4) + lr) * 64 + pg];
#pragma unroll
            for (int n = 0; n < 4; ++n)
                fb[n] = *(const bhalf8*)&lb[((wc << 6) + (n << 4) + lr) * 64 + pg];
#pragma unroll
            for (int m = 0; m < 4; ++m)
#pragma unroll
                for (int n = 0; n < 4; ++n)
                    acc[m][n] = __builtin_amdgcn_mfma_f32_16x16x32_bf16(fa[m], fb[n], acc[m][n], 0, 0, 0);
        }

        __builtin_amdgcn_s_barrier();
        if (t + 2 < NT) stage(t + 2, cur);
    }

    const int rgrp = l4 * 4;
    if (OUT == 2) {
        __syncthreads();
#pragma unroll
        for (int n = 0; n < 4; ++n) {
            const int colt = (wc << 6) + (n << 4) + lr;
            const float bv = bias[col0 + colt];
#pragma unroll
            for (int m = 0; m < 4; ++m) {
                const int rwt = (wr << 6) + (m << 4) + rgrp;
#pragma unroll
                for (int j = 0; j < 4; ++j)
                    lds_all[(rwt + j) * 136 + colt] = f2bf(fmaxf(acc[m][n][j] + bv, 0.f));
            }
        }
        __syncthreads();
        const int orow = tid >> 1;
        const int ocol = (tid & 1) << 6;
        if (row0 + orow < M) {
            const uint4* sp = (const uint4*)(lds_all + orow * 136 + ocol);
            uint4* dp = (uint4*)(Z + (size_t)(row0 + orow) * N + col0 + ocol);
#pragma unroll
            for (int q = 0; q < 8; ++q) dp[q] = sp[q];
        }
    } else {
#pragma unroll
        for (int n = 0; n < 4; ++n) {
            const int col = col0 + (wc << 6) + (n << 4) + lr;
            const float bv = bias[col];
#pragma unroll
            for (int m = 0; m < 4; ++m) {
                const int rw = row0 + (wr << 6) + (m << 4) + rgrp;
#pragma unroll
                for (int j = 0; j < 4; ++j) {
                    const int row = rw + j;
                    if (row < M) C[(size_t)row * N + col] = acc[m][n][j] + bv;
                }
            }
        }
    }
}

// ------- pool: sorted-batch segment mean over bf16 h -> bf16 [g][HDIM] -------
__global__ void pool_kernel(const unsigned short* __restrict__ h,
                            const int* __restrict__ batch,
                            unsigned short* __restrict__ gz) {
    __shared__ int sse[2];
    const int g = blockIdx.x;
    if (threadIdx.x < 2) {
        const int target = g + threadIdx.x;
        int lo = 0, hi = N_NODES;
        while (lo < hi) {
            const int mid = (lo + hi) >> 1;
            if (batch[mid] < target) lo = mid + 1; else hi = mid;
        }
        sse[threadIdx.x] = lo;
    }
    __syncthreads();
    const int s = sse[0], e = sse[1];
    const int j = threadIdx.x;
    float acc = 0.f;
    for (int n = s; n < e; ++n) acc += bf2f(h[(size_t)n * HDIM + j]);
    const float v = acc * ((e > s) ? 1.f / (float)(e - s) : 1.f);
    gz[(size_t)g * HDIM + j] = f2bf(v);
}

extern "C" void kernel_launch(void* const* d_in, const int* in_sizes, int n_in,
                              void* d_out, int out_size, void* d_ws, size_t ws_size,
                              hipStream_t stream) {
    const float* x      = (const float*)d_in[0];
    const int*   eidx   = (const int*)d_in[1];
    const int*   batch  = (const int*)d_in[2];
    const float* W_atom = (const float*)d_in[3];
    const float* b_atom = (const float*)d_in[4];
    const float* W1     = (const float*)d_in[5];
    const float* b1     = (const float*)d_in[6];
    const float* W2     = (const float*)d_in[7];
    const float* b2     = (const float*)d_in[8];
    const float* Wf1    = (const float*)d_in[9];
    const float* bf1    = (const float*)d_in[10];
    const float* Wf2    = (const float*)d_in[11];
    const float* bf2    = (const float*)d_in[12];
    float* out = (float*)d_out;

    const int* src = eidx;
    const int* dst = eidx + N_EDGES;

    const size_t NH = (size_t)N_NODES * HDIM;           // 25.6M elems
    const int WSZ = HDIM * 2 * HDIM;                    // 131072 elems per layer weight

    // ---- workspace layout ----
    char* base = (char*)d_ws;
    size_t off = 0;
    unsigned short* h = (unsigned short*)(base + off);      off += NH * 2;  // bf16 [N][256]
    unsigned short* zin = (unsigned short*)(base + off);    off += NH * 2;  // bf16 [N][256]
    unsigned short* xb = (unsigned short*)(base + off);     off += (size_t)N_NODES * 64 * 2;
    int* deg     = (int*)(base + off);            off += (size_t)N_NODES * 4;
    int* row_ptr = (int*)(base + off);            off += (size_t)(N_NODES + 1) * 4;
    int* cursor  = (int*)(base + off);            off += (size_t)N_NODES * 4;
    int* eids    = (int*)(base + off);            off += (size_t)N_EDGES * 4;
    int* blk     = (int*)(base + off);            off += 512 * 4;
    off = (off + 255) & ~(size_t)255;
    unsigned short* t1 = (unsigned short*)(base + off); off += (size_t)NLAYERS * WSZ * 2;
    unsigned short* t2 = (unsigned short*)(base + off); off += (size_t)NLAYERS * WSZ * 2;
    unsigned short* tf1 = (unsigned short*)(base + off); off += (size_t)HDIM * HDIM * 2;
    unsigned short* tf2 = (unsigned short*)(base + off); off += (size_t)HDIM * EDIM * 2;
    unsigned short* tat = (unsigned short*)(base + off); off += (size_t)HDIM * 64 * 2;
    off = (off + 255) & ~(size_t)255;

    // head buffers overlap the (dead-after-layers) zin region
    const size_t GH = (size_t)N_GRAPHS * HDIM;
    unsigned short* hg  = zin;            // [4000][256] bf16
    unsigned short* hg1 = zin + GH;       // [4000][256] bf16

    const int nb = (N_NODES + 255) / 256;
    const int nrow128 = (N_NODES + 127) / 128;   // 782

    // 1. x -> bf16 padded [N][64]; weights -> transposed bf16 (one dispatch each)
    xprep_kernel<<<1024, 256, 0, stream>>>(x, xb);
    wprep_all<<<1024, 256, 0, stream>>>(W1, W2, Wf1, Wf2, W_atom, t1, t2, tf1, tf2, tat);

    // 2. CSR build (+ deterministic segment sort)
    zero_kernel<<<128, 256, 0, stream>>>((float*)deg, N_NODES / 4);
    hist_kernel<<<(N_EDGES + 255) / 256, 256, 0, stream>>>(dst, deg);
    scan1_kernel<<<nb, 256, 0, stream>>>(deg, row_ptr, blk);
    scan2_kernel<<<1, 64, 0, stream>>>(blk, nb);
    scan3_kernel<<<nb, 256, 0, stream>>>(row_ptr, blk);
    cursor_kernel<<<nb, 256, 0, stream>>>(row_ptr, cursor);
    fill_kernel<<<(N_EDGES + 255) / 256, 256, 0, stream>>>(src, dst, cursor, eids);
    sort_kernel<<<nb, 256, 0, stream>>>(row_ptr, eids);   // deterministic gather order

    // 3. atom MLP as MFMA GEMM: h = relu(xb @ W_atom + b_atom)  [100000, 256], KK=64
    gemm_mfma<2><<<2 * nrow128, 256, 0, stream>>>(
        xb, tat, b_atom, nullptr, h, N_NODES, HDIM, 64);

    // 4. GIN layers: gather + single fused (GEMM1+GEMM2) kernel per layer
    for (int l = 0; l < NLAYERS; ++l) {
        gather_kernel<<<N_NODES / 4, 256, 0, stream>>>(h, row_ptr, eids, zin);
        fused_layer<<<nrow128, 256, 0, stream>>>(
            zin, t1 + (size_t)l * WSZ, t2 + (size_t)l * WSZ,
            b1 + (size_t)l * 2 * HDIM, b2 + (size_t)l * HDIM, h, N_NODES);
    }

    // 5. pool (bf16 in/out)
    pool_kernel<<<N_GRAPHS, HDIM, 0, stream>>>(h, batch, hg);

    // 6. head
    gemm_mfma<2><<<2 * ((N_GRAPHS + 127) / 128), 256, 0, stream>>>(
        hg, tf1, bf1, nullptr, hg1, N_GRAPHS, HDIM, HDIM);
    gemm_mfma<0><<<4 * ((N_GRAPHS + 127) / 128), 256, 0, stream>>>(
        hg1, tf2, bf2, out, nullptr, N_GRAPHS, EDIM, HDIM);
}